// Round 3
// baseline (564.592 us; speedup 1.0000x reference)
//
#include <hip/hip_runtime.h>
#include <hip/hip_bf16.h>
#include <math.h>

// ---------------------------------------------------------------------------
// Dims (fixed per reference)
// ---------------------------------------------------------------------------
#define BATCH   16384
#define D_IN    1024
#define H1_DIM  512
#define H2_DIM  256
#define H3_DIM  128
#define D_CBP   2048
#define H_C     1024
#define CLASSES 10
#define SLOPE   0.2f

// FFT-domain dims: rfft bins k = 0..1024 (1025), padded to 1088 complex
// -> 2176 real columns (Re,Im interleaved), = 17 tiles of 128.
#define NK_PAD  1088
#define NF      (2 * NK_PAD)   // 2176

typedef short v8s __attribute__((ext_vector_type(8)));
typedef float v4f __attribute__((ext_vector_type(4)));
typedef unsigned short u16;
typedef unsigned int   u32;

__device__ __forceinline__ float b2f(unsigned short u) {
  return __uint_as_float(((unsigned)u) << 16);
}
__device__ __forceinline__ u16 f2b(float f) {
  __hip_bfloat16 h = __float2bfloat16(f);   // RNE
  return __builtin_bit_cast(unsigned short, h);
}

// async 16B global->LDS (direct-to-shared DMA). LDS dest = wave-uniform base
// + lane*16 -> LDS layout is forced packed lane-order.
__device__ __forceinline__ void g2l16(const void* g, void* l) {
  __builtin_amdgcn_global_load_lds(
      (const __attribute__((address_space(1))) void*)g,
      (__attribute__((address_space(3))) void*)l, 16, 0, 0);
}

// ---------------------------------------------------------------------------
// bf16 MFMA GEMM (m97 structure): C[M,N] = lrelu(A[M,K] @ Bt[N,K]^T + bias)
// Tile 128x128, BK=32, 256 threads (4 waves, 2x2 of 64x64), 16 MFMA/wave/step.
// Granule rotation swizzle applied at the GLOBAL address so both A- and
// B-fragment ds_read_b128 are exactly 2 lanes/bank (free).
// Bijective XCD-aware block swizzle (T1, r2: −17 µs verified).
// slope: LeakyReLU negative slope; 1.0f = identity epilogue.
// ---------------------------------------------------------------------------
__global__ __launch_bounds__(256) void gemm_bf16(
    const u16* __restrict__ A,   // [M][K] bf16
    const u16* __restrict__ Bt,  // [N][K] bf16  (weights pre-transposed)
    const float* __restrict__ bias,
    u16* __restrict__ C,         // [M][N] bf16
    int M, int N, int K, float slope)
{
  __shared__ __align__(16) short Asb[128 * 32];
  __shared__ __align__(16) short Bsb[128 * 32];

  const int tid  = threadIdx.x;
  const int wave = tid >> 6, lane = tid & 63;
  const int wm = wave >> 1, wn = wave & 1;
  const int u = lane & 15, quad = lane >> 4;

  // XCD swizzle: contiguous panel per XCD (bijective iff nwg % 8 == 0).
  const int nwg = gridDim.x * gridDim.y;
  int id = blockIdx.y * gridDim.x + blockIdx.x;
  if ((nwg & 7) == 0) id = (id & 7) * (nwg >> 3) + (id >> 3);
  const int m0 = (id / gridDim.x) * 128, n0 = (id % gridDim.x) * 128;

  const int g_log = ((lane & 3) - ((lane >> 3) & 3)) & 3;
  const int srow  = wave * 32 + (lane >> 2);
  const u16* gA0 = A  + (size_t)(m0 + srow)      * K + g_log * 8;
  const u16* gA1 = A  + (size_t)(m0 + srow + 16) * K + g_log * 8;
  const u16* gB0 = Bt + (size_t)(n0 + srow)      * K + g_log * 8;
  const u16* gB1 = Bt + (size_t)(n0 + srow + 16) * K + g_log * 8;
  short* lA0 = &Asb[(wave * 32)      * 32];
  short* lA1 = &Asb[(wave * 32 + 16) * 32];
  short* lB0 = &Bsb[(wave * 32)      * 32];
  short* lB1 = &Bsb[(wave * 32 + 16) * 32];

  const int gran = (quad + (u >> 1)) & 3;
  int offA[4], offB[4];
#pragma unroll
  for (int i = 0; i < 4; ++i) {
    offA[i] = (wm * 64 + i * 16 + u) * 32 + gran * 8;
    offB[i] = (wn * 64 + i * 16 + u) * 32 + gran * 8;
  }

  v4f acc[4][4];
#pragma unroll
  for (int i = 0; i < 4; ++i)
#pragma unroll
    for (int j = 0; j < 4; ++j) acc[i][j] = (v4f){0.f, 0.f, 0.f, 0.f};

  for (int k0 = 0; k0 < K; k0 += 32) {
    __syncthreads();
    g2l16(gA0 + k0, lA0);
    g2l16(gA1 + k0, lA1);
    g2l16(gB0 + k0, lB0);
    g2l16(gB1 + k0, lB1);
    __syncthreads();
    v8s a[4], b[4];
#pragma unroll
    for (int i = 0; i < 4; ++i) a[i] = *(const v8s*)&Asb[offA[i]];
#pragma unroll
    for (int j = 0; j < 4; ++j) b[j] = *(const v8s*)&Bsb[offB[j]];
#pragma unroll
    for (int i = 0; i < 4; ++i)
#pragma unroll
      for (int j = 0; j < 4; ++j)
        acc[i][j] = __builtin_amdgcn_mfma_f32_16x16x32_bf16(a[i], b[j], acc[i][j], 0, 0, 0);
  }

  // C/D layout (m89-verified): col = lane&15, row = quad*4 + reg
  float bcol[4];
#pragma unroll
  for (int j = 0; j < 4; ++j) bcol[j] = bias[n0 + wn * 64 + j * 16 + u];
#pragma unroll
  for (int i = 0; i < 4; ++i)
#pragma unroll
    for (int r = 0; r < 4; ++r) {
      const size_t ro = (size_t)(m0 + wm * 64 + i * 16 + quad * 4 + r) * N
                        + n0 + wn * 64 + u;
#pragma unroll
      for (int j = 0; j < 4; ++j) {
        float v = acc[i][j][r] + bcol[j];
        v = v >= 0.f ? v : slope * v;
        C[ro + j * 16] = f2b(v);
      }
    }
}

// ---------------------------------------------------------------------------
// cast fp32 -> bf16, two sources in one launch (X then Centers)
// ---------------------------------------------------------------------------
#define CAST_NB (BATCH * D_IN / 4 / 256)   // blocks per source
__global__ __launch_bounds__(256) void cast2_bf16(
    const float* __restrict__ srcA, const float* __restrict__ srcB,
    u16* __restrict__ dst)
{
  const int bx = blockIdx.x;
  const float* s = (bx < CAST_NB) ? srcA : srcB;
  const int i = ((bx < CAST_NB) ? bx : bx - CAST_NB) * 256 + threadIdx.x;
  u16* d = dst + ((bx < CAST_NB) ? 0 : (size_t)BATCH * D_IN);
  const float4 v = ((const float4*)s)[i];
  __align__(8) u16 o[4] = {f2b(v.x), f2b(v.y), f2b(v.z), f2b(v.w)};
  *(uint2*)(d + (size_t)i * 4) = *(uint2*)o;
}

// ---------------------------------------------------------------------------
// transpose + cast, all 4 weights in one launch (z selects the matrix):
// W[K][N] fp32 -> Wt[N][K] bf16.  32x32 tiles via LDS.
// ---------------------------------------------------------------------------
__global__ __launch_bounds__(256) void transpose_cast4(
    const float* __restrict__ W1, u16* __restrict__ W1t,
    const float* __restrict__ W2, u16* __restrict__ W2t,
    const float* __restrict__ W3, u16* __restrict__ W3t,
    const float* __restrict__ Wc1, u16* __restrict__ Wc1t)
{
  __shared__ float tile[32][33];
  const int z = blockIdx.z;
  const float* W; u16* Wt; int K, N;
  if      (z == 0) { W = W1;  Wt = W1t;  K = D_IN;   N = H1_DIM; }
  else if (z == 1) { W = W2;  Wt = W2t;  K = H1_DIM; N = H2_DIM; }
  else if (z == 2) { W = W3;  Wt = W3t;  K = H2_DIM; N = H3_DIM; }
  else             { W = Wc1; Wt = Wc1t; K = D_CBP;  N = H_C;    }
  const int k0 = blockIdx.x * 32, n0 = blockIdx.y * 32;
  if (k0 >= K || n0 >= N) return;
  const int tx = threadIdx.x & 31, ty = threadIdx.x >> 5;
#pragma unroll
  for (int s = 0; s < 4; ++s) {
    const int k = ty * 4 + s;
    tile[k][tx] = W[(size_t)(k0 + k) * N + n0 + tx];
  }
  __syncthreads();
#pragma unroll
  for (int s = 0; s < 4; ++s) {
    const int n = ty * 4 + s;
    Wt[(size_t)(n0 + n) * K + k0 + tx] = f2b(tile[tx][n]);
  }
}

// ---------------------------------------------------------------------------
// FFT-domain CBP (replaces the LDS gather kernel, which was at its dual
// DS/VALU roofline at 167 µs).  Identity used:
//   cbp = irfft(F1 .* F2),  F1[k] = sum_i a_i e^{-2πi k h1_i/2048}  (K=128!)
//   cbp @ Wc1 = sum_k w_k/N * (Pr[k] Gr[k,c] - Pi[k] Gi[k,c]),
//     G[k,c] = sum_q Wc1[q,c] e^{+2πi qk/N},  w_0 = w_1024 = 1 else 2.
// So the whole CBP+G4 chain becomes GEMMs:
//   F1 = E3x @ C1, F2 = E3c @ C2   (C = per-launch twiddle matrices, K=128)
//   P  = F1 (.)complex F2           (pointwise, in-place)
//   Z  = lrelu(P @ FWt^T + bc1),   FWt = Wc1t @ Tt^T (twiddle GEMM)
// [r1 post-mortem: random-bank LDS atomics ~198 cyc/wave-op -> never again.]
// ---------------------------------------------------------------------------

// tab[t] = (cos, sin)(2π t / 2048);  zbias = zeros (bias for slope-1 GEMMs)
__global__ __launch_bounds__(256) void setup_tab(
    float2* __restrict__ tab, float* __restrict__ zbias)
{
  const int t = blockIdx.x * 256 + threadIdx.x;
  if (t < D_CBP) {
    const float ang = 6.2831853071795864769f * (float)t / (float)D_CBP;
    tab[t] = make_float2(__cosf(ang), __sinf(ang));
  }
  if (t < NF) zbias[t] = 0.f;
}

// C1t/C2t [NF][128] bf16:  row m (k=m>>1): even m -> s_i cos(2π k h_i/2048),
// odd m -> -s_i sin(...).  m >= 2050 -> 0 (pad).
__global__ __launch_bounds__(256) void gen_C(
    const float2* __restrict__ tab,
    const int* __restrict__ h1, const float* __restrict__ s1,
    const int* __restrict__ h2, const float* __restrict__ s2,
    u16* __restrict__ C1t, u16* __restrict__ C2t)
{
  const int id = blockIdx.x * 256 + threadIdx.x;   // [0, NF*128)
  if (id >= NF * H3_DIM) return;
  const int m = id >> 7, i = id & 127;
  const int k = m >> 1;
  float v1 = 0.f, v2 = 0.f;
  if (m < 2 * (D_CBP / 2 + 1)) {                   // m < 2050
    const float2 c1 = tab[(k * h1[i]) & (D_CBP - 1)];
    const float2 c2 = tab[(k * h2[i]) & (D_CBP - 1)];
    v1 = (m & 1) ? -s1[i] * c1.y : s1[i] * c1.x;
    v2 = (m & 1) ? -s2[i] * c2.y : s2[i] * c2.x;
  }
  C1t[id] = f2b(v1);
  C2t[id] = f2b(v2);
}

// Tt [NF][2048] bf16: row m (k=m>>1): even -> w_k cos(2π kq/2048)/2048,
// odd -> -w_k sin(...)/2048.  8 q per thread.
__global__ __launch_bounds__(256) void gen_T(
    const float2* __restrict__ tab, u16* __restrict__ Tt)
{
  const int id = blockIdx.x * 256 + threadIdx.x;   // [0, NF*256)
  const int m = id >> 8, q0 = (id & 255) * 8;
  const int k = m >> 1;
  const float sc = ((k == 0) || (k == D_CBP / 2)) ? (1.f / D_CBP) : (2.f / D_CBP);
  __align__(16) u16 o[8];
#pragma unroll
  for (int j = 0; j < 8; ++j) {
    float v = 0.f;
    if (m < 2 * (D_CBP / 2 + 1)) {
      const float2 cs = tab[(k * (q0 + j)) & (D_CBP - 1)];
      v = (m & 1) ? -sc * cs.y : sc * cs.x;
    }
    o[j] = f2b(v);
  }
  *(v8s*)&Tt[(size_t)m * D_CBP + q0] = *(v8s*)o;
}

// P = F1 (.)complex F2, in place into F1.  Layout [..][2k]=Re, [2k+1]=Im;
// one uint4 = 4 complex per thread.
__global__ __launch_bounds__(256) void cplx_mul(
    u16* __restrict__ F1, const u16* __restrict__ F2)
{
  const int id = blockIdx.x * 256 + threadIdx.x;
  uint4 a = *(const uint4*)&F1[(size_t)id * 8];
  const uint4 b = *(const uint4*)&F2[(size_t)id * 8];
  u32* ap = (u32*)&a;
  const u32* bp = (const u32*)&b;
#pragma unroll
  for (int c = 0; c < 4; ++c) {
    const float ar = b2f((u16)(ap[c] & 0xffffu)), ai = b2f((u16)(ap[c] >> 16));
    const float br = b2f((u16)(bp[c] & 0xffffu)), bi = b2f((u16)(bp[c] >> 16));
    const float pr = ar * br - ai * bi;
    const float pi = ar * bi + ai * br;
    ap[c] = (u32)f2b(pr) | ((u32)f2b(pi) << 16);
  }
  *(uint4*)&F1[(size_t)id * 8] = a;
}

// ---------------------------------------------------------------------------
// Head: logits = Z[B,1024](bf16) @ Wc2[1024,10] + bc2; softmax -> fp32 out.
// ---------------------------------------------------------------------------
__global__ __launch_bounds__(256) void head_softmax(
    const u16* __restrict__ Z, const float* __restrict__ Wc2,
    const float* __restrict__ bc2, float* __restrict__ out)
{
  const int row  = blockIdx.x * 4 + (threadIdx.x >> 6);
  const int lane = threadIdx.x & 63;

  float acc[CLASSES];
#pragma unroll
  for (int c = 0; c < CLASSES; ++c) acc[c] = 0.f;

  const u16* z = Z + (size_t)row * H_C;
  for (int k = lane; k < H_C; k += 64) {
    const float zv = b2f(z[k]);
    const float* w = Wc2 + (size_t)k * CLASSES;
#pragma unroll
    for (int c = 0; c < CLASSES; ++c) acc[c] += zv * w[c];
  }
#pragma unroll
  for (int c = 0; c < CLASSES; ++c) {
#pragma unroll
    for (int off = 32; off > 0; off >>= 1)
      acc[c] += __shfl_down(acc[c], off);
  }
  if (lane == 0) {
    float l[CLASSES], mx = -1e30f;
#pragma unroll
    for (int c = 0; c < CLASSES; ++c) { l[c] = acc[c] + bc2[c]; mx = fmaxf(mx, l[c]); }
    float s = 0.f;
#pragma unroll
    for (int c = 0; c < CLASSES; ++c) { l[c] = __expf(l[c] - mx); s += l[c]; }
    const float inv = 1.f / s;
#pragma unroll
    for (int c = 0; c < CLASSES; ++c) out[(size_t)row * CLASSES + c] = l[c] * inv;
  }
}

// ---------------------------------------------------------------------------
// Launcher.  Workspace map (MB = 1<<20), peak < 128 MiB:
//   Xb   @ 0..64     [2B,1024] bf16      (cast -> G1; dead after G1)
//   Tt   @ 0..8.5    [2176,2048] bf16    (gen_T after G1 -> FWt gemm)
//   FWt  @ 8.5..12.75 [1024,2176] bf16   (FWt gemm -> G4')
//   F1h  @ 13..47    [8192,2176] bf16    (per half; P overwrites in place)
//   F2h  @ 47..81    [8192,2176] bf16    (per half)
//   Zb   @ 81..113   [16384,1024] bf16   (G4' -> head; over dead E1b/E2b)
//   E1b  @ 64..96    (G1 -> G2)
//   E2b  @ 96..112   (G2 -> G3)
//   W1t @113  W2t @114  W3t @114.25  Wc1t @114.5..118.5
//   E3b  @ 118.5..126.5 [2B,128] bf16    (G3 -> F gemms)
//   C1t @126.5  C2t @127.0625  tab @127.625  zbias @127.65625
// ---------------------------------------------------------------------------
extern "C" void kernel_launch(void* const* d_in, const int* in_sizes, int n_in,
                              void* d_out, int out_size, void* d_ws, size_t ws_size,
                              hipStream_t stream) {
  const float* X       = (const float*)d_in[0];
  const float* Centers = (const float*)d_in[1];
  const float* W1      = (const float*)d_in[2];
  const float* b1      = (const float*)d_in[3];
  const float* W2      = (const float*)d_in[4];
  const float* b2      = (const float*)d_in[5];
  const float* W3      = (const float*)d_in[6];
  const float* b3      = (const float*)d_in[7];
  const int*   h1      = (const int*)d_in[8];
  const float* s1      = (const float*)d_in[9];
  const int*   h2      = (const int*)d_in[10];
  const float* s2      = (const float*)d_in[11];
  const float* Wc1     = (const float*)d_in[12];
  const float* bc1     = (const float*)d_in[13];
  const float* Wc2     = (const float*)d_in[14];
  const float* bc2     = (const float*)d_in[15];
  float* out = (float*)d_out;

  char* ws = (char*)d_ws;
  const size_t MB = 1u << 20;
  const size_t KB = 1u << 10;
  u16*    Xb    = (u16*)(ws);
  u16*    Tt    = (u16*)(ws);                       // after G1
  u16*    FWt   = (u16*)(ws + 8 * MB + 512 * KB);
  u16*    F1h   = (u16*)(ws + 13 * MB);
  u16*    F2h   = (u16*)(ws + 47 * MB);
  u16*    Zb    = (u16*)(ws + 81 * MB);
  u16*    E1b   = (u16*)(ws + 64 * MB);
  u16*    E2b   = (u16*)(ws + 96 * MB);
  u16*    W1t   = (u16*)(ws + 113 * MB);
  u16*    W2t   = (u16*)(ws + 114 * MB);
  u16*    W3t   = (u16*)(ws + 114 * MB + 256 * KB);
  u16*    Wc1t  = (u16*)(ws + 114 * MB + 512 * KB);
  u16*    E3b   = (u16*)(ws + 118 * MB + 512 * KB);
  u16*    C1t   = (u16*)(ws + 126 * MB + 512 * KB);
  u16*    C2t   = (u16*)(ws + 127 * MB + 64 * KB);
  float2* tab   = (float2*)(ws + 127 * MB + 640 * KB);
  float*  zbias = (float*)(ws + 127 * MB + 672 * KB);

  const dim3 blk(256);
  const int HB = BATCH / 2;   // 8192 rows per half

  // casts: X, Centers -> Xb rows [0..B), [B..2B)
  cast2_bf16<<<dim3(2 * CAST_NB), blk, 0, stream>>>(X, Centers, Xb);

  // weight transposes
  transpose_cast4<<<dim3(D_CBP / 32, H_C / 32, 4), blk, 0, stream>>>(
      W1, W1t, W2, W2t, W3, W3t, Wc1, Wc1t);

  // twiddle table + zero bias; C1t/C2t (need only h/s inputs)
  setup_tab<<<dim3(9), blk, 0, stream>>>(tab, zbias);
  gen_C<<<dim3(NF * H3_DIM / 256), blk, 0, stream>>>(tab, h1, s1, h2, s2, C1t, C2t);

  // G1 (frees Xb region for Tt/FWt)
  gemm_bf16<<<dim3(H1_DIM / 128, 2 * BATCH / 128), blk, 0, stream>>>(
      Xb, W1t, b1, E1b, 2 * BATCH, H1_DIM, D_IN, SLOPE);

  // Tt and FWt = Wc1t @ Tt^T   [1024][2176]
  gen_T<<<dim3(NF), blk, 0, stream>>>(tab, Tt);
  gemm_bf16<<<dim3(NF / 128, H_C / 128), blk, 0, stream>>>(
      Wc1t, Tt, zbias, FWt, H_C, NF, D_CBP, 1.0f);

  // G2, G3
  gemm_bf16<<<dim3(H2_DIM / 128, 2 * BATCH / 128), blk, 0, stream>>>(
      E1b, W2t, b2, E2b, 2 * BATCH, H2_DIM, H1_DIM, SLOPE);
  gemm_bf16<<<dim3(H3_DIM / 128, 2 * BATCH / 128), blk, 0, stream>>>(
      E2b, W3t, b3, E3b, 2 * BATCH, H3_DIM, H2_DIM, SLOPE);

  // FFT-domain CBP + comparator layer, two batch halves (workspace budget)
  for (int h = 0; h < 2; ++h) {
    const u16* E3x = E3b + (size_t)h * HB * H3_DIM;
    const u16* E3c = E3b + (size_t)(BATCH + h * HB) * H3_DIM;
    // F1 = E3x @ C1, F2 = E3c @ C2   [8192][2176], K=128
    gemm_bf16<<<dim3(NF / 128, HB / 128), blk, 0, stream>>>(
        E3x, C1t, zbias, F1h, HB, NF, H3_DIM, 1.0f);
    gemm_bf16<<<dim3(NF / 128, HB / 128), blk, 0, stream>>>(
        E3c, C2t, zbias, F2h, HB, NF, H3_DIM, 1.0f);
    // P = F1 .* F2 (complex), in place into F1h
    cplx_mul<<<dim3(HB * NF / 8 / 256), blk, 0, stream>>>(F1h, F2h);
    // Z = lrelu(P @ FWt^T + bc1)   [8192][1024], K=2176
    gemm_bf16<<<dim3(H_C / 128, HB / 128), blk, 0, stream>>>(
        F1h, FWt, bc1, Zb + (size_t)h * HB * H_C, HB, H_C, NF, SLOPE);
  }

  // head
  head_softmax<<<dim3(BATCH / 4), blk, 0, stream>>>(Zb, Wc2, bc2, out);
}

// Round 4
// 536.679 us; speedup vs baseline: 1.0520x; 1.0520x over previous
//
#include <hip/hip_runtime.h>
#include <hip/hip_bf16.h>
#include <math.h>

// ---------------------------------------------------------------------------
// Dims (fixed per reference)
// ---------------------------------------------------------------------------
#define BATCH   16384
#define D_IN    1024
#define H1_DIM  512
#define H2_DIM  256
#define H3_DIM  128
#define D_CBP   2048
#define H_C     1024
#define CLASSES 10
#define SLOPE   0.2f

// FFT-domain dims: rfft bins k = 0..1024 (1025), padded to 1088 complex
// -> 2176 real columns (Re,Im interleaved), = 17 tiles of 128.
#define NK_PAD  1088
#define NF      (2 * NK_PAD)   // 2176

typedef short v8s __attribute__((ext_vector_type(8)));
typedef float v4f __attribute__((ext_vector_type(4)));
typedef unsigned short u16;
typedef unsigned int   u32;

__device__ __forceinline__ float b2f(unsigned short u) {
  return __uint_as_float(((unsigned)u) << 16);
}
__device__ __forceinline__ u16 f2b(float f) {
  __hip_bfloat16 h = __float2bfloat16(f);   // RNE
  return __builtin_bit_cast(unsigned short, h);
}

// async 16B global->LDS (direct-to-shared DMA). LDS dest = wave-uniform base
// + lane*16 -> LDS layout is forced packed lane-order.
__device__ __forceinline__ void g2l16(const void* g, void* l) {
  __builtin_amdgcn_global_load_lds(
      (const __attribute__((address_space(1))) void*)g,
      (__attribute__((address_space(3))) void*)l, 16, 0, 0);
}

// ---------------------------------------------------------------------------
// bf16 MFMA GEMM (m97 structure): C[M,N] = epilogue(A[M,K] @ Bt[N,K]^T).
// Tile 128x128, BK=32, 256 threads (4 waves, 2x2 of 64x64), 16 MFMA/wave/step.
// Granule rotation swizzle applied at the GLOBAL address so both A- and
// B-fragment ds_read_b128 are exactly 2 lanes/bank (free).
// Bijective XCD-aware block swizzle (T1, r2: −17 µs verified).
// CMUL=0: C = lrelu_slope(acc + bias).
// CMUL=1: C holds F1 (Re,Im interleaved cols); acc is F2. In-place complex
//         product: Re/Im partner is lane^1 (adjacent column, same quad),
//         exchanged with shfl_xor. C <- F1 (.) F2.  (bias/slope unused)
// ---------------------------------------------------------------------------
template <int CMUL>
__global__ __launch_bounds__(256) void gemm_bf16_t(
    const u16* __restrict__ A,   // [M][K] bf16
    const u16* __restrict__ Bt,  // [N][K] bf16  (weights pre-transposed)
    const float* __restrict__ bias,
    u16* __restrict__ C,         // [M][N] bf16
    int M, int N, int K, float slope)
{
  __shared__ __align__(16) short Asb[128 * 32];
  __shared__ __align__(16) short Bsb[128 * 32];

  const int tid  = threadIdx.x;
  const int wave = tid >> 6, lane = tid & 63;
  const int wm = wave >> 1, wn = wave & 1;
  const int u = lane & 15, quad = lane >> 4;

  // XCD swizzle: contiguous panel per XCD (bijective iff nwg % 8 == 0).
  const int nwg = gridDim.x * gridDim.y;
  int id = blockIdx.y * gridDim.x + blockIdx.x;
  if ((nwg & 7) == 0) id = (id & 7) * (nwg >> 3) + (id >> 3);
  const int m0 = (id / gridDim.x) * 128, n0 = (id % gridDim.x) * 128;

  const int g_log = ((lane & 3) - ((lane >> 3) & 3)) & 3;
  const int srow  = wave * 32 + (lane >> 2);
  const u16* gA0 = A  + (size_t)(m0 + srow)      * K + g_log * 8;
  const u16* gA1 = A  + (size_t)(m0 + srow + 16) * K + g_log * 8;
  const u16* gB0 = Bt + (size_t)(n0 + srow)      * K + g_log * 8;
  const u16* gB1 = Bt + (size_t)(n0 + srow + 16) * K + g_log * 8;
  short* lA0 = &Asb[(wave * 32)      * 32];
  short* lA1 = &Asb[(wave * 32 + 16) * 32];
  short* lB0 = &Bsb[(wave * 32)      * 32];
  short* lB1 = &Bsb[(wave * 32 + 16) * 32];

  const int gran = (quad + (u >> 1)) & 3;
  int offA[4], offB[4];
#pragma unroll
  for (int i = 0; i < 4; ++i) {
    offA[i] = (wm * 64 + i * 16 + u) * 32 + gran * 8;
    offB[i] = (wn * 64 + i * 16 + u) * 32 + gran * 8;
  }

  v4f acc[4][4];
#pragma unroll
  for (int i = 0; i < 4; ++i)
#pragma unroll
    for (int j = 0; j < 4; ++j) acc[i][j] = (v4f){0.f, 0.f, 0.f, 0.f};

  for (int k0 = 0; k0 < K; k0 += 32) {
    __syncthreads();
    g2l16(gA0 + k0, lA0);
    g2l16(gA1 + k0, lA1);
    g2l16(gB0 + k0, lB0);
    g2l16(gB1 + k0, lB1);
    __syncthreads();
    v8s a[4], b[4];
#pragma unroll
    for (int i = 0; i < 4; ++i) a[i] = *(const v8s*)&Asb[offA[i]];
#pragma unroll
    for (int j = 0; j < 4; ++j) b[j] = *(const v8s*)&Bsb[offB[j]];
#pragma unroll
    for (int i = 0; i < 4; ++i)
#pragma unroll
      for (int j = 0; j < 4; ++j)
        acc[i][j] = __builtin_amdgcn_mfma_f32_16x16x32_bf16(a[i], b[j], acc[i][j], 0, 0, 0);
  }

  // C/D layout (m89-verified): col = lane&15, row = quad*4 + reg
  if (CMUL == 0) {
    float bcol[4];
#pragma unroll
    for (int j = 0; j < 4; ++j) bcol[j] = bias[n0 + wn * 64 + j * 16 + u];
#pragma unroll
    for (int i = 0; i < 4; ++i)
#pragma unroll
      for (int r = 0; r < 4; ++r) {
        const size_t ro = (size_t)(m0 + wm * 64 + i * 16 + quad * 4 + r) * N
                          + n0 + wn * 64 + u;
#pragma unroll
        for (int j = 0; j < 4; ++j) {
          float v = acc[i][j][r] + bcol[j];
          v = v >= 0.f ? v : slope * v;
          C[ro + j * 16] = f2b(v);
        }
      }
  } else {
    // In-place complex product: even col (u even) = Re, odd = Im.
    const bool im = (u & 1);
#pragma unroll
    for (int i = 0; i < 4; ++i)
#pragma unroll
      for (int r = 0; r < 4; ++r) {
        const size_t ro = (size_t)(m0 + wm * 64 + i * 16 + quad * 4 + r) * N
                          + n0 + wn * 64 + u;
#pragma unroll
        for (int j = 0; j < 4; ++j) {
          const float f2v = acc[i][j][r];
          const float f2p = __shfl_xor(f2v, 1, 64);
          const float f1v = b2f(C[ro + j * 16]);
          const float f1p = __shfl_xor(f1v, 1, 64);
          // even lane: f1r*f2r - f1i*f2i ; odd lane: f1r*f2i + f1i*f2r
          const float outv = im ? (f1p * f2v + f1v * f2p)
                                : (f1v * f2v - f1p * f2p);
          C[ro + j * 16] = f2b(outv);
        }
      }
  }
}

// ---------------------------------------------------------------------------
// cast fp32 -> bf16, two sources in one launch (X then Centers)
// ---------------------------------------------------------------------------
#define CAST_NB (BATCH * D_IN / 4 / 256)   // blocks per source
__global__ __launch_bounds__(256) void cast2_bf16(
    const float* __restrict__ srcA, const float* __restrict__ srcB,
    u16* __restrict__ dst)
{
  const int bx = blockIdx.x;
  const float* s = (bx < CAST_NB) ? srcA : srcB;
  const int i = ((bx < CAST_NB) ? bx : bx - CAST_NB) * 256 + threadIdx.x;
  u16* d = dst + ((bx < CAST_NB) ? 0 : (size_t)BATCH * D_IN);
  const float4 v = ((const float4*)s)[i];
  __align__(8) u16 o[4] = {f2b(v.x), f2b(v.y), f2b(v.z), f2b(v.w)};
  *(uint2*)(d + (size_t)i * 4) = *(uint2*)o;
}

// ---------------------------------------------------------------------------
// transpose + cast, all 4 weights in one launch (z selects the matrix):
// W[K][N] fp32 -> Wt[N][K] bf16.  32x32 tiles via LDS.
// ---------------------------------------------------------------------------
__global__ __launch_bounds__(256) void transpose_cast4(
    const float* __restrict__ W1, u16* __restrict__ W1t,
    const float* __restrict__ W2, u16* __restrict__ W2t,
    const float* __restrict__ W3, u16* __restrict__ W3t,
    const float* __restrict__ Wc1, u16* __restrict__ Wc1t)
{
  __shared__ float tile[32][33];
  const int z = blockIdx.z;
  const float* W; u16* Wt; int K, N;
  if      (z == 0) { W = W1;  Wt = W1t;  K = D_IN;   N = H1_DIM; }
  else if (z == 1) { W = W2;  Wt = W2t;  K = H1_DIM; N = H2_DIM; }
  else if (z == 2) { W = W3;  Wt = W3t;  K = H2_DIM; N = H3_DIM; }
  else             { W = Wc1; Wt = Wc1t; K = D_CBP;  N = H_C;    }
  const int k0 = blockIdx.x * 32, n0 = blockIdx.y * 32;
  if (k0 >= K || n0 >= N) return;
  const int tx = threadIdx.x & 31, ty = threadIdx.x >> 5;
#pragma unroll
  for (int s = 0; s < 4; ++s) {
    const int k = ty * 4 + s;
    tile[k][tx] = W[(size_t)(k0 + k) * N + n0 + tx];
  }
  __syncthreads();
#pragma unroll
  for (int s = 0; s < 4; ++s) {
    const int n = ty * 4 + s;
    Wt[(size_t)(n0 + n) * K + k0 + tx] = f2b(tile[tx][n]);
  }
}

// ---------------------------------------------------------------------------
// FFT-domain CBP.  Identity:
//   cbp = irfft(F1 .* F2),  F1[k] = sum_i a_i e^{-2πi k h1_i/2048}  (K=128)
//   cbp @ Wc1 = sum_k w_k/N * (Pr[k] Gr[k,c] - Pi[k] Gi[k,c]),
//     G[k,c] = sum_q Wc1[q,c] e^{+2πi qk/N},  w_0 = w_1024 = 1 else 2.
// Chain: F1 = E3x @ C1;  F1 <- F1 (.) (E3c @ C2)  [fused epilogue];
//        Z = lrelu(F1 @ FWt^T + bc1),  FWt = Wc1t @ Tt^T.
// [r1: random-bank LDS atomics ~198 cyc/wave-op — never on critical path.
//  r3: half-split G4' = 2 blk/CU = 589 TF; full-batch + fused cplx fixes.]
// ---------------------------------------------------------------------------

// tab[t] = (cos, sin)(2π t / 2048);  zbias = zeros (bias for slope-1 GEMMs)
__global__ __launch_bounds__(256) void setup_tab(
    float2* __restrict__ tab, float* __restrict__ zbias)
{
  const int t = blockIdx.x * 256 + threadIdx.x;
  if (t < D_CBP) {
    const float ang = 6.2831853071795864769f * (float)t / (float)D_CBP;
    tab[t] = make_float2(__cosf(ang), __sinf(ang));
  }
  if (t < NF) zbias[t] = 0.f;
}

// C1t/C2t [NF][128] bf16:  row m (k=m>>1): even m -> s_i cos(2π k h_i/2048),
// odd m -> -s_i sin(...).  m >= 2050 -> 0 (pad).
__global__ __launch_bounds__(256) void gen_C(
    const float2* __restrict__ tab,
    const int* __restrict__ h1, const float* __restrict__ s1,
    const int* __restrict__ h2, const float* __restrict__ s2,
    u16* __restrict__ C1t, u16* __restrict__ C2t)
{
  const int id = blockIdx.x * 256 + threadIdx.x;   // [0, NF*128)
  if (id >= NF * H3_DIM) return;
  const int m = id >> 7, i = id & 127;
  const int k = m >> 1;
  float v1 = 0.f, v2 = 0.f;
  if (m < 2 * (D_CBP / 2 + 1)) {                   // m < 2050
    const float2 c1 = tab[(k * h1[i]) & (D_CBP - 1)];
    const float2 c2 = tab[(k * h2[i]) & (D_CBP - 1)];
    v1 = (m & 1) ? -s1[i] * c1.y : s1[i] * c1.x;
    v2 = (m & 1) ? -s2[i] * c2.y : s2[i] * c2.x;
  }
  C1t[id] = f2b(v1);
  C2t[id] = f2b(v2);
}

// Tt [NF][2048] bf16: row m (k=m>>1): even -> w_k cos(2π kq/2048)/2048,
// odd -> -w_k sin(...)/2048.  8 q per thread.
__global__ __launch_bounds__(256) void gen_T(
    const float2* __restrict__ tab, u16* __restrict__ Tt)
{
  const int id = blockIdx.x * 256 + threadIdx.x;   // [0, NF*256)
  const int m = id >> 8, q0 = (id & 255) * 8;
  const int k = m >> 1;
  const float sc = ((k == 0) || (k == D_CBP / 2)) ? (1.f / D_CBP) : (2.f / D_CBP);
  __align__(16) u16 o[8];
#pragma unroll
  for (int j = 0; j < 8; ++j) {
    float v = 0.f;
    if (m < 2 * (D_CBP / 2 + 1)) {
      const float2 cs = tab[(k * (q0 + j)) & (D_CBP - 1)];
      v = (m & 1) ? -sc * cs.y : sc * cs.x;
    }
    o[j] = f2b(v);
  }
  *(v8s*)&Tt[(size_t)m * D_CBP + q0] = *(v8s*)o;
}

// ---------------------------------------------------------------------------
// Head: logits = Z[B,1024](bf16) @ Wc2[1024,10] + bc2; softmax -> fp32 out.
// ---------------------------------------------------------------------------
__global__ __launch_bounds__(256) void head_softmax(
    const u16* __restrict__ Z, const float* __restrict__ Wc2,
    const float* __restrict__ bc2, float* __restrict__ out)
{
  const int row  = blockIdx.x * 4 + (threadIdx.x >> 6);
  const int lane = threadIdx.x & 63;

  float acc[CLASSES];
#pragma unroll
  for (int c = 0; c < CLASSES; ++c) acc[c] = 0.f;

  const u16* z = Z + (size_t)row * H_C;
  for (int k = lane; k < H_C; k += 64) {
    const float zv = b2f(z[k]);
    const float* w = Wc2 + (size_t)k * CLASSES;
#pragma unroll
    for (int c = 0; c < CLASSES; ++c) acc[c] += zv * w[c];
  }
#pragma unroll
  for (int c = 0; c < CLASSES; ++c) {
#pragma unroll
    for (int off = 32; off > 0; off >>= 1)
      acc[c] += __shfl_down(acc[c], off);
  }
  if (lane == 0) {
    float l[CLASSES], mx = -1e30f;
#pragma unroll
    for (int c = 0; c < CLASSES; ++c) { l[c] = acc[c] + bc2[c]; mx = fmaxf(mx, l[c]); }
    float s = 0.f;
#pragma unroll
    for (int c = 0; c < CLASSES; ++c) { l[c] = __expf(l[c] - mx); s += l[c]; }
    const float inv = 1.f / s;
#pragma unroll
    for (int c = 0; c < CLASSES; ++c) out[(size_t)row * CLASSES + c] = l[c] * inv;
  }
}

// ---------------------------------------------------------------------------
// Launcher.  Workspace map (MB = 1<<20), full-batch, peak < 128 MiB:
//   Xb   @ 0..64     [2B,1024] bf16      (cast -> G1; dead after G1)
//   Tt   @ 0..8.5    [2176,2048] bf16    (gen_T after G1 -> FWt gemm)
//   FWt  @ 8.5..12.75 [1024,2176] bf16
//   F1   @ 13..81    [16384,2176] bf16   (F1 gemm -> F2-fused RMW -> G4')
//   E1b  @ 64..96    (G1 -> G2; overlap with F1 tail is dead by F1-write)
//   Zb   @ 81..113   (G4' -> head; over dead E2b)
//   E2b  @ 96..112   (G2 -> G3)
//   E3b  @ 113..121  [2B,128] bf16       (G3 -> F gemms)
//   W1t @121  W2t @122  W3t @122.25  Wc1t @122.5..126.5
//   C1t @126.5  C2t @127.0625  tab @127.625  zbias @127.65
// ---------------------------------------------------------------------------
extern "C" void kernel_launch(void* const* d_in, const int* in_sizes, int n_in,
                              void* d_out, int out_size, void* d_ws, size_t ws_size,
                              hipStream_t stream) {
  const float* X       = (const float*)d_in[0];
  const float* Centers = (const float*)d_in[1];
  const float* W1      = (const float*)d_in[2];
  const float* b1      = (const float*)d_in[3];
  const float* W2      = (const float*)d_in[4];
  const float* b2      = (const float*)d_in[5];
  const float* W3      = (const float*)d_in[6];
  const float* b3      = (const float*)d_in[7];
  const int*   h1      = (const int*)d_in[8];
  const float* s1      = (const float*)d_in[9];
  const int*   h2      = (const int*)d_in[10];
  const float* s2      = (const float*)d_in[11];
  const float* Wc1     = (const float*)d_in[12];
  const float* bc1     = (const float*)d_in[13];
  const float* Wc2     = (const float*)d_in[14];
  const float* bc2     = (const float*)d_in[15];
  float* out = (float*)d_out;

  char* ws = (char*)d_ws;
  const size_t MB = 1u << 20;
  const size_t KB = 1u << 10;
  u16*    Xb    = (u16*)(ws);
  u16*    Tt    = (u16*)(ws);                       // after G1
  u16*    FWt   = (u16*)(ws + 8 * MB + 512 * KB);
  u16*    F1    = (u16*)(ws + 13 * MB);
  u16*    E1b   = (u16*)(ws + 64 * MB);
  u16*    Zb    = (u16*)(ws + 81 * MB);
  u16*    E2b   = (u16*)(ws + 96 * MB);
  u16*    E3b   = (u16*)(ws + 113 * MB);
  u16*    W1t   = (u16*)(ws + 121 * MB);
  u16*    W2t   = (u16*)(ws + 122 * MB);
  u16*    W3t   = (u16*)(ws + 122 * MB + 256 * KB);
  u16*    Wc1t  = (u16*)(ws + 122 * MB + 512 * KB);
  u16*    C1t   = (u16*)(ws + 126 * MB + 512 * KB);
  u16*    C2t   = (u16*)(ws + 127 * MB + 64 * KB);
  float2* tab   = (float2*)(ws + 127 * MB + 640 * KB);
  float*  zbias = (float*)(ws + 127 * MB + 672 * KB);

  const dim3 blk(256);

  // casts: X, Centers -> Xb rows [0..B), [B..2B)
  cast2_bf16<<<dim3(2 * CAST_NB), blk, 0, stream>>>(X, Centers, Xb);

  // weight transposes
  transpose_cast4<<<dim3(D_CBP / 32, H_C / 32, 4), blk, 0, stream>>>(
      W1, W1t, W2, W2t, W3, W3t, Wc1, Wc1t);

  // twiddle table + zero bias; C1t/C2t (need only h/s inputs)
  setup_tab<<<dim3(9), blk, 0, stream>>>(tab, zbias);
  gen_C<<<dim3(NF * H3_DIM / 256), blk, 0, stream>>>(tab, h1, s1, h2, s2, C1t, C2t);

  // G1 (frees Xb region for Tt/FWt)
  gemm_bf16_t<0><<<dim3(H1_DIM / 128, 2 * BATCH / 128), blk, 0, stream>>>(
      Xb, W1t, b1, E1b, 2 * BATCH, H1_DIM, D_IN, SLOPE);

  // Tt and FWt = Wc1t @ Tt^T   [1024][2176]
  gen_T<<<dim3(NF), blk, 0, stream>>>(tab, Tt);
  gemm_bf16_t<0><<<dim3(NF / 128, H_C / 128), blk, 0, stream>>>(
      Wc1t, Tt, zbias, FWt, H_C, NF, D_CBP, 1.0f);

  // G2, G3
  gemm_bf16_t<0><<<dim3(H2_DIM / 128, 2 * BATCH / 128), blk, 0, stream>>>(
      E1b, W2t, b2, E2b, 2 * BATCH, H2_DIM, H1_DIM, SLOPE);
  gemm_bf16_t<0><<<dim3(H3_DIM / 128, 2 * BATCH / 128), blk, 0, stream>>>(
      E2b, W3t, b3, E3b, 2 * BATCH, H3_DIM, H2_DIM, SLOPE);

  // F1 = E3x @ C1   [16384][2176], K=128
  gemm_bf16_t<0><<<dim3(NF / 128, BATCH / 128), blk, 0, stream>>>(
      E3b, C1t, zbias, F1, BATCH, NF, H3_DIM, 1.0f);
  // F1 <- F1 (.)complex (E3c @ C2)   [fused epilogue, in place]
  gemm_bf16_t<1><<<dim3(NF / 128, BATCH / 128), blk, 0, stream>>>(
      E3b + (size_t)BATCH * H3_DIM, C2t, zbias, F1, BATCH, NF, H3_DIM, 1.0f);
  // Z = lrelu(P @ FWt^T + bc1)   [16384][1024], K=2176
  gemm_bf16_t<0><<<dim3(H_C / 128, BATCH / 128), blk, 0, stream>>>(
      F1, FWt, bc1, Zb, BATCH, H_C, NF, SLOPE);

  // head
  head_softmax<<<dim3(BATCH / 4), blk, 0, stream>>>(Zb, Wc2, bc2, out);
}

// Round 6
// 518.133 us; speedup vs baseline: 1.0897x; 1.0358x over previous
//
#include <hip/hip_runtime.h>
#include <hip/hip_bf16.h>
#include <math.h>

// ---------------------------------------------------------------------------
// Dims (fixed per reference)
// ---------------------------------------------------------------------------
#define BATCH   16384
#define D_IN    1024
#define H1_DIM  512
#define H2_DIM  256
#define H3_DIM  128
#define D_CBP   2048
#define H_C     1024
#define CLASSES 10
#define SLOPE   0.2f

// FFT-domain dims: rfft bins k = 0..1024 (1025), padded to 1088 complex
// -> 2176 real columns (Re,Im interleaved), = 17 tiles of 128.
#define NK_PAD  1088
#define NF      (2 * NK_PAD)   // 2176

typedef short v8s __attribute__((ext_vector_type(8)));
typedef float v4f __attribute__((ext_vector_type(4)));
typedef unsigned short u16;
typedef unsigned int   u32;

__device__ __forceinline__ float b2f(unsigned short u) {
  return __uint_as_float(((unsigned)u) << 16);
}
__device__ __forceinline__ u16 f2b(float f) {
  __hip_bfloat16 h = __float2bfloat16(f);   // RNE
  return __builtin_bit_cast(unsigned short, h);
}

// async 16B global->LDS (direct-to-shared DMA). LDS dest = wave-uniform base
// + lane*16 -> LDS layout is forced packed lane-order.
__device__ __forceinline__ void g2l16(const void* g, void* l) {
  __builtin_amdgcn_global_load_lds(
      (const __attribute__((address_space(1))) void*)g,
      (__attribute__((address_space(3))) void*)l, 16, 0, 0);
}

// ---------------------------------------------------------------------------
// bf16 MFMA GEMM: C[M,N] = epilogue(A[M,K] @ Bt[N,K]^T).
// Tile 128x128, BK=32, 256 threads (4 waves, 2x2 of 64x64), 16 MFMA/wave/step.
// Granule rotation swizzle applied at the GLOBAL address so both A- and
// B-fragment ds_read_b128 are exactly 2 lanes/bank (free).
// Bijective XCD-aware block swizzle (T1, r2: −17 µs verified).
//
// r5: 3-buffer / prefetch-depth-2 K-loop with COUNTED vmcnt (T3+T4).
// r4 post-mortem: __syncthreads' vmcnt(0) drain made every K-step eat the
// full ~900-cyc HBM latency (MfmaUtil 25%, HBM 10% -> latency-bound).
// Now: stage(t+2) -> vmcnt(8) [waits only step-t loads, issued 2 steps ago]
// -> s_barrier -> ds_read+MFMA -> lgkmcnt(0) -> s_barrier [buffer-reuse WAR:
// earliest rewrite of buf cb is 2 barriers later -> conservative by a step].
// vmcnt target = 4 loads x steps-in-flight (8/4/0 at tail). All waits asm
// volatile + "memory" so LDS ops can't cross; control flow wave-uniform so
// raw s_barrier is safe.
//
// CMUL=0: C = lrelu_slope(acc + bias).
// CMUL=1: C holds F1 (Re,Im interleaved cols); acc is F2. In-place complex
//         product via lane^1 shfl_xor partner. C <- F1 (.) F2.
// ---------------------------------------------------------------------------
template <int CMUL>
__global__ __launch_bounds__(256) void gemm_bf16_t(
    const u16* __restrict__ A,   // [M][K] bf16
    const u16* __restrict__ Bt,  // [N][K] bf16  (weights pre-transposed)
    const float* __restrict__ bias,
    u16* __restrict__ C,         // [M][N] bf16
    int M, int N, int K, float slope)
{
  __shared__ __align__(16) short Asb[3][128 * 32];   // 24 KiB
  __shared__ __align__(16) short Bsb[3][128 * 32];   // 24 KiB

  const int tid  = threadIdx.x;
  const int wave = tid >> 6, lane = tid & 63;
  const int wm = wave >> 1, wn = wave & 1;
  const int u = lane & 15, quad = lane >> 4;

  // XCD swizzle: contiguous panel per XCD (bijective iff nwg % 8 == 0).
  const int nwg = gridDim.x * gridDim.y;
  int id = blockIdx.y * gridDim.x + blockIdx.x;
  if ((nwg & 7) == 0) id = (id & 7) * (nwg >> 3) + (id >> 3);
  const int m0 = (id / gridDim.x) * 128, n0 = (id % gridDim.x) * 128;

  const int g_log = ((lane & 3) - ((lane >> 3) & 3)) & 3;
  const int srow  = wave * 32 + (lane >> 2);
  const u16* gA0 = A  + (size_t)(m0 + srow)      * K + g_log * 8;
  const u16* gA1 = A  + (size_t)(m0 + srow + 16) * K + g_log * 8;
  const u16* gB0 = Bt + (size_t)(n0 + srow)      * K + g_log * 8;
  const u16* gB1 = Bt + (size_t)(n0 + srow + 16) * K + g_log * 8;
  const int lo0 = (wave * 32)      * 32;
  const int lo1 = (wave * 32 + 16) * 32;

  const int gran = (quad + (u >> 1)) & 3;
  int offA[4], offB[4];
#pragma unroll
  for (int i = 0; i < 4; ++i) {
    offA[i] = (wm * 64 + i * 16 + u) * 32 + gran * 8;
    offB[i] = (wn * 64 + i * 16 + u) * 32 + gran * 8;
  }

  v4f acc[4][4];
#pragma unroll
  for (int i = 0; i < 4; ++i)
#pragma unroll
    for (int j = 0; j < 4; ++j) acc[i][j] = (v4f){0.f, 0.f, 0.f, 0.f};

  const int nsteps = K >> 5;   // BK=32

  auto stage = [&](int s, int buf) {
    const int k0 = s * 32;
    g2l16(gA0 + k0, &Asb[buf][lo0]);
    g2l16(gA1 + k0, &Asb[buf][lo1]);
    g2l16(gB0 + k0, &Bsb[buf][lo0]);
    g2l16(gB1 + k0, &Bsb[buf][lo1]);
  };

  // prologue: fill pipeline 2 deep
  stage(0, 0);
  if (nsteps > 1) stage(1, 1);

  int cb = 0, sb = 2;   // compute-buffer, stage-buffer (wrap mod 3)
  for (int t = 0; t < nsteps; ++t) {
    if (t + 2 < nsteps) stage(t + 2, sb);

    // wait for step-t loads only: 4 loads per in-flight future step remain
    const int rem = nsteps - 1 - t;
    if (rem >= 2)      asm volatile("s_waitcnt vmcnt(8)" ::: "memory");
    else if (rem == 1) asm volatile("s_waitcnt vmcnt(4)" ::: "memory");
    else               asm volatile("s_waitcnt vmcnt(0)" ::: "memory");
    __builtin_amdgcn_s_barrier();

    v8s a[4], b[4];
#pragma unroll
    for (int i = 0; i < 4; ++i) a[i] = *(const v8s*)&Asb[cb][offA[i]];
#pragma unroll
    for (int j = 0; j < 4; ++j) b[j] = *(const v8s*)&Bsb[cb][offB[j]];
#pragma unroll
    for (int i = 0; i < 4; ++i)
#pragma unroll
      for (int j = 0; j < 4; ++j)
        acc[i][j] = __builtin_amdgcn_mfma_f32_16x16x32_bf16(a[i], b[j], acc[i][j], 0, 0, 0);

    // buffer-reuse WAR fence: a later iteration's stage overwrites buf[cb]
    asm volatile("s_waitcnt lgkmcnt(0)" ::: "memory");
    __builtin_amdgcn_s_barrier();

    cb = (cb == 2) ? 0 : cb + 1;
    sb = (sb == 2) ? 0 : sb + 1;
  }

  // C/D layout (m89-verified): col = lane&15, row = quad*4 + reg
  if (CMUL == 0) {
    float bcol[4];
#pragma unroll
    for (int j = 0; j < 4; ++j) bcol[j] = bias[n0 + wn * 64 + j * 16 + u];
#pragma unroll
    for (int i = 0; i < 4; ++i)
#pragma unroll
      for (int r = 0; r < 4; ++r) {
        const size_t ro = (size_t)(m0 + wm * 64 + i * 16 + quad * 4 + r) * N
                          + n0 + wn * 64 + u;
#pragma unroll
        for (int j = 0; j < 4; ++j) {
          float v = acc[i][j][r] + bcol[j];
          v = v >= 0.f ? v : slope * v;
          C[ro + j * 16] = f2b(v);
        }
      }
  } else {
    // In-place complex product: even col (u even) = Re, odd = Im.
    const bool im = (u & 1);
#pragma unroll
    for (int i = 0; i < 4; ++i)
#pragma unroll
      for (int r = 0; r < 4; ++r) {
        const size_t ro = (size_t)(m0 + wm * 64 + i * 16 + quad * 4 + r) * N
                          + n0 + wn * 64 + u;
#pragma unroll
        for (int j = 0; j < 4; ++j) {
          const float f2v = acc[i][j][r];
          const float f2p = __shfl_xor(f2v, 1, 64);
          const float f1v = b2f(C[ro + j * 16]);
          const float f1p = __shfl_xor(f1v, 1, 64);
          // even lane: f1r*f2r - f1i*f2i ; odd lane: f1r*f2i + f1i*f2r
          const float outv = im ? (f1p * f2v + f1v * f2p)
                                : (f1v * f2v - f1p * f2p);
          C[ro + j * 16] = f2b(outv);
        }
      }
  }
}

// ---------------------------------------------------------------------------
// cast fp32 -> bf16, two sources in one launch (X then Centers)
// ---------------------------------------------------------------------------
#define CAST_NB (BATCH * D_IN / 4 / 256)   // blocks per source
__global__ __launch_bounds__(256) void cast2_bf16(
    const float* __restrict__ srcA, const float* __restrict__ srcB,
    u16* __restrict__ dst)
{
  const int bx = blockIdx.x;
  const float* s = (bx < CAST_NB) ? srcA : srcB;
  const int i = ((bx < CAST_NB) ? bx : bx - CAST_NB) * 256 + threadIdx.x;
  u16* d = dst + ((bx < CAST_NB) ? 0 : (size_t)BATCH * D_IN);
  const float4 v = ((const float4*)s)[i];
  __align__(8) u16 o[4] = {f2b(v.x), f2b(v.y), f2b(v.z), f2b(v.w)};
  *(uint2*)(d + (size_t)i * 4) = *(uint2*)o;
}

// ---------------------------------------------------------------------------
// transpose + cast, all 4 weights in one launch (z selects the matrix):
// W[K][N] fp32 -> Wt[N][K] bf16.  32x32 tiles via LDS.
// ---------------------------------------------------------------------------
__global__ __launch_bounds__(256) void transpose_cast4(
    const float* __restrict__ W1, u16* __restrict__ W1t,
    const float* __restrict__ W2, u16* __restrict__ W2t,
    const float* __restrict__ W3, u16* __restrict__ W3t,
    const float* __restrict__ Wc1, u16* __restrict__ Wc1t)
{
  __shared__ float tile[32][33];
  const int z = blockIdx.z;
  const float* W; u16* Wt; int K, N;
  if      (z == 0) { W = W1;  Wt = W1t;  K = D_IN;   N = H1_DIM; }
  else if (z == 1) { W = W2;  Wt = W2t;  K = H1_DIM; N = H2_DIM; }
  else if (z == 2) { W = W3;  Wt = W3t;  K = H2_DIM; N = H3_DIM; }
  else             { W = Wc1; Wt = Wc1t; K = D_CBP;  N = H_C;    }
  const int k0 = blockIdx.x * 32, n0 = blockIdx.y * 32;
  if (k0 >= K || n0 >= N) return;
  const int tx = threadIdx.x & 31, ty = threadIdx.x >> 5;
#pragma unroll
  for (int s = 0; s < 4; ++s) {
    const int k = ty * 4 + s;
    tile[k][tx] = W[(size_t)(k0 + k) * N + n0 + tx];
  }
  __syncthreads();
#pragma unroll
  for (int s = 0; s < 4; ++s) {
    const int n = ty * 4 + s;
    Wt[(size_t)(n0 + n) * K + k0 + tx] = f2b(tile[tx][n]);
  }
}

// ---------------------------------------------------------------------------
// FFT-domain CBP.  Identity:
//   cbp = irfft(F1 .* F2),  F1[k] = sum_i a_i e^{-2πi k h1_i/2048}  (K=128)
//   cbp @ Wc1 = sum_k w_k/N * (Pr[k] Gr[k,c] - Pi[k] Gi[k,c]),
//     G[k,c] = sum_q Wc1[q,c] e^{+2πi qk/N},  w_0 = w_1024 = 1 else 2.
// Chain: F1 = E3x @ C1;  F1 <- F1 (.) (E3c @ C2)  [fused epilogue];
//        Z = lrelu(F1 @ FWt^T + bc1),  FWt = Wc1t @ Tt^T.
// [r1: random-bank LDS atomics ~198 cyc/wave-op — never on critical path.
//  r3: half-split G4' = 2 blk/CU = 589 TF; r4: full-batch same per-block
//  speed -> K-loop is HBM-latency-bound, not occupancy-bound.]
// ---------------------------------------------------------------------------

// tab[t] = (cos, sin)(2π t / 2048);  zbias = zeros (bias for slope-1 GEMMs)
__global__ __launch_bounds__(256) void setup_tab(
    float2* __restrict__ tab, float* __restrict__ zbias)
{
  const int t = blockIdx.x * 256 + threadIdx.x;
  if (t < D_CBP) {
    const float ang = 6.2831853071795864769f * (float)t / (float)D_CBP;
    tab[t] = make_float2(__cosf(ang), __sinf(ang));
  }
  if (t < NF) zbias[t] = 0.f;
}

// C1t/C2t [NF][128] bf16:  row m (k=m>>1): even m -> s_i cos(2π k h_i/2048),
// odd m -> -s_i sin(...).  m >= 2050 -> 0 (pad).
__global__ __launch_bounds__(256) void gen_C(
    const float2* __restrict__ tab,
    const int* __restrict__ h1, const float* __restrict__ s1,
    const int* __restrict__ h2, const float* __restrict__ s2,
    u16* __restrict__ C1t, u16* __restrict__ C2t)
{
  const int id = blockIdx.x * 256 + threadIdx.x;   // [0, NF*128)
  if (id >= NF * H3_DIM) return;
  const int m = id >> 7, i = id & 127;
  const int k = m >> 1;
  float v1 = 0.f, v2 = 0.f;
  if (m < 2 * (D_CBP / 2 + 1)) {                   // m < 2050
    const float2 c1 = tab[(k * h1[i]) & (D_CBP - 1)];
    const float2 c2 = tab[(k * h2[i]) & (D_CBP - 1)];
    v1 = (m & 1) ? -s1[i] * c1.y : s1[i] * c1.x;
    v2 = (m & 1) ? -s2[i] * c2.y : s2[i] * c2.x;
  }
  C1t[id] = f2b(v1);
  C2t[id] = f2b(v2);
}

// Tt [NF][2048] bf16: row m (k=m>>1): even -> w_k cos(2π kq/2048)/2048,
// odd -> -w_k sin(...)/2048.  8 q per thread.
__global__ __launch_bounds__(256) void gen_T(
    const float2* __restrict__ tab, u16* __restrict__ Tt)
{
  const int id = blockIdx.x * 256 + threadIdx.x;   // [0, NF*256)
  const int m = id >> 8, q0 = (id & 255) * 8;
  const int k = m >> 1;
  const float sc = ((k == 0) || (k == D_CBP / 2)) ? (1.f / D_CBP) : (2.f / D_CBP);
  __align__(16) u16 o[8];
#pragma unroll
  for (int j = 0; j < 8; ++j) {
    float v = 0.f;
    if (m < 2 * (D_CBP / 2 + 1)) {
      const float2 cs = tab[(k * (q0 + j)) & (D_CBP - 1)];
      v = (m & 1) ? -sc * cs.y : sc * cs.x;
    }
    o[j] = f2b(v);
  }
  *(v8s*)&Tt[(size_t)m * D_CBP + q0] = *(v8s*)o;
}

// ---------------------------------------------------------------------------
// Head: logits = Z[B,1024](bf16) @ Wc2[1024,10] + bc2; softmax -> fp32 out.
// ---------------------------------------------------------------------------
__global__ __launch_bounds__(256) void head_softmax(
    const u16* __restrict__ Z, const float* __restrict__ Wc2,
    const float* __restrict__ bc2, float* __restrict__ out)
{
  const int row  = blockIdx.x * 4 + (threadIdx.x >> 6);
  const int lane = threadIdx.x & 63;

  float acc[CLASSES];
#pragma unroll
  for (int c = 0; c < CLASSES; ++c) acc[c] = 0.f;

  const u16* z = Z + (size_t)row * H_C;
  for (int k = lane; k < H_C; k += 64) {
    const float zv = b2f(z[k]);
    const float* w = Wc2 + (size_t)k * CLASSES;
#pragma unroll
    for (int c = 0; c < CLASSES; ++c) acc[c] += zv * w[c];
  }
#pragma unroll
  for (int c = 0; c < CLASSES; ++c) {
#pragma unroll
    for (int off = 32; off > 0; off >>= 1)
      acc[c] += __shfl_down(acc[c], off);
  }
  if (lane == 0) {
    float l[CLASSES], mx = -1e30f;
#pragma unroll
    for (int c = 0; c < CLASSES; ++c) { l[c] = acc[c] + bc2[c]; mx = fmaxf(mx, l[c]); }
    float s = 0.f;
#pragma unroll
    for (int c = 0; c < CLASSES; ++c) { l[c] = __expf(l[c] - mx); s += l[c]; }
    const float inv = 1.f / s;
#pragma unroll
    for (int c = 0; c < CLASSES; ++c) out[(size_t)row * CLASSES + c] = l[c] * inv;
  }
}

// ---------------------------------------------------------------------------
// Launcher.  Workspace map (MB = 1<<20), full-batch, peak < 128 MiB:
//   Xb   @ 0..64     [2B,1024] bf16      (cast -> G1; dead after G1)
//   Tt   @ 0..8.5    [2176,2048] bf16    (gen_T after G1 -> FWt gemm)
//   FWt  @ 8.5..12.75 [1024,2176] bf16
//   F1   @ 13..81    [16384,2176] bf16   (F1 gemm -> F2-fused RMW -> G4')
//   E1b  @ 64..96    (G1 -> G2; overlap with F1 tail is dead by F1-write)
//   Zb   @ 81..113   (G4' -> head; over dead E2b)
//   E2b  @ 96..112   (G2 -> G3)
//   E3b  @ 113..121  [2B,128] bf16       (G3 -> F gemms)
//   W1t @121  W2t @122  W3t @122.25  Wc1t @122.5..126.5
//   C1t @126.5  C2t @127.0625  tab @127.625  zbias @127.65
// ---------------------------------------------------------------------------
extern "C" void kernel_launch(void* const* d_in, const int* in_sizes, int n_in,
                              void* d_out, int out_size, void* d_ws, size_t ws_size,
                              hipStream_t stream) {
  const float* X       = (const float*)d_in[0];
  const float* Centers = (const float*)d_in[1];
  const float* W1      = (const float*)d_in[2];
  const float* b1      = (const float*)d_in[3];
  const float* W2      = (const float*)d_in[4];
  const float* b2      = (const float*)d_in[5];
  const float* W3      = (const float*)d_in[6];
  const float* b3      = (const float*)d_in[7];
  const int*   h1      = (const int*)d_in[8];
  const float* s1      = (const float*)d_in[9];
  const int*   h2      = (const int*)d_in[10];
  const float* s2      = (const float*)d_in[11];
  const float* Wc1     = (const float*)d_in[12];
  const float* bc1     = (const float*)d_in[13];
  const float* Wc2     = (const float*)d_in[14];
  const float* bc2     = (const float*)d_in[15];
  float* out = (float*)d_out;

  char* ws = (char*)d_ws;
  const size_t MB = 1u << 20;
  const size_t KB = 1u << 10;
  u16*    Xb    = (u16*)(ws);
  u16*    Tt    = (u16*)(ws);                       // after G1
  u16*    FWt   = (u16*)(ws + 8 * MB + 512 * KB);
  u16*    F1    = (u16*)(ws + 13 * MB);
  u16*    E1b   = (u16*)(ws + 64 * MB);
  u16*    Zb    = (u16*)(ws + 81 * MB);
  u16*    E2b   = (u16*)(ws + 96 * MB);
  u16*    E3b   = (u16*)(ws + 113 * MB);
  u16*    W1t   = (u16*)(ws + 121 * MB);
  u16*    W2t   = (u16*)(ws + 122 * MB);
  u16*    W3t   = (u16*)(ws + 122 * MB + 256 * KB);
  u16*    Wc1t  = (u16*)(ws + 122 * MB + 512 * KB);
  u16*    C1t   = (u16*)(ws + 126 * MB + 512 * KB);
  u16*    C2t   = (u16*)(ws + 127 * MB + 64 * KB);
  float2* tab   = (float2*)(ws + 127 * MB + 640 * KB);
  float*  zbias = (float*)(ws + 127 * MB + 672 * KB);

  const dim3 blk(256);

  // casts: X, Centers -> Xb rows [0..B), [B..2B)
  cast2_bf16<<<dim3(2 * CAST_NB), blk, 0, stream>>>(X, Centers, Xb);

  // weight transposes
  transpose_cast4<<<dim3(D_CBP / 32, H_C / 32, 4), blk, 0, stream>>>(
      W1, W1t, W2, W2t, W3, W3t, Wc1, Wc1t);

  // twiddle table + zero bias; C1t/C2t (need only h/s inputs)
  setup_tab<<<dim3(9), blk, 0, stream>>>(tab, zbias);
  gen_C<<<dim3(NF * H3_DIM / 256), blk, 0, stream>>>(tab, h1, s1, h2, s2, C1t, C2t);

  // G1 (frees Xb region for Tt/FWt)
  gemm_bf16_t<0><<<dim3(H1_DIM / 128, 2 * BATCH / 128), blk, 0, stream>>>(
      Xb, W1t, b1, E1b, 2 * BATCH, H1_DIM, D_IN, SLOPE);

  // Tt and FWt = Wc1t @ Tt^T   [1024][2176]
  gen_T<<<dim3(NF), blk, 0, stream>>>(tab, Tt);
  gemm_bf16_t<0><<<dim3(NF / 128, H_C / 128), blk, 0, stream>>>(
      Wc1t, Tt, zbias, FWt, H_C, NF, D_CBP, 1.0f);

  // G2, G3
  gemm_bf16_t<0><<<dim3(H2_DIM / 128, 2 * BATCH / 128), blk, 0, stream>>>(
      E1b, W2t, b2, E2b, 2 * BATCH, H2_DIM, H1_DIM, SLOPE);
  gemm_bf16_t<0><<<dim3(H3_DIM / 128, 2 * BATCH / 128), blk, 0, stream>>>(
      E2b, W3t, b3, E3b, 2 * BATCH, H3_DIM, H2_DIM, SLOPE);

  // F1 = E3x @ C1   [16384][2176], K=128
  gemm_bf16_t<0><<<dim3(NF / 128, BATCH / 128), blk, 0, stream>>>(
      E3b, C1t, zbias, F1, BATCH, NF, H3_DIM, 1.0f);
  // F1 <- F1 (.)complex (E3c @ C2)   [fused epilogue, in place]
  gemm_bf16_t<1><<<dim3(NF / 128, BATCH / 128), blk, 0, stream>>>(
      E3b + (size_t)BATCH * H3_DIM, C2t, zbias, F1, BATCH, NF, H3_DIM, 1.0f);
  // Z = lrelu(P @ FWt^T + bc1)   [16384][1024], K=2176
  gemm_bf16_t<0><<<dim3(H_C / 128, BATCH / 128), blk, 0, stream>>>(
      F1, FWt, bc1, Zb, BATCH, H_C, NF, SLOPE);

  // head
  head_softmax<<<dim3(BATCH / 4), blk, 0, stream>>>(Zb, Wc2, bc2, out);
}

// Round 7
// 517.127 us; speedup vs baseline: 1.0918x; 1.0019x over previous
//
#include <hip/hip_runtime.h>
#include <hip/hip_bf16.h>
#include <math.h>

// ---------------------------------------------------------------------------
// Dims (fixed per reference)
// ---------------------------------------------------------------------------
#define BATCH   16384
#define D_IN    1024
#define H1_DIM  512
#define H2_DIM  256
#define H3_DIM  128
#define D_CBP   2048
#define H_C     1024
#define CLASSES 10
#define SLOPE   0.2f

// FFT-domain dims: rfft bins k = 0..1024 (1025), padded to 1088 complex
// -> 2176 real columns (Re,Im interleaved), = 17 tiles of 128.
#define NK_PAD  1088
#define NF      (2 * NK_PAD)   // 2176

typedef short v8s __attribute__((ext_vector_type(8)));
typedef float v4f __attribute__((ext_vector_type(4)));
typedef unsigned short u16;
typedef unsigned int   u32;

__device__ __forceinline__ float b2f(unsigned short u) {
  return __uint_as_float(((unsigned)u) << 16);
}
__device__ __forceinline__ u16 f2b(float f) {
  __hip_bfloat16 h = __float2bfloat16(f);   // RNE
  return __builtin_bit_cast(unsigned short, h);
}

// async 16B global->LDS (direct-to-shared DMA). LDS dest = wave-uniform base
// + lane*16 -> LDS layout is forced packed lane-order.
__device__ __forceinline__ void g2l16(const void* g, void* l) {
  __builtin_amdgcn_global_load_lds(
      (const __attribute__((address_space(1))) void*)g,
      (__attribute__((address_space(3))) void*)l, 16, 0, 0);
}

// ---------------------------------------------------------------------------
// bf16 MFMA GEMM: C[M,N] = epilogue(A[M,K] @ Bt[N,K]^T).
// Tile 128x128, BK=32, 256 threads (4 waves, 2x2 of 64x64), 16 MFMA/wave/step.
// Granule rotation swizzle applied at the GLOBAL address so both A- and
// B-fragment ds_read_b128 are exactly 2 lanes/bank (free).
// Bijective XCD-aware block swizzle (T1, r2: −17 µs verified).
//
// r6: 5-buffer ring / prefetch-depth-3 / ONE barrier per K-step.
// r5 post-mortem: 2 barriers + lgkmcnt(0) drain per 16-MFMA step left
// MfmaUtil at 27% with no pipe saturated (DS 39%, HBM 12%) -> sync-bound.
// WAR proof for dropping barrier #2: stage at iter t writes buf (t+3)%5,
// last read at iter t-2; every wave's ds_reads(t-2) complete before its
// MFMAs(t-2) (compiler lgkmcnt), which precede barrier(t-1) in program
// order; stage(t) is issued after barrier(t-1) rendezvous -> race-free.
// Depth-3 prefetch covers ~900-cyc HBM latency for first-reader blocks.
// vmcnt target = 4 loads x steps-in-flight (12/8/4/0 at tail). Cost:
// LDS 80 KiB -> 2 blocks/CU.
//
// CMUL=0: C = lrelu_slope(acc + bias).
// CMUL=1: C holds F1 (Re,Im interleaved cols); acc is F2. In-place complex
//         product via lane^1 shfl_xor partner. C <- F1 (.) F2.
// ---------------------------------------------------------------------------
template <int CMUL>
__global__ __launch_bounds__(256) void gemm_bf16_t(
    const u16* __restrict__ A,   // [M][K] bf16
    const u16* __restrict__ Bt,  // [N][K] bf16  (weights pre-transposed)
    const float* __restrict__ bias,
    u16* __restrict__ C,         // [M][N] bf16
    int M, int N, int K, float slope)
{
  __shared__ __align__(16) short Asb[5][128 * 32];   // 40 KiB
  __shared__ __align__(16) short Bsb[5][128 * 32];   // 40 KiB

  const int tid  = threadIdx.x;
  const int wave = tid >> 6, lane = tid & 63;
  const int wm = wave >> 1, wn = wave & 1;
  const int u = lane & 15, quad = lane >> 4;

  // XCD swizzle: contiguous panel per XCD (bijective iff nwg % 8 == 0).
  const int nwg = gridDim.x * gridDim.y;
  int id = blockIdx.y * gridDim.x + blockIdx.x;
  if ((nwg & 7) == 0) id = (id & 7) * (nwg >> 3) + (id >> 3);
  const int m0 = (id / gridDim.x) * 128, n0 = (id % gridDim.x) * 128;

  const int g_log = ((lane & 3) - ((lane >> 3) & 3)) & 3;
  const int srow  = wave * 32 + (lane >> 2);
  const u16* gA0 = A  + (size_t)(m0 + srow)      * K + g_log * 8;
  const u16* gA1 = A  + (size_t)(m0 + srow + 16) * K + g_log * 8;
  const u16* gB0 = Bt + (size_t)(n0 + srow)      * K + g_log * 8;
  const u16* gB1 = Bt + (size_t)(n0 + srow + 16) * K + g_log * 8;
  const int lo0 = (wave * 32)      * 32;
  const int lo1 = (wave * 32 + 16) * 32;

  const int gran = (quad + (u >> 1)) & 3;
  int offA[4], offB[4];
#pragma unroll
  for (int i = 0; i < 4; ++i) {
    offA[i] = (wm * 64 + i * 16 + u) * 32 + gran * 8;
    offB[i] = (wn * 64 + i * 16 + u) * 32 + gran * 8;
  }

  v4f acc[4][4];
#pragma unroll
  for (int i = 0; i < 4; ++i)
#pragma unroll
    for (int j = 0; j < 4; ++j) acc[i][j] = (v4f){0.f, 0.f, 0.f, 0.f};

  const int nsteps = K >> 5;   // BK=32

  auto stage = [&](int s, int buf) {
    const int k0 = s * 32;
    g2l16(gA0 + k0, &Asb[buf][lo0]);
    g2l16(gA1 + k0, &Asb[buf][lo1]);
    g2l16(gB0 + k0, &Bsb[buf][lo0]);
    g2l16(gB1 + k0, &Bsb[buf][lo1]);
  };

  // prologue: fill pipeline 3 deep
  stage(0, 0);
  if (nsteps > 1) stage(1, 1);
  if (nsteps > 2) stage(2, 2);

  int cb = 0, sb = 3;   // compute-buffer, stage-buffer (wrap mod 5)
  for (int t = 0; t < nsteps; ++t) {
    if (t + 3 < nsteps) stage(t + 3, sb);

    // wait for step-t loads only: 4 loads per in-flight future step remain
    const int rem = nsteps - 1 - t;
    if (rem >= 3)      asm volatile("s_waitcnt vmcnt(12)" ::: "memory");
    else if (rem == 2) asm volatile("s_waitcnt vmcnt(8)"  ::: "memory");
    else if (rem == 1) asm volatile("s_waitcnt vmcnt(4)"  ::: "memory");
    else               asm volatile("s_waitcnt vmcnt(0)"  ::: "memory");
    __builtin_amdgcn_s_barrier();
    asm volatile("" ::: "memory");   // pin ds_reads below the barrier

    v8s a[4], b[4];
#pragma unroll
    for (int i = 0; i < 4; ++i) a[i] = *(const v8s*)&Asb[cb][offA[i]];
#pragma unroll
    for (int j = 0; j < 4; ++j) b[j] = *(const v8s*)&Bsb[cb][offB[j]];
#pragma unroll
    for (int i = 0; i < 4; ++i)
#pragma unroll
      for (int j = 0; j < 4; ++j)
        acc[i][j] = __builtin_amdgcn_mfma_f32_16x16x32_bf16(a[i], b[j], acc[i][j], 0, 0, 0);

    cb = (cb == 4) ? 0 : cb + 1;
    sb = (sb == 4) ? 0 : sb + 1;
  }

  // C/D layout (m89-verified): col = lane&15, row = quad*4 + reg
  if (CMUL == 0) {
    float bcol[4];
#pragma unroll
    for (int j = 0; j < 4; ++j) bcol[j] = bias[n0 + wn * 64 + j * 16 + u];
#pragma unroll
    for (int i = 0; i < 4; ++i)
#pragma unroll
      for (int r = 0; r < 4; ++r) {
        const size_t ro = (size_t)(m0 + wm * 64 + i * 16 + quad * 4 + r) * N
                          + n0 + wn * 64 + u;
#pragma unroll
        for (int j = 0; j < 4; ++j) {
          float v = acc[i][j][r] + bcol[j];
          v = v >= 0.f ? v : slope * v;
          C[ro + j * 16] = f2b(v);
        }
      }
  } else {
    // In-place complex product: even col (u even) = Re, odd = Im.
    const bool im = (u & 1);
#pragma unroll
    for (int i = 0; i < 4; ++i)
#pragma unroll
      for (int r = 0; r < 4; ++r) {
        const size_t ro = (size_t)(m0 + wm * 64 + i * 16 + quad * 4 + r) * N
                          + n0 + wn * 64 + u;
#pragma unroll
        for (int j = 0; j < 4; ++j) {
          const float f2v = acc[i][j][r];
          const float f2p = __shfl_xor(f2v, 1, 64);
          const float f1v = b2f(C[ro + j * 16]);
          const float f1p = __shfl_xor(f1v, 1, 64);
          // even lane: f1r*f2r - f1i*f2i ; odd lane: f1r*f2i + f1i*f2r
          const float outv = im ? (f1p * f2v + f1v * f2p)
                                : (f1v * f2v - f1p * f2p);
          C[ro + j * 16] = f2b(outv);
        }
      }
  }
}

// ---------------------------------------------------------------------------
// cast fp32 -> bf16, two sources in one launch (X then Centers)
// ---------------------------------------------------------------------------
#define CAST_NB (BATCH * D_IN / 4 / 256)   // blocks per source
__global__ __launch_bounds__(256) void cast2_bf16(
    const float* __restrict__ srcA, const float* __restrict__ srcB,
    u16* __restrict__ dst)
{
  const int bx = blockIdx.x;
  const float* s = (bx < CAST_NB) ? srcA : srcB;
  const int i = ((bx < CAST_NB) ? bx : bx - CAST_NB) * 256 + threadIdx.x;
  u16* d = dst + ((bx < CAST_NB) ? 0 : (size_t)BATCH * D_IN);
  const float4 v = ((const float4*)s)[i];
  __align__(8) u16 o[4] = {f2b(v.x), f2b(v.y), f2b(v.z), f2b(v.w)};
  *(uint2*)(d + (size_t)i * 4) = *(uint2*)o;
}

// ---------------------------------------------------------------------------
// transpose + cast, all 4 weights in one launch (z selects the matrix):
// W[K][N] fp32 -> Wt[N][K] bf16.  32x32 tiles via LDS.
// ---------------------------------------------------------------------------
__global__ __launch_bounds__(256) void transpose_cast4(
    const float* __restrict__ W1, u16* __restrict__ W1t,
    const float* __restrict__ W2, u16* __restrict__ W2t,
    const float* __restrict__ W3, u16* __restrict__ W3t,
    const float* __restrict__ Wc1, u16* __restrict__ Wc1t)
{
  __shared__ float tile[32][33];
  const int z = blockIdx.z;
  const float* W; u16* Wt; int K, N;
  if      (z == 0) { W = W1;  Wt = W1t;  K = D_IN;   N = H1_DIM; }
  else if (z == 1) { W = W2;  Wt = W2t;  K = H1_DIM; N = H2_DIM; }
  else if (z == 2) { W = W3;  Wt = W3t;  K = H2_DIM; N = H3_DIM; }
  else             { W = Wc1; Wt = Wc1t; K = D_CBP;  N = H_C;    }
  const int k0 = blockIdx.x * 32, n0 = blockIdx.y * 32;
  if (k0 >= K || n0 >= N) return;
  const int tx = threadIdx.x & 31, ty = threadIdx.x >> 5;
#pragma unroll
  for (int s = 0; s < 4; ++s) {
    const int k = ty * 4 + s;
    tile[k][tx] = W[(size_t)(k0 + k) * N + n0 + tx];
  }
  __syncthreads();
#pragma unroll
  for (int s = 0; s < 4; ++s) {
    const int n = ty * 4 + s;
    Wt[(size_t)(n0 + n) * K + k0 + tx] = f2b(tile[tx][n]);
  }
}

// ---------------------------------------------------------------------------
// FFT-domain CBP.  Identity:
//   cbp = irfft(F1 .* F2),  F1[k] = sum_i a_i e^{-2πi k h1_i/2048}  (K=128)
//   cbp @ Wc1 = sum_k w_k/N * (Pr[k] Gr[k,c] - Pi[k] Gi[k,c]),
//     G[k,c] = sum_q Wc1[q,c] e^{+2πi qk/N},  w_0 = w_1024 = 1 else 2.
// Chain: F1 = E3x @ C1;  F1 <- F1 (.) (E3c @ C2)  [fused epilogue];
//        Z = lrelu(F1 @ FWt^T + bc1),  FWt = Wc1t @ Tt^T.
// [r1: random-bank LDS atomics ~198 cyc/wave-op — never on critical path.
//  r3: half-split G4' = 2 blk/CU = 589 TF; r4: full-batch same per-block
//  speed -> latency-bound; r5: counted vmcnt helped only −9% -> sync-bound.]
// ---------------------------------------------------------------------------

// tab[t] = (cos, sin)(2π t / 2048);  zbias = zeros (bias for slope-1 GEMMs)
__global__ __launch_bounds__(256) void setup_tab(
    float2* __restrict__ tab, float* __restrict__ zbias)
{
  const int t = blockIdx.x * 256 + threadIdx.x;
  if (t < D_CBP) {
    const float ang = 6.2831853071795864769f * (float)t / (float)D_CBP;
    tab[t] = make_float2(__cosf(ang), __sinf(ang));
  }
  if (t < NF) zbias[t] = 0.f;
}

// C1t/C2t [NF][128] bf16:  row m (k=m>>1): even m -> s_i cos(2π k h_i/2048),
// odd m -> -s_i sin(...).  m >= 2050 -> 0 (pad).
__global__ __launch_bounds__(256) void gen_C(
    const float2* __restrict__ tab,
    const int* __restrict__ h1, const float* __restrict__ s1,
    const int* __restrict__ h2, const float* __restrict__ s2,
    u16* __restrict__ C1t, u16* __restrict__ C2t)
{
  const int id = blockIdx.x * 256 + threadIdx.x;   // [0, NF*128)
  if (id >= NF * H3_DIM) return;
  const int m = id >> 7, i = id & 127;
  const int k = m >> 1;
  float v1 = 0.f, v2 = 0.f;
  if (m < 2 * (D_CBP / 2 + 1)) {                   // m < 2050
    const float2 c1 = tab[(k * h1[i]) & (D_CBP - 1)];
    const float2 c2 = tab[(k * h2[i]) & (D_CBP - 1)];
    v1 = (m & 1) ? -s1[i] * c1.y : s1[i] * c1.x;
    v2 = (m & 1) ? -s2[i] * c2.y : s2[i] * c2.x;
  }
  C1t[id] = f2b(v1);
  C2t[id] = f2b(v2);
}

// Tt [NF][2048] bf16: row m (k=m>>1): even -> w_k cos(2π kq/2048)/2048,
// odd -> -w_k sin(...)/2048.  8 q per thread.
__global__ __launch_bounds__(256) void gen_T(
    const float2* __restrict__ tab, u16* __restrict__ Tt)
{
  const int id = blockIdx.x * 256 + threadIdx.x;   // [0, NF*256)
  const int m = id >> 8, q0 = (id & 255) * 8;
  const int k = m >> 1;
  const float sc = ((k == 0) || (k == D_CBP / 2)) ? (1.f / D_CBP) : (2.f / D_CBP);
  __align__(16) u16 o[8];
#pragma unroll
  for (int j = 0; j < 8; ++j) {
    float v = 0.f;
    if (m < 2 * (D_CBP / 2 + 1)) {
      const float2 cs = tab[(k * (q0 + j)) & (D_CBP - 1)];
      v = (m & 1) ? -sc * cs.y : sc * cs.x;
    }
    o[j] = f2b(v);
  }
  *(v8s*)&Tt[(size_t)m * D_CBP + q0] = *(v8s*)o;
}

// ---------------------------------------------------------------------------
// Head: logits = Z[B,1024](bf16) @ Wc2[1024,10] + bc2; softmax -> fp32 out.
// ---------------------------------------------------------------------------
__global__ __launch_bounds__(256) void head_softmax(
    const u16* __restrict__ Z, const float* __restrict__ Wc2,
    const float* __restrict__ bc2, float* __restrict__ out)
{
  const int row  = blockIdx.x * 4 + (threadIdx.x >> 6);
  const int lane = threadIdx.x & 63;

  float acc[CLASSES];
#pragma unroll
  for (int c = 0; c < CLASSES; ++c) acc[c] = 0.f;

  const u16* z = Z + (size_t)row * H_C;
  for (int k = lane; k < H_C; k += 64) {
    const float zv = b2f(z[k]);
    const float* w = Wc2 + (size_t)k * CLASSES;
#pragma unroll
    for (int c = 0; c < CLASSES; ++c) acc[c] += zv * w[c];
  }
#pragma unroll
  for (int c = 0; c < CLASSES; ++c) {
#pragma unroll
    for (int off = 32; off > 0; off >>= 1)
      acc[c] += __shfl_down(acc[c], off);
  }
  if (lane == 0) {
    float l[CLASSES], mx = -1e30f;
#pragma unroll
    for (int c = 0; c < CLASSES; ++c) { l[c] = acc[c] + bc2[c]; mx = fmaxf(mx, l[c]); }
    float s = 0.f;
#pragma unroll
    for (int c = 0; c < CLASSES; ++c) { l[c] = __expf(l[c] - mx); s += l[c]; }
    const float inv = 1.f / s;
#pragma unroll
    for (int c = 0; c < CLASSES; ++c) out[(size_t)row * CLASSES + c] = l[c] * inv;
  }
}

// ---------------------------------------------------------------------------
// Launcher.  Workspace map (MB = 1<<20), full-batch, peak < 128 MiB:
//   Xb   @ 0..64     [2B,1024] bf16      (cast -> G1; dead after G1)
//   Tt   @ 0..8.5    [2176,2048] bf16    (gen_T after G1 -> FWt gemm)
//   FWt  @ 8.5..12.75 [1024,2176] bf16
//   F1   @ 13..81    [16384,2176] bf16   (F1 gemm -> F2-fused RMW -> G4')
//   E1b  @ 64..96    (G1 -> G2; overlap with F1 tail is dead by F1-write)
//   Zb   @ 81..113   (G4' -> head; over dead E2b)
//   E2b  @ 96..112   (G2 -> G3)
//   E3b  @ 113..121  [2B,128] bf16       (G3 -> F gemms)
//   W1t @121  W2t @122  W3t @122.25  Wc1t @122.5..126.5
//   C1t @126.5  C2t @127.0625  tab @127.625  zbias @127.65
// ---------------------------------------------------------------------------
extern "C" void kernel_launch(void* const* d_in, const int* in_sizes, int n_in,
                              void* d_out, int out_size, void* d_ws, size_t ws_size,
                              hipStream_t stream) {
  const float* X       = (const float*)d_in[0];
  const float* Centers = (const float*)d_in[1];
  const float* W1      = (const float*)d_in[2];
  const float* b1      = (const float*)d_in[3];
  const float* W2      = (const float*)d_in[4];
  const float* b2      = (const float*)d_in[5];
  const float* W3      = (const float*)d_in[6];
  const float* b3      = (const float*)d_in[7];
  const int*   h1      = (const int*)d_in[8];
  const float* s1      = (const float*)d_in[9];
  const int*   h2      = (const int*)d_in[10];
  const float* s2      = (const float*)d_in[11];
  const float* Wc1     = (const float*)d_in[12];
  const float* bc1     = (const float*)d_in[13];
  const float* Wc2     = (const float*)d_in[14];
  const float* bc2     = (const float*)d_in[15];
  float* out = (float*)d_out;

  char* ws = (char*)d_ws;
  const size_t MB = 1u << 20;
  const size_t KB = 1u << 10;
  u16*    Xb    = (u16*)(ws);
  u16*    Tt    = (u16*)(ws);                       // after G1
  u16*    FWt   = (u16*)(ws + 8 * MB + 512 * KB);
  u16*    F1    = (u16*)(ws + 13 * MB);
  u16*    E1b   = (u16*)(ws + 64 * MB);
  u16*    Zb    = (u16*)(ws + 81 * MB);
  u16*    E2b   = (u16*)(ws + 96 * MB);
  u16*    E3b   = (u16*)(ws + 113 * MB);
  u16*    W1t   = (u16*)(ws + 121 * MB);
  u16*    W2t   = (u16*)(ws + 122 * MB);
  u16*    W3t   = (u16*)(ws + 122 * MB + 256 * KB);
  u16*    Wc1t  = (u16*)(ws + 122 * MB + 512 * KB);
  u16*    C1t   = (u16*)(ws + 126 * MB + 512 * KB);
  u16*    C2t   = (u16*)(ws + 127 * MB + 64 * KB);
  float2* tab   = (float2*)(ws + 127 * MB + 640 * KB);
  float*  zbias = (float*)(ws + 127 * MB + 672 * KB);

  const dim3 blk(256);

  // casts: X, Centers -> Xb rows [0..B), [B..2B)
  cast2_bf16<<<dim3(2 * CAST_NB), blk, 0, stream>>>(X, Centers, Xb);

  // weight transposes
  transpose_cast4<<<dim3(D_CBP / 32, H_C / 32, 4), blk, 0, stream>>>(
      W1, W1t, W2, W2t, W3, W3t, Wc1, Wc1t);

  // twiddle table + zero bias; C1t/C2t (need only h/s inputs)
  setup_tab<<<dim3(9), blk, 0, stream>>>(tab, zbias);
  gen_C<<<dim3(NF * H3_DIM / 256), blk, 0, stream>>>(tab, h1, s1, h2, s2, C1t, C2t);

  // G1 (frees Xb region for Tt/FWt)
  gemm_bf16_t<0><<<dim3(H1_DIM / 128, 2 * BATCH / 128), blk, 0, stream>>>(
      Xb, W1t, b1, E1b, 2 * BATCH, H1_DIM, D_IN, SLOPE);

  // Tt and FWt = Wc1t @ Tt^T   [1024][2176]
  gen_T<<<dim3(NF), blk, 0, stream>>>(tab, Tt);
  gemm_bf16_t<0><<<dim3(NF / 128, H_C / 128), blk, 0, stream>>>(
      Wc1t, Tt, zbias, FWt, H_C, NF, D_CBP, 1.0f);

  // G2, G3
  gemm_bf16_t<0><<<dim3(H2_DIM / 128, 2 * BATCH / 128), blk, 0, stream>>>(
      E1b, W2t, b2, E2b, 2 * BATCH, H2_DIM, H1_DIM, SLOPE);
  gemm_bf16_t<0><<<dim3(H3_DIM / 128, 2 * BATCH / 128), blk, 0, stream>>>(
      E2b, W3t, b3, E3b, 2 * BATCH, H3_DIM, H2_DIM, SLOPE);

  // F1 = E3x @ C1   [16384][2176], K=128
  gemm_bf16_t<0><<<dim3(NF / 128, BATCH / 128), blk, 0, stream>>>(
      E3b, C1t, zbias, F1, BATCH, NF, H3_DIM, 1.0f);
  // F1 <- F1 (.)complex (E3c @ C2)   [fused epilogue, in place]
  gemm_bf16_t<1><<<dim3(NF / 128, BATCH / 128), blk, 0, stream>>>(
      E3b + (size_t)BATCH * H3_DIM, C2t, zbias, F1, BATCH, NF, H3_DIM, 1.0f);
  // Z = lrelu(P @ FWt^T + bc1)   [16384][1024], K=2176
  gemm_bf16_t<0><<<dim3(H_C / 128, BATCH / 128), blk, 0, stream>>>(
      F1, FWt, bc1, Zb, BATCH, H_C, NF, SLOPE);

  // head
  head_softmax<<<dim3(BATCH / 4), blk, 0, stream>>>(Zb, Wc2, bc2, out);
}

// Round 8
// 470.203 us; speedup vs baseline: 1.2007x; 1.0998x over previous
//
#include <hip/hip_runtime.h>
#include <hip/hip_bf16.h>
#include <math.h>

// ---------------------------------------------------------------------------
// Dims (fixed per reference)
// ---------------------------------------------------------------------------
#define BATCH   16384
#define D_IN    1024
#define H1_DIM  512
#define H2_DIM  256
#define H3_DIM  128
#define D_CBP   2048
#define H_C     1024
#define CLASSES 10
#define SLOPE   0.2f

// FFT-domain dims: rfft bins k = 0..1024 (1025), padded to 1088 complex
// -> 2176 real columns (Re,Im interleaved), = 17 tiles of 128.
// Non-zero real columns: 2*1025 = 2050 -> K-trim to 2080 (mult of 32).
#define NK_PAD  1088
#define NF      (2 * NK_PAD)   // 2176
#define NF_USED 2080           // K-trim for G4' (cols 2050.. are zeros)

typedef short v8s __attribute__((ext_vector_type(8)));
typedef float v4f __attribute__((ext_vector_type(4)));
typedef unsigned short u16;
typedef unsigned int   u32;

__device__ __forceinline__ float b2f(unsigned short u) {
  return __uint_as_float(((unsigned)u) << 16);
}
__device__ __forceinline__ u16 f2b(float f) {
  __hip_bfloat16 h = __float2bfloat16(f);   // RNE
  return __builtin_bit_cast(unsigned short, h);
}

// async 16B global->LDS (direct-to-shared DMA). LDS dest = wave-uniform base
// + lane*16 -> LDS layout is forced packed lane-order.
__device__ __forceinline__ void g2l16(const void* g, void* l) {
  __builtin_amdgcn_global_load_lds(
      (const __attribute__((address_space(1))) void*)g,
      (__attribute__((address_space(3))) void*)l, 16, 0, 0);
}

// ---------------------------------------------------------------------------
// bf16 MFMA GEMM: C[M,N] = lrelu_slope(A[M,K]@Bt[N,K]^T + bias).
// Tile 128x128, BK=32, 256 threads (4 waves, 2x2 of 64x64), 16 MFMA/wave/step.
// Granule rotation swizzle at the GLOBAL address -> both A/B ds_read_b128
// are 2 lanes/bank (free). Bijective XCD swizzle (T1, r2 verified).
// r6/r7: 5-buffer ring / prefetch-depth-3 / ONE barrier per K-step /
// counted vmcnt (12/8/4/0 tail). 709 TF on G4' — near this structure's cap.
// lda/ldb: row strides of A / Bt (enable K-trim against padded buffers).
// ---------------------------------------------------------------------------
__global__ __launch_bounds__(256) void gemm_bf16(
    const u16* __restrict__ A,   // [M][lda] bf16
    const u16* __restrict__ Bt,  // [N][ldb] bf16  (weights pre-transposed)
    const float* __restrict__ bias,
    u16* __restrict__ C,         // [M][N] bf16
    int M, int N, int K, int lda, int ldb, float slope)
{
  __shared__ __align__(16) short Asb[5][128 * 32];   // 40 KiB
  __shared__ __align__(16) short Bsb[5][128 * 32];   // 40 KiB

  const int tid  = threadIdx.x;
  const int wave = tid >> 6, lane = tid & 63;
  const int wm = wave >> 1, wn = wave & 1;
  const int u = lane & 15, quad = lane >> 4;

  const int nwg = gridDim.x * gridDim.y;
  int id = blockIdx.y * gridDim.x + blockIdx.x;
  if ((nwg & 7) == 0) id = (id & 7) * (nwg >> 3) + (id >> 3);
  const int m0 = (id / gridDim.x) * 128, n0 = (id % gridDim.x) * 128;

  const int g_log = ((lane & 3) - ((lane >> 3) & 3)) & 3;
  const int srow  = wave * 32 + (lane >> 2);
  const u16* gA0 = A  + (size_t)(m0 + srow)      * lda + g_log * 8;
  const u16* gA1 = A  + (size_t)(m0 + srow + 16) * lda + g_log * 8;
  const u16* gB0 = Bt + (size_t)(n0 + srow)      * ldb + g_log * 8;
  const u16* gB1 = Bt + (size_t)(n0 + srow + 16) * ldb + g_log * 8;
  const int lo0 = (wave * 32)      * 32;
  const int lo1 = (wave * 32 + 16) * 32;

  const int gran = (quad + (u >> 1)) & 3;
  int offA[4], offB[4];
#pragma unroll
  for (int i = 0; i < 4; ++i) {
    offA[i] = (wm * 64 + i * 16 + u) * 32 + gran * 8;
    offB[i] = (wn * 64 + i * 16 + u) * 32 + gran * 8;
  }

  v4f acc[4][4];
#pragma unroll
  for (int i = 0; i < 4; ++i)
#pragma unroll
    for (int j = 0; j < 4; ++j) acc[i][j] = (v4f){0.f, 0.f, 0.f, 0.f};

  const int nsteps = K >> 5;   // BK=32

  auto stage = [&](int s, int buf) {
    const int k0 = s * 32;
    g2l16(gA0 + k0, &Asb[buf][lo0]);
    g2l16(gA1 + k0, &Asb[buf][lo1]);
    g2l16(gB0 + k0, &Bsb[buf][lo0]);
    g2l16(gB1 + k0, &Bsb[buf][lo1]);
  };

  // prologue: fill pipeline 3 deep
  stage(0, 0);
  if (nsteps > 1) stage(1, 1);
  if (nsteps > 2) stage(2, 2);

  int cb = 0, sb = 3;   // compute-buffer, stage-buffer (wrap mod 5)
  for (int t = 0; t < nsteps; ++t) {
    if (t + 3 < nsteps) stage(t + 3, sb);

    const int rem = nsteps - 1 - t;
    if (rem >= 3)      asm volatile("s_waitcnt vmcnt(12)" ::: "memory");
    else if (rem == 2) asm volatile("s_waitcnt vmcnt(8)"  ::: "memory");
    else if (rem == 1) asm volatile("s_waitcnt vmcnt(4)"  ::: "memory");
    else               asm volatile("s_waitcnt vmcnt(0)"  ::: "memory");
    __builtin_amdgcn_s_barrier();
    asm volatile("" ::: "memory");   // pin ds_reads below the barrier

    v8s a[4], b[4];
#pragma unroll
    for (int i = 0; i < 4; ++i) a[i] = *(const v8s*)&Asb[cb][offA[i]];
#pragma unroll
    for (int j = 0; j < 4; ++j) b[j] = *(const v8s*)&Bsb[cb][offB[j]];
#pragma unroll
    for (int i = 0; i < 4; ++i)
#pragma unroll
      for (int j = 0; j < 4; ++j)
        acc[i][j] = __builtin_amdgcn_mfma_f32_16x16x32_bf16(a[i], b[j], acc[i][j], 0, 0, 0);

    cb = (cb == 4) ? 0 : cb + 1;
    sb = (sb == 4) ? 0 : sb + 1;
  }

  // C/D layout (m89-verified): col = lane&15, row = quad*4 + reg
  float bcol[4];
#pragma unroll
  for (int j = 0; j < 4; ++j) bcol[j] = bias[n0 + wn * 64 + j * 16 + u];
#pragma unroll
  for (int i = 0; i < 4; ++i)
#pragma unroll
    for (int r = 0; r < 4; ++r) {
      const size_t ro = (size_t)(m0 + wm * 64 + i * 16 + quad * 4 + r) * N
                        + n0 + wn * 64 + u;
#pragma unroll
      for (int j = 0; j < 4; ++j) {
        float v = acc[i][j][r] + bcol[j];
        v = v >= 0.f ? v : slope * v;
        C[ro + j * 16] = f2b(v);
      }
    }
}

// ---------------------------------------------------------------------------
// Fused F1/F2/complex-product kernel (r8).
// Each block computes BOTH K=128 GEMM passes for its (m,n) tile —
//   acc1 = E3x_tile @ C1^T,  acc2 = E3c_tile @ C2^T —
// then writes F1 <- acc1 (.)complex acc2 once, from f32 registers.
// vs r7: removes 68 MB F1-interim write + 68 MB RMW re-read (one launch).
// Cross-pass LDS WAR race-free: a wave entering pass 2 passed
// barrier(pass1,t=3); all waves' buf0..2 ds_reads (t<=2) completed in
// program order before that barrier; pass-2 prologue writes only buf0..2.
// nsteps=4 fixed -> vmcnt ladder 12/8/4/0 per pass.
// ---------------------------------------------------------------------------
__device__ __forceinline__ void f_pass(
    const u16* gA0, const u16* gA1, const u16* gB0, const u16* gB1,
    short (*Asb)[128 * 32], short (*Bsb)[128 * 32],
    int lo0, int lo1, const int* offA, const int* offB,
    v4f (&acc)[4][4])
{
  auto stage = [&](int s, int buf) {
    const int k0 = s * 32;
    g2l16(gA0 + k0, &Asb[buf][lo0]);
    g2l16(gA1 + k0, &Asb[buf][lo1]);
    g2l16(gB0 + k0, &Bsb[buf][lo0]);
    g2l16(gB1 + k0, &Bsb[buf][lo1]);
  };
  stage(0, 0); stage(1, 1); stage(2, 2);
#pragma unroll
  for (int t = 0; t < 4; ++t) {
    if (t == 0) stage(3, 3);
    if (t == 0)      asm volatile("s_waitcnt vmcnt(12)" ::: "memory");
    else if (t == 1) asm volatile("s_waitcnt vmcnt(8)"  ::: "memory");
    else if (t == 2) asm volatile("s_waitcnt vmcnt(4)"  ::: "memory");
    else             asm volatile("s_waitcnt vmcnt(0)"  ::: "memory");
    __builtin_amdgcn_s_barrier();
    asm volatile("" ::: "memory");
    v8s a[4], b[4];
#pragma unroll
    for (int i = 0; i < 4; ++i) a[i] = *(const v8s*)&Asb[t][offA[i]];
#pragma unroll
    for (int j = 0; j < 4; ++j) b[j] = *(const v8s*)&Bsb[t][offB[j]];
#pragma unroll
    for (int i = 0; i < 4; ++i)
#pragma unroll
      for (int j = 0; j < 4; ++j)
        acc[i][j] = __builtin_amdgcn_mfma_f32_16x16x32_bf16(a[i], b[j], acc[i][j], 0, 0, 0);
  }
}

__global__ __launch_bounds__(256) void gemm_f1f2(
    const u16* __restrict__ E3,    // [2*BATCH][128]; rows B.. = centers
    const u16* __restrict__ C1t,   // [NF][128]
    const u16* __restrict__ C2t,   // [NF][128]
    u16* __restrict__ F1)          // [BATCH][NF] <- F1 .* F2
{
  __shared__ __align__(16) short Asb[5][128 * 32];
  __shared__ __align__(16) short Bsb[5][128 * 32];

  const int tid  = threadIdx.x;
  const int wave = tid >> 6, lane = tid & 63;
  const int wm = wave >> 1, wn = wave & 1;
  const int u = lane & 15, quad = lane >> 4;
  const int N = NF, K = H3_DIM;

  const int nwg = gridDim.x * gridDim.y;
  int id = blockIdx.y * gridDim.x + blockIdx.x;
  if ((nwg & 7) == 0) id = (id & 7) * (nwg >> 3) + (id >> 3);
  const int m0 = (id / gridDim.x) * 128, n0 = (id % gridDim.x) * 128;

  const int g_log = ((lane & 3) - ((lane >> 3) & 3)) & 3;
  const int srow  = wave * 32 + (lane >> 2);
  const size_t aoffX = (size_t)(m0 + srow) * K + g_log * 8;
  const size_t boff  = (size_t)(n0 + srow) * K + g_log * 8;
  const int lo0 = (wave * 32)      * 32;
  const int lo1 = (wave * 32 + 16) * 32;

  const int gran = (quad + (u >> 1)) & 3;
  int offA[4], offB[4];
#pragma unroll
  for (int i = 0; i < 4; ++i) {
    offA[i] = (wm * 64 + i * 16 + u) * 32 + gran * 8;
    offB[i] = (wn * 64 + i * 16 + u) * 32 + gran * 8;
  }

  v4f acc1[4][4], acc2[4][4];
#pragma unroll
  for (int i = 0; i < 4; ++i)
#pragma unroll
    for (int j = 0; j < 4; ++j) {
      acc1[i][j] = (v4f){0.f, 0.f, 0.f, 0.f};
      acc2[i][j] = (v4f){0.f, 0.f, 0.f, 0.f};
    }

  // pass 1: F1 = E3x @ C1^T
  f_pass(E3 + aoffX, E3 + aoffX + (size_t)16 * K,
         C1t + boff, C1t + boff + (size_t)16 * K,
         Asb, Bsb, lo0, lo1, offA, offB, acc1);
  // pass 2: F2 = E3c @ C2^T  (centers rows start at BATCH)
  const size_t aoffC = aoffX + (size_t)BATCH * K;
  f_pass(E3 + aoffC, E3 + aoffC + (size_t)16 * K,
         C2t + boff, C2t + boff + (size_t)16 * K,
         Asb, Bsb, lo0, lo1, offA, offB, acc2);

  // epilogue: complex product, all in registers.
  // even col (u even) = Re, odd = Im; partner is lane^1 (same quad).
  const bool im = (u & 1);
#pragma unroll
  for (int i = 0; i < 4; ++i)
#pragma unroll
    for (int r = 0; r < 4; ++r) {
      const size_t ro = (size_t)(m0 + wm * 64 + i * 16 + quad * 4 + r) * N
                        + n0 + wn * 64 + u;
#pragma unroll
      for (int j = 0; j < 4; ++j) {
        const float f1v = acc1[i][j][r];
        const float f1p = __shfl_xor(f1v, 1, 64);
        const float f2v = acc2[i][j][r];
        const float f2p = __shfl_xor(f2v, 1, 64);
        // even lane: F1r*F2r - F1i*F2i ; odd lane: F1r*F2i + F1i*F2r
        const float outv = im ? (f1p * f2v + f1v * f2p)
                              : (f1v * f2v - f1p * f2p);
        F1[ro + j * 16] = f2b(outv);
      }
    }
}

// ---------------------------------------------------------------------------
// cast fp32 -> bf16, two sources in one launch (X then Centers)
// ---------------------------------------------------------------------------
#define CAST_NB (BATCH * D_IN / 4 / 256)   // blocks per source
__global__ __launch_bounds__(256) void cast2_bf16(
    const float* __restrict__ srcA, const float* __restrict__ srcB,
    u16* __restrict__ dst)
{
  const int bx = blockIdx.x;
  const float* s = (bx < CAST_NB) ? srcA : srcB;
  const int i = ((bx < CAST_NB) ? bx : bx - CAST_NB) * 256 + threadIdx.x;
  u16* d = dst + ((bx < CAST_NB) ? 0 : (size_t)BATCH * D_IN);
  const float4 v = ((const float4*)s)[i];
  __align__(8) u16 o[4] = {f2b(v.x), f2b(v.y), f2b(v.z), f2b(v.w)};
  *(uint2*)(d + (size_t)i * 4) = *(uint2*)o;
}

// ---------------------------------------------------------------------------
// transpose + cast, all 4 weights in one launch (z selects the matrix):
// W[K][N] fp32 -> Wt[N][K] bf16.  32x32 tiles via LDS.
// ---------------------------------------------------------------------------
__global__ __launch_bounds__(256) void transpose_cast4(
    const float* __restrict__ W1, u16* __restrict__ W1t,
    const float* __restrict__ W2, u16* __restrict__ W2t,
    const float* __restrict__ W3, u16* __restrict__ W3t,
    const float* __restrict__ Wc1, u16* __restrict__ Wc1t)
{
  __shared__ float tile[32][33];
  const int z = blockIdx.z;
  const float* W; u16* Wt; int K, N;
  if      (z == 0) { W = W1;  Wt = W1t;  K = D_IN;   N = H1_DIM; }
  else if (z == 1) { W = W2;  Wt = W2t;  K = H1_DIM; N = H2_DIM; }
  else if (z == 2) { W = W3;  Wt = W3t;  K = H2_DIM; N = H3_DIM; }
  else             { W = Wc1; Wt = Wc1t; K = D_CBP;  N = H_C;    }
  const int k0 = blockIdx.x * 32, n0 = blockIdx.y * 32;
  if (k0 >= K || n0 >= N) return;
  const int tx = threadIdx.x & 31, ty = threadIdx.x >> 5;
#pragma unroll
  for (int s = 0; s < 4; ++s) {
    const int k = ty * 4 + s;
    tile[k][tx] = W[(size_t)(k0 + k) * N + n0 + tx];
  }
  __syncthreads();
#pragma unroll
  for (int s = 0; s < 4; ++s) {
    const int n = ty * 4 + s;
    Wt[(size_t)(n0 + n) * K + k0 + tx] = f2b(tile[tx][n]);
  }
}

// ---------------------------------------------------------------------------
// FFT-domain CBP.  Identity:
//   cbp = irfft(F1 .* F2),  F1[k] = sum_i a_i e^{-2πi k h1_i/2048}  (K=128)
//   cbp @ Wc1 = sum_k w_k/N * (Pr[k] Gr[k,c] - Pi[k] Gi[k,c]),
//     G[k,c] = sum_q Wc1[q,c] e^{+2πi qk/N},  w_0 = w_1024 = 1 else 2.
// Chain: P = gemm_f1f2(E3)  [fused, register complex product];
//        Z = lrelu(P @ FWt^T + bc1),  FWt = Wc1t @ Tt^T,  K trimmed to 2080.
// [r1: random-bank LDS atomics ~198 cyc/wave-op — never on critical path.
//  r4: barrier-drain latency-bound; r5-r7: counted-vmcnt ring -> 709 TF,
//  near the 128^2 structure cap.]
// ---------------------------------------------------------------------------

// tab[t] = (cos, sin)(2π t / 2048);  zbias = zeros (bias for slope-1 GEMMs)
__global__ __launch_bounds__(256) void setup_tab(
    float2* __restrict__ tab, float* __restrict__ zbias)
{
  const int t = blockIdx.x * 256 + threadIdx.x;
  if (t < D_CBP) {
    const float ang = 6.2831853071795864769f * (float)t / (float)D_CBP;
    tab[t] = make_float2(__cosf(ang), __sinf(ang));
  }
  if (t < NF) zbias[t] = 0.f;
}

// C1t/C2t [NF][128] bf16:  row m (k=m>>1): even m -> s_i cos(2π k h_i/2048),
// odd m -> -s_i sin(...).  m >= 2050 -> 0 (pad).
__global__ __launch_bounds__(256) void gen_C(
    const float2* __restrict__ tab,
    const int* __restrict__ h1, const float* __restrict__ s1,
    const int* __restrict__ h2, const float* __restrict__ s2,
    u16* __restrict__ C1t, u16* __restrict__ C2t)
{
  const int id = blockIdx.x * 256 + threadIdx.x;   // [0, NF*128)
  if (id >= NF * H3_DIM) return;
  const int m = id >> 7, i = id & 127;
  const int k = m >> 1;
  float v1 = 0.f, v2 = 0.f;
  if (m < 2 * (D_CBP / 2 + 1)) {                   // m < 2050
    const float2 c1 = tab[(k * h1[i]) & (D_CBP - 1)];
    const float2 c2 = tab[(k * h2[i]) & (D_CBP - 1)];
    v1 = (m & 1) ? -s1[i] * c1.y : s1[i] * c1.x;
    v2 = (m & 1) ? -s2[i] * c2.y : s2[i] * c2.x;
  }
  C1t[id] = f2b(v1);
  C2t[id] = f2b(v2);
}

// Tt [NF][2048] bf16: row m (k=m>>1): even -> w_k cos(2π kq/2048)/2048,
// odd -> -w_k sin(...)/2048.  8 q per thread.
__global__ __launch_bounds__(256) void gen_T(
    const float2* __restrict__ tab, u16* __restrict__ Tt)
{
  const int id = blockIdx.x * 256 + threadIdx.x;   // [0, NF*256)
  const int m = id >> 8, q0 = (id & 255) * 8;
  const int k = m >> 1;
  const float sc = ((k == 0) || (k == D_CBP / 2)) ? (1.f / D_CBP) : (2.f / D_CBP);
  __align__(16) u16 o[8];
#pragma unroll
  for (int j = 0; j < 8; ++j) {
    float v = 0.f;
    if (m < 2 * (D_CBP / 2 + 1)) {
      const float2 cs = tab[(k * (q0 + j)) & (D_CBP - 1)];
      v = (m & 1) ? -sc * cs.y : sc * cs.x;
    }
    o[j] = f2b(v);
  }
  *(v8s*)&Tt[(size_t)m * D_CBP + q0] = *(v8s*)o;
}

// ---------------------------------------------------------------------------
// Head: logits = Z[B,1024](bf16) @ Wc2[1024,10] + bc2; softmax -> fp32 out.
// ---------------------------------------------------------------------------
__global__ __launch_bounds__(256) void head_softmax(
    const u16* __restrict__ Z, const float* __restrict__ Wc2,
    const float* __restrict__ bc2, float* __restrict__ out)
{
  const int row  = blockIdx.x * 4 + (threadIdx.x >> 6);
  const int lane = threadIdx.x & 63;

  float acc[CLASSES];
#pragma unroll
  for (int c = 0; c < CLASSES; ++c) acc[c] = 0.f;

  const u16* z = Z + (size_t)row * H_C;
  for (int k = lane; k < H_C; k += 64) {
    const float zv = b2f(z[k]);
    const float* w = Wc2 + (size_t)k * CLASSES;
#pragma unroll
    for (int c = 0; c < CLASSES; ++c) acc[c] += zv * w[c];
  }
#pragma unroll
  for (int c = 0; c < CLASSES; ++c) {
#pragma unroll
    for (int off = 32; off > 0; off >>= 1)
      acc[c] += __shfl_down(acc[c], off);
  }
  if (lane == 0) {
    float l[CLASSES], mx = -1e30f;
#pragma unroll
    for (int c = 0; c < CLASSES; ++c) { l[c] = acc[c] + bc2[c]; mx = fmaxf(mx, l[c]); }
    float s = 0.f;
#pragma unroll
    for (int c = 0; c < CLASSES; ++c) { l[c] = __expf(l[c] - mx); s += l[c]; }
    const float inv = 1.f / s;
#pragma unroll
    for (int c = 0; c < CLASSES; ++c) out[(size_t)row * CLASSES + c] = l[c] * inv;
  }
}

// ---------------------------------------------------------------------------
// Launcher.  Workspace map (MB = 1<<20), full-batch, peak < 128 MiB:
//   Xb   @ 0..64     [2B,1024] bf16      (cast -> G1; dead after G1)
//   Tt   @ 0..8.5    [2176,2048] bf16    (gen_T after G1 -> FWt gemm)
//   FWt  @ 8.5..12.75 [1024,2176] bf16
//   F1   @ 13..81    [16384,2176] bf16   (gemm_f1f2 -> G4')
//   E1b  @ 64..96    (G1 -> G2; overlap with F1 tail is dead by F1-write)
//   Zb   @ 81..113   (G4' -> head; over dead E2b)
//   E2b  @ 96..112   (G2 -> G3)
//   E3b  @ 113..121  [2B,128] bf16       (G3 -> gemm_f1f2)
//   W1t @121  W2t @122  W3t @122.25  Wc1t @122.5..126.5
//   C1t @126.5  C2t @127.0625  tab @127.625  zbias @127.65
// ---------------------------------------------------------------------------
extern "C" void kernel_launch(void* const* d_in, const int* in_sizes, int n_in,
                              void* d_out, int out_size, void* d_ws, size_t ws_size,
                              hipStream_t stream) {
  const float* X       = (const float*)d_in[0];
  const float* Centers = (const float*)d_in[1];
  const float* W1      = (const float*)d_in[2];
  const float* b1      = (const float*)d_in[3];
  const float* W2      = (const float*)d_in[4];
  const float* b2      = (const float*)d_in[5];
  const float* W3      = (const float*)d_in[6];
  const float* b3      = (const float*)d_in[7];
  const int*   h1      = (const int*)d_in[8];
  const float* s1      = (const float*)d_in[9];
  const int*   h2      = (const int*)d_in[10];
  const float* s2      = (const float*)d_in[11];
  const float* Wc1     = (const float*)d_in[12];
  const float* bc1     = (const float*)d_in[13];
  const float* Wc2     = (const float*)d_in[14];
  const float* bc2     = (const float*)d_in[15];
  float* out = (float*)d_out;

  char* ws = (char*)d_ws;
  const size_t MB = 1u << 20;
  const size_t KB = 1u << 10;
  u16*    Xb    = (u16*)(ws);
  u16*    Tt    = (u16*)(ws);                       // after G1
  u16*    FWt   = (u16*)(ws + 8 * MB + 512 * KB);
  u16*    F1    = (u16*)(ws + 13 * MB);
  u16*    E1b   = (u16*)(ws + 64 * MB);
  u16*    Zb    = (u16*)(ws + 81 * MB);
  u16*    E2b   = (u16*)(ws + 96 * MB);
  u16*    E3b   = (u16*)(ws + 113 * MB);
  u16*    W1t   = (u16*)(ws + 121 * MB);
  u16*    W2t   = (u16*)(ws + 122 * MB);
  u16*    W3t   = (u16*)(ws + 122 * MB + 256 * KB);
  u16*    Wc1t  = (u16*)(ws + 122 * MB + 512 * KB);
  u16*    C1t   = (u16*)(ws + 126 * MB + 512 * KB);
  u16*    C2t   = (u16*)(ws + 127 * MB + 64 * KB);
  float2* tab   = (float2*)(ws + 127 * MB + 640 * KB);
  float*  zbias = (float*)(ws + 127 * MB + 672 * KB);

  const dim3 blk(256);

  // casts: X, Centers -> Xb rows [0..B), [B..2B)
  cast2_bf16<<<dim3(2 * CAST_NB), blk, 0, stream>>>(X, Centers, Xb);

  // weight transposes
  transpose_cast4<<<dim3(D_CBP / 32, H_C / 32, 4), blk, 0, stream>>>(
      W1, W1t, W2, W2t, W3, W3t, Wc1, Wc1t);

  // twiddle table + zero bias; C1t/C2t (need only h/s inputs)
  setup_tab<<<dim3(9), blk, 0, stream>>>(tab, zbias);
  gen_C<<<dim3(NF * H3_DIM / 256), blk, 0, stream>>>(tab, h1, s1, h2, s2, C1t, C2t);

  // G1 (frees Xb region for Tt/FWt)
  gemm_bf16<<<dim3(H1_DIM / 128, 2 * BATCH / 128), blk, 0, stream>>>(
      Xb, W1t, b1, E1b, 2 * BATCH, H1_DIM, D_IN, D_IN, D_IN, SLOPE);

  // Tt and FWt = Wc1t @ Tt^T   [1024][2176]
  gen_T<<<dim3(NF), blk, 0, stream>>>(tab, Tt);
  gemm_bf16<<<dim3(NF / 128, H_C / 128), blk, 0, stream>>>(
      Wc1t, Tt, zbias, FWt, H_C, NF, D_CBP, D_CBP, D_CBP, 1.0f);

  // G2, G3
  gemm_bf16<<<dim3(H2_DIM / 128, 2 * BATCH / 128), blk, 0, stream>>>(
      E1b, W2t, b2, E2b, 2 * BATCH, H2_DIM, H1_DIM, H1_DIM, H1_DIM, SLOPE);
  gemm_bf16<<<dim3(H3_DIM / 128, 2 * BATCH / 128), blk, 0, stream>>>(
      E2b, W3t, b3, E3b, 2 * BATCH, H3_DIM, H2_DIM, H2_DIM, H2_DIM, SLOPE);

  // P = F1 .* F2, fused dual-GEMM, register complex product
  gemm_f1f2<<<dim3(NF / 128, BATCH / 128), blk, 0, stream>>>(
      E3b, C1t, C2t, F1);

  // Z = lrelu(P @ FWt^T + bc1)   [16384][1024], K trimmed 2176 -> 2080
  gemm_bf16<<<dim3(H_C / 128, BATCH / 128), blk, 0, stream>>>(
      F1, FWt, bc1, Zb, BATCH, H_C, NF_USED, NF, NF, SLOPE);

  // head
  head_softmax<<<dim3(BATCH / 4), blk, 0, stream>>>(Zb, Wc2, bc2, out);
}

// Round 9
// 453.628 us; speedup vs baseline: 1.2446x; 1.0365x over previous
//
#include <hip/hip_runtime.h>
#include <hip/hip_bf16.h>
#include <math.h>

// ---------------------------------------------------------------------------
// Dims (fixed per reference)
// ---------------------------------------------------------------------------
#define BATCH   16384
#define D_IN    1024
#define H1_DIM  512
#define H2_DIM  256
#define H3_DIM  128
#define D_CBP   2048
#define H_C     1024
#define CLASSES 10
#define SLOPE   0.2f

// FFT-domain dims: rfft bins k = 0..1024 (1025), padded to 1088 complex
// -> 2176 real columns (Re,Im interleaved), = 17 tiles of 128.
// Non-zero real columns: 2*1025 = 2050 -> K-trim to 2080 (mult of 32).
#define NK_PAD  1088
#define NF      (2 * NK_PAD)   // 2176
#define NF_USED 2080           // K-trim for G4' (cols 2050.. are zeros)

typedef short v8s __attribute__((ext_vector_type(8)));
typedef float v4f __attribute__((ext_vector_type(4)));
typedef unsigned short u16;
typedef unsigned int   u32;

__device__ __forceinline__ float b2f(unsigned short u) {
  return __uint_as_float(((unsigned)u) << 16);
}
__device__ __forceinline__ u16 f2b(float f) {
  __hip_bfloat16 h = __float2bfloat16(f);   // RNE
  return __builtin_bit_cast(unsigned short, h);
}

// twiddle (cos,sin)(2π idx/2048) — same expression the old table used,
// so values are bit-identical to the r8 tab[] path.
__device__ __forceinline__ float2 twiddle(int idx) {
  const float ang = 6.2831853071795864769f * (float)idx / 2048.f;
  return make_float2(__cosf(ang), __sinf(ang));
}

// async 16B global->LDS (direct-to-shared DMA). LDS dest = wave-uniform base
// + lane*16 -> LDS layout is forced packed lane-order.
__device__ __forceinline__ void g2l16(const void* g, void* l) {
  __builtin_amdgcn_global_load_lds(
      (const __attribute__((address_space(1))) void*)g,
      (__attribute__((address_space(3))) void*)l, 16, 0, 0);
}

// ---------------------------------------------------------------------------
// bf16 MFMA GEMM: C[M,N] = lrelu_slope(A[M,K]@Bt[N,K]^T + bias).
// Tile 128x128, BK=32, 256 threads (4 waves, 2x2 of 64x64), 16 MFMA/wave/step.
// Granule rotation swizzle at the GLOBAL address -> both A/B ds_read_b128
// are 2 lanes/bank (free). Bijective XCD swizzle (T1, r2 verified).
// r6/r7: 5-buffer ring / prefetch-depth-3 / ONE barrier per K-step /
// counted vmcnt (12/8/4/0 tail). r9: + T5 setprio around the MFMA cluster
// (2 resident blocks at different phases -> scheduler has roles to arbitrate).
// lda/ldb: row strides of A / Bt (enable K-trim against padded buffers).
// ---------------------------------------------------------------------------
__global__ __launch_bounds__(256) void gemm_bf16(
    const u16* __restrict__ A,   // [M][lda] bf16
    const u16* __restrict__ Bt,  // [N][ldb] bf16  (weights pre-transposed)
    const float* __restrict__ bias,
    u16* __restrict__ C,         // [M][N] bf16
    int M, int N, int K, int lda, int ldb, float slope)
{
  __shared__ __align__(16) short Asb[5][128 * 32];   // 40 KiB
  __shared__ __align__(16) short Bsb[5][128 * 32];   // 40 KiB

  const int tid  = threadIdx.x;
  const int wave = tid >> 6, lane = tid & 63;
  const int wm = wave >> 1, wn = wave & 1;
  const int u = lane & 15, quad = lane >> 4;

  const int nwg = gridDim.x * gridDim.y;
  int id = blockIdx.y * gridDim.x + blockIdx.x;
  if ((nwg & 7) == 0) id = (id & 7) * (nwg >> 3) + (id >> 3);
  const int m0 = (id / gridDim.x) * 128, n0 = (id % gridDim.x) * 128;

  const int g_log = ((lane & 3) - ((lane >> 3) & 3)) & 3;
  const int srow  = wave * 32 + (lane >> 2);
  const u16* gA0 = A  + (size_t)(m0 + srow)      * lda + g_log * 8;
  const u16* gA1 = A  + (size_t)(m0 + srow + 16) * lda + g_log * 8;
  const u16* gB0 = Bt + (size_t)(n0 + srow)      * ldb + g_log * 8;
  const u16* gB1 = Bt + (size_t)(n0 + srow + 16) * ldb + g_log * 8;
  const int lo0 = (wave * 32)      * 32;
  const int lo1 = (wave * 32 + 16) * 32;

  const int gran = (quad + (u >> 1)) & 3;
  int offA[4], offB[4];
#pragma unroll
  for (int i = 0; i < 4; ++i) {
    offA[i] = (wm * 64 + i * 16 + u) * 32 + gran * 8;
    offB[i] = (wn * 64 + i * 16 + u) * 32 + gran * 8;
  }

  v4f acc[4][4];
#pragma unroll
  for (int i = 0; i < 4; ++i)
#pragma unroll
    for (int j = 0; j < 4; ++j) acc[i][j] = (v4f){0.f, 0.f, 0.f, 0.f};

  const int nsteps = K >> 5;   // BK=32

  auto stage = [&](int s, int buf) {
    const int k0 = s * 32;
    g2l16(gA0 + k0, &Asb[buf][lo0]);
    g2l16(gA1 + k0, &Asb[buf][lo1]);
    g2l16(gB0 + k0, &Bsb[buf][lo0]);
    g2l16(gB1 + k0, &Bsb[buf][lo1]);
  };

  // prologue: fill pipeline 3 deep
  stage(0, 0);
  if (nsteps > 1) stage(1, 1);
  if (nsteps > 2) stage(2, 2);

  int cb = 0, sb = 3;   // compute-buffer, stage-buffer (wrap mod 5)
  for (int t = 0; t < nsteps; ++t) {
    if (t + 3 < nsteps) stage(t + 3, sb);

    const int rem = nsteps - 1 - t;
    if (rem >= 3)      asm volatile("s_waitcnt vmcnt(12)" ::: "memory");
    else if (rem == 2) asm volatile("s_waitcnt vmcnt(8)"  ::: "memory");
    else if (rem == 1) asm volatile("s_waitcnt vmcnt(4)"  ::: "memory");
    else               asm volatile("s_waitcnt vmcnt(0)"  ::: "memory");
    __builtin_amdgcn_s_barrier();
    asm volatile("" ::: "memory");   // pin ds_reads below the barrier

    v8s a[4], b[4];
#pragma unroll
    for (int i = 0; i < 4; ++i) a[i] = *(const v8s*)&Asb[cb][offA[i]];
#pragma unroll
    for (int j = 0; j < 4; ++j) b[j] = *(const v8s*)&Bsb[cb][offB[j]];
    __builtin_amdgcn_s_setprio(1);
#pragma unroll
    for (int i = 0; i < 4; ++i)
#pragma unroll
      for (int j = 0; j < 4; ++j)
        acc[i][j] = __builtin_amdgcn_mfma_f32_16x16x32_bf16(a[i], b[j], acc[i][j], 0, 0, 0);
    __builtin_amdgcn_s_setprio(0);

    cb = (cb == 4) ? 0 : cb + 1;
    sb = (sb == 4) ? 0 : sb + 1;
  }

  // C/D layout (m89-verified): col = lane&15, row = quad*4 + reg
  float bcol[4];
#pragma unroll
  for (int j = 0; j < 4; ++j) bcol[j] = bias[n0 + wn * 64 + j * 16 + u];
#pragma unroll
  for (int i = 0; i < 4; ++i)
#pragma unroll
    for (int r = 0; r < 4; ++r) {
      const size_t ro = (size_t)(m0 + wm * 64 + i * 16 + quad * 4 + r) * N
                        + n0 + wn * 64 + u;
#pragma unroll
      for (int j = 0; j < 4; ++j) {
        float v = acc[i][j][r] + bcol[j];
        v = v >= 0.f ? v : slope * v;
        C[ro + j * 16] = f2b(v);
      }
    }
}

// ---------------------------------------------------------------------------
// Fused F1/F2/complex-product kernel (r8, verified).
// Each block computes BOTH K=128 GEMM passes for its (m,n) tile, then writes
// F1 <- acc1 (.)complex acc2 once, from f32 registers.
// Cross-pass LDS WAR race-free (see r8 proof). vmcnt ladder 12/8/4/0.
// ---------------------------------------------------------------------------
__device__ __forceinline__ void f_pass(
    const u16* gA0, const u16* gA1, const u16* gB0, const u16* gB1,
    short (*Asb)[128 * 32], short (*Bsb)[128 * 32],
    int lo0, int lo1, const int* offA, const int* offB,
    v4f (&acc)[4][4])
{
  auto stage = [&](int s, int buf) {
    const int k0 = s * 32;
    g2l16(gA0 + k0, &Asb[buf][lo0]);
    g2l16(gA1 + k0, &Asb[buf][lo1]);
    g2l16(gB0 + k0, &Bsb[buf][lo0]);
    g2l16(gB1 + k0, &Bsb[buf][lo1]);
  };
  stage(0, 0); stage(1, 1); stage(2, 2);
#pragma unroll
  for (int t = 0; t < 4; ++t) {
    if (t == 0) stage(3, 3);
    if (t == 0)      asm volatile("s_waitcnt vmcnt(12)" ::: "memory");
    else if (t == 1) asm volatile("s_waitcnt vmcnt(8)"  ::: "memory");
    else if (t == 2) asm volatile("s_waitcnt vmcnt(4)"  ::: "memory");
    else             asm volatile("s_waitcnt vmcnt(0)"  ::: "memory");
    __builtin_amdgcn_s_barrier();
    asm volatile("" ::: "memory");
    v8s a[4], b[4];
#pragma unroll
    for (int i = 0; i < 4; ++i) a[i] = *(const v8s*)&Asb[t][offA[i]];
#pragma unroll
    for (int j = 0; j < 4; ++j) b[j] = *(const v8s*)&Bsb[t][offB[j]];
    __builtin_amdgcn_s_setprio(1);
#pragma unroll
    for (int i = 0; i < 4; ++i)
#pragma unroll
      for (int j = 0; j < 4; ++j)
        acc[i][j] = __builtin_amdgcn_mfma_f32_16x16x32_bf16(a[i], b[j], acc[i][j], 0, 0, 0);
    __builtin_amdgcn_s_setprio(0);
  }
}

__global__ __launch_bounds__(256) void gemm_f1f2(
    const u16* __restrict__ E3,    // [2*BATCH][128]; rows B.. = centers
    const u16* __restrict__ C1t,   // [NF][128]
    const u16* __restrict__ C2t,   // [NF][128]
    u16* __restrict__ F1)          // [BATCH][NF] <- F1 .* F2
{
  __shared__ __align__(16) short Asb[5][128 * 32];
  __shared__ __align__(16) short Bsb[5][128 * 32];

  const int tid  = threadIdx.x;
  const int wave = tid >> 6, lane = tid & 63;
  const int wm = wave >> 1, wn = wave & 1;
  const int u = lane & 15, quad = lane >> 4;
  const int N = NF, K = H3_DIM;

  const int nwg = gridDim.x * gridDim.y;
  int id = blockIdx.y * gridDim.x + blockIdx.x;
  if ((nwg & 7) == 0) id = (id & 7) * (nwg >> 3) + (id >> 3);
  const int m0 = (id / gridDim.x) * 128, n0 = (id % gridDim.x) * 128;

  const int g_log = ((lane & 3) - ((lane >> 3) & 3)) & 3;
  const int srow  = wave * 32 + (lane >> 2);
  const size_t aoffX = (size_t)(m0 + srow) * K + g_log * 8;
  const size_t boff  = (size_t)(n0 + srow) * K + g_log * 8;
  const int lo0 = (wave * 32)      * 32;
  const int lo1 = (wave * 32 + 16) * 32;

  const int gran = (quad + (u >> 1)) & 3;
  int offA[4], offB[4];
#pragma unroll
  for (int i = 0; i < 4; ++i) {
    offA[i] = (wm * 64 + i * 16 + u) * 32 + gran * 8;
    offB[i] = (wn * 64 + i * 16 + u) * 32 + gran * 8;
  }

  v4f acc1[4][4], acc2[4][4];
#pragma unroll
  for (int i = 0; i < 4; ++i)
#pragma unroll
    for (int j = 0; j < 4; ++j) {
      acc1[i][j] = (v4f){0.f, 0.f, 0.f, 0.f};
      acc2[i][j] = (v4f){0.f, 0.f, 0.f, 0.f};
    }

  // pass 1: F1 = E3x @ C1^T
  f_pass(E3 + aoffX, E3 + aoffX + (size_t)16 * K,
         C1t + boff, C1t + boff + (size_t)16 * K,
         Asb, Bsb, lo0, lo1, offA, offB, acc1);
  // pass 2: F2 = E3c @ C2^T  (centers rows start at BATCH)
  const size_t aoffC = aoffX + (size_t)BATCH * K;
  f_pass(E3 + aoffC, E3 + aoffC + (size_t)16 * K,
         C2t + boff, C2t + boff + (size_t)16 * K,
         Asb, Bsb, lo0, lo1, offA, offB, acc2);

  // epilogue: complex product, all in registers.
  // even col (u even) = Re, odd = Im; partner is lane^1 (same quad).
  const bool im = (u & 1);
#pragma unroll
  for (int i = 0; i < 4; ++i)
#pragma unroll
    for (int r = 0; r < 4; ++r) {
      const size_t ro = (size_t)(m0 + wm * 64 + i * 16 + quad * 4 + r) * N
                        + n0 + wn * 64 + u;
#pragma unroll
      for (int j = 0; j < 4; ++j) {
        const float f1v = acc1[i][j][r];
        const float f1p = __shfl_xor(f1v, 1, 64);
        const float f2v = acc2[i][j][r];
        const float f2p = __shfl_xor(f2v, 1, 64);
        // even lane: F1r*F2r - F1i*F2i ; odd lane: F1r*F2i + F1i*F2r
        const float outv = im ? (f1p * f2v + f1v * f2p)
                              : (f1v * f2v - f1p * f2p);
        F1[ro + j * 16] = f2b(outv);
      }
    }
}

// ---------------------------------------------------------------------------
// prep_all (r9): ONE launch replacing {cast2_bf16, transpose_cast4,
// setup_tab, gen_C, gen_T}. All roles are independent: the cos/sin table is
// replaced by inline __cosf/__sinf of the IDENTICAL expression
// (2π·((k·h)&2047)/2048) -> bit-identical twiddles.
// Block-role ranges over blockIdx.x:
//   [0, 32768)          cast X / Centers -> Xb
//   [+0, +2720)         4 weight transposes (bf16, pre-transposed)
//   [+0, +1088)         gen_C  (C1t, C2t [NF][128])
//   [+0, +2176)         gen_T  (Tt [NF][2048], now at ws+96MB)
//   [+0, +9)            zbias = 0
// ---------------------------------------------------------------------------
#define CAST_NB   (BATCH * D_IN / 4 / 256)        // 16384 blocks per source
#define NB_CAST   (2 * CAST_NB)                   // 32768
#define NB_TW1    ((D_IN / 32) * (H1_DIM / 32))   // 512
#define NB_TW2    ((H1_DIM / 32) * (H2_DIM / 32)) // 128
#define NB_TW3    ((H2_DIM / 32) * (H3_DIM / 32)) // 32
#define NB_TWC1   ((D_CBP / 32) * (H_C / 32))     // 2048
#define NB_TRANS  (NB_TW1 + NB_TW2 + NB_TW3 + NB_TWC1)  // 2720
#define NB_GENC   (NF * H3_DIM / 256)             // 1088
#define NB_GENT   (NF)                            // 2176
#define NB_ZB     9
#define NB_PREP   (NB_CAST + NB_TRANS + NB_GENC + NB_GENT + NB_ZB)

__global__ __launch_bounds__(256) void prep_all(
    const float* __restrict__ X, const float* __restrict__ Centers,
    u16* __restrict__ Xb,
    const float* __restrict__ W1, u16* __restrict__ W1t,
    const float* __restrict__ W2, u16* __restrict__ W2t,
    const float* __restrict__ W3, u16* __restrict__ W3t,
    const float* __restrict__ Wc1, u16* __restrict__ Wc1t,
    const int* __restrict__ h1, const float* __restrict__ s1,
    const int* __restrict__ h2, const float* __restrict__ s2,
    u16* __restrict__ C1t, u16* __restrict__ C2t,
    u16* __restrict__ Tt, float* __restrict__ zbias)
{
  __shared__ float tile[32][33];
  int bx = blockIdx.x;
  const int t = threadIdx.x;

  if (bx < NB_CAST) {                       // ---- cast role ----
    const float* s = (bx < CAST_NB) ? X : Centers;
    const int i = ((bx < CAST_NB) ? bx : bx - CAST_NB) * 256 + t;
    u16* d = Xb + ((bx < CAST_NB) ? 0 : (size_t)BATCH * D_IN);
    const float4 v = ((const float4*)s)[i];
    __align__(8) u16 o[4] = {f2b(v.x), f2b(v.y), f2b(v.z), f2b(v.w)};
    *(uint2*)(d + (size_t)i * 4) = *(uint2*)o;
    return;
  }
  bx -= NB_CAST;

  if (bx < NB_TRANS) {                      // ---- transpose role ----
    const float* W; u16* Wt; int K, N;
    if (bx < NB_TW1)        { W = W1;  Wt = W1t;  K = D_IN;   N = H1_DIM; }
    else if (bx < NB_TW1 + NB_TW2) {
      bx -= NB_TW1;           W = W2;  Wt = W2t;  K = H1_DIM; N = H2_DIM; }
    else if (bx < NB_TW1 + NB_TW2 + NB_TW3) {
      bx -= NB_TW1 + NB_TW2;  W = W3;  Wt = W3t;  K = H2_DIM; N = H3_DIM; }
    else {
      bx -= NB_TW1 + NB_TW2 + NB_TW3;
                              W = Wc1; Wt = Wc1t; K = D_CBP;  N = H_C;    }
    const int nt = N / 32;
    const int k0 = (bx / nt) * 32, n0 = (bx % nt) * 32;
    const int tx = t & 31, ty = t >> 5;
#pragma unroll
    for (int s = 0; s < 4; ++s) {
      const int k = ty * 4 + s;
      tile[k][tx] = W[(size_t)(k0 + k) * N + n0 + tx];
    }
    __syncthreads();
#pragma unroll
    for (int s = 0; s < 4; ++s) {
      const int n = ty * 4 + s;
      Wt[(size_t)(n0 + n) * K + k0 + tx] = f2b(tile[tx][n]);
    }
    return;
  }
  bx -= NB_TRANS;

  if (bx < NB_GENC) {                       // ---- gen_C role ----
    const int id = bx * 256 + t;            // [0, NF*128)
    const int m = id >> 7, i = id & 127;
    const int k = m >> 1;
    float v1 = 0.f, v2 = 0.f;
    if (m < 2 * (D_CBP / 2 + 1)) {          // m < 2050
      const float2 c1 = twiddle((k * h1[i]) & (D_CBP - 1));
      const float2 c2 = twiddle((k * h2[i]) & (D_CBP - 1));
      v1 = (m & 1) ? -s1[i] * c1.y : s1[i] * c1.x;
      v2 = (m & 1) ? -s2[i] * c2.y : s2[i] * c2.x;
    }
    C1t[id] = f2b(v1);
    C2t[id] = f2b(v2);
    return;
  }
  bx -= NB_GENC;

  if (bx < NB_GENT) {                       // ---- gen_T role ----
    const int id = bx * 256 + t;            // [0, NF*256)
    const int m = id >> 8, q0 = (id & 255) * 8;
    const int k = m >> 1;
    const float sc = ((k == 0) || (k == D_CBP / 2)) ? (1.f / D_CBP)
                                                    : (2.f / D_CBP);
    __align__(16) u16 o[8];
#pragma unroll
    for (int j = 0; j < 8; ++j) {
      float v = 0.f;
      if (m < 2 * (D_CBP / 2 + 1)) {
        const float2 cs = twiddle((k * (q0 + j)) & (D_CBP - 1));
        v = (m & 1) ? -sc * cs.y : sc * cs.x;
      }
      o[j] = f2b(v);
    }
    *(v8s*)&Tt[(size_t)m * D_CBP + q0] = *(v8s*)o;
    return;
  }
  bx -= NB_GENT;

  {                                         // ---- zbias role ----
    const int i = bx * 256 + t;
    if (i < NF) zbias[i] = 0.f;
  }
}

// ---------------------------------------------------------------------------
// Head: logits = Z[B,1024](bf16) @ Wc2[1024,10] + bc2; softmax -> fp32 out.
// ---------------------------------------------------------------------------
__global__ __launch_bounds__(256) void head_softmax(
    const u16* __restrict__ Z, const float* __restrict__ Wc2,
    const float* __restrict__ bc2, float* __restrict__ out)
{
  const int row  = blockIdx.x * 4 + (threadIdx.x >> 6);
  const int lane = threadIdx.x & 63;

  float acc[CLASSES];
#pragma unroll
  for (int c = 0; c < CLASSES; ++c) acc[c] = 0.f;

  const u16* z = Z + (size_t)row * H_C;
  for (int k = lane; k < H_C; k += 64) {
    const float zv = b2f(z[k]);
    const float* w = Wc2 + (size_t)k * CLASSES;
#pragma unroll
    for (int c = 0; c < CLASSES; ++c) acc[c] += zv * w[c];
  }
#pragma unroll
  for (int c = 0; c < CLASSES; ++c) {
#pragma unroll
    for (int off = 32; off > 0; off >>= 1)
      acc[c] += __shfl_down(acc[c], off);
  }
  if (lane == 0) {
    float l[CLASSES], mx = -1e30f;
#pragma unroll
    for (int c = 0; c < CLASSES; ++c) { l[c] = acc[c] + bc2[c]; mx = fmaxf(mx, l[c]); }
    float s = 0.f;
#pragma unroll
    for (int c = 0; c < CLASSES; ++c) { l[c] = __expf(l[c] - mx); s += l[c]; }
    const float inv = 1.f / s;
#pragma unroll
    for (int c = 0; c < CLASSES; ++c) out[(size_t)row * CLASSES + c] = l[c] * inv;
  }
}

// ---------------------------------------------------------------------------
// Launcher (8 dispatches).  Workspace map (MB = 1<<20), peak < 128 MiB:
//   Xb   @ 0..64     [2B,1024] bf16      (prep -> G1; dead after G1)
//   FWt  @ 8.5..12.75 [1024,2176] bf16   (FWt-gemm after G1, over dead Xb)
//   F1   @ 13..81    [16384,2176] bf16   (gemm_f1f2 -> G4')
//   E1b  @ 64..96    (G1 -> G2)
//   Zb   @ 81..113   (G4' -> head; over dead E2b)
//   E2b  @ 96..112   (G2 -> G3; overwrites dead Tt)
//   Tt   @ 96..104.5 [2176,2048] bf16    (prep -> FWt-gemm; dead before G2)
//   E3b  @ 113..121  [2B,128] bf16       (G3 -> gemm_f1f2)
//   W1t @121  W2t @122  W3t @122.25  Wc1t @122.5..126.5
//   C1t @126.5  C2t @127.0625  zbias @127.65
// Order: prep -> G1 -> FWt-gemm (reads Tt, writes dead-Xb) -> G2 (kills Tt)
//        -> G3 -> f1f2 -> G4' -> head.
// ---------------------------------------------------------------------------
extern "C" void kernel_launch(void* const* d_in, const int* in_sizes, int n_in,
                              void* d_out, int out_size, void* d_ws, size_t ws_size,
                              hipStream_t stream) {
  const float* X       = (const float*)d_in[0];
  const float* Centers = (const float*)d_in[1];
  const float* W1      = (const float*)d_in[2];
  const float* b1      = (const float*)d_in[3];
  const float* W2      = (const float*)d_in[4];
  const float* b2      = (const float*)d_in[5];
  const float* W3      = (const float*)d_in[6];
  const float* b3      = (const float*)d_in[7];
  const int*   h1      = (const int*)d_in[8];
  const float* s1      = (const float*)d_in[9];
  const int*   h2      = (const int*)d_in[10];
  const float* s2      = (const float*)d_in[11];
  const float* Wc1     = (const float*)d_in[12];
  const float* bc1     = (const float*)d_in[13];
  const float* Wc2     = (const float*)d_in[14];
  const float* bc2     = (const float*)d_in[15];
  float* out = (float*)d_out;

  char* ws = (char*)d_ws;
  const size_t MB = 1u << 20;
  const size_t KB = 1u << 10;
  u16*    Xb    = (u16*)(ws);
  u16*    FWt   = (u16*)(ws + 8 * MB + 512 * KB);
  u16*    F1    = (u16*)(ws + 13 * MB);
  u16*    E1b   = (u16*)(ws + 64 * MB);
  u16*    Zb    = (u16*)(ws + 81 * MB);
  u16*    E2b   = (u16*)(ws + 96 * MB);
  u16*    Tt    = (u16*)(ws + 96 * MB);             // dead before G2
  u16*    E3b   = (u16*)(ws + 113 * MB);
  u16*    W1t   = (u16*)(ws + 121 * MB);
  u16*    W2t   = (u16*)(ws + 122 * MB);
  u16*    W3t   = (u16*)(ws + 122 * MB + 256 * KB);
  u16*    Wc1t  = (u16*)(ws + 122 * MB + 512 * KB);
  u16*    C1t   = (u16*)(ws + 126 * MB + 512 * KB);
  u16*    C2t   = (u16*)(ws + 127 * MB + 64 * KB);
  float*  zbias = (float*)(ws + 127 * MB + 672 * KB);

  const dim3 blk(256);

  // all input prep in one launch
  prep_all<<<dim3(NB_PREP), blk, 0, stream>>>(
      X, Centers, Xb, W1, W1t, W2, W2t, W3, W3t, Wc1, Wc1t,
      h1, s1, h2, s2, C1t, C2t, Tt, zbias);

  // G1 (frees Xb region for FWt)
  gemm_bf16<<<dim3(H1_DIM / 128, 2 * BATCH / 128), blk, 0, stream>>>(
      Xb, W1t, b1, E1b, 2 * BATCH, H1_DIM, D_IN, D_IN, D_IN, SLOPE);

  // FWt = Wc1t @ Tt^T   [1024][2176]   (consumes Tt before G2 kills it)
  gemm_bf16<<<dim3(NF / 128, H_C / 128), blk, 0, stream>>>(
      Wc1t, Tt, zbias, FWt, H_C, NF, D_CBP, D_CBP, D_CBP, 1.0f);

  // G2, G3
  gemm_bf16<<<dim3(H2_DIM / 128, 2 * BATCH / 128), blk, 0, stream>>>(
      E1b, W2t, b2, E2b, 2 * BATCH, H2_DIM, H1_DIM, H1_DIM, H1_DIM, SLOPE);
  gemm_bf16<<<dim3(H3_DIM / 128, 2 * BATCH / 128), blk, 0, stream>>>(
      E2b, W3t, b3, E3b, 2 * BATCH, H3_DIM, H2_DIM, H2_DIM, H2_DIM, SLOPE);

  // P = F1 .* F2, fused dual-GEMM, register complex product
  gemm_f1f2<<<dim3(NF / 128, BATCH / 128), blk, 0, stream>>>(
      E3b, C1t, C2t, F1);

  // Z = lrelu(P @ FWt^T + bc1)   [16384][1024], K trimmed 2176 -> 2080
  gemm_bf16<<<dim3(H_C / 128, BATCH / 128), blk, 0, stream>>>(
      F1, FWt, bc1, Zb, BATCH, H_C, NF_USED, NF, NF, SLOPE);

  // head
  head_softmax<<<dim3(BATCH / 4), blk, 0, stream>>>(Zb, Wc2, bc2, out);
}

// Round 10
// 433.387 us; speedup vs baseline: 1.3027x; 1.0467x over previous
//
#include <hip/hip_runtime.h>
#include <hip/hip_bf16.h>
#include <math.h>

// ---------------------------------------------------------------------------
// Dims (fixed per reference)
// ---------------------------------------------------------------------------
#define BATCH   16384
#define D_IN    1024
#define H1_DIM  512
#define H2_DIM  256
#define H3_DIM  128
#define D_CBP   2048
#define H_C     1024
#define CLASSES 10
#define SLOPE   0.2f

// FFT-domain dims: rfft bins k = 0..1024 (1025), padded to 1088 complex
// -> 2176 real columns (Re,Im interleaved), = 17 tiles of 128.
// Non-zero real columns: 2*1025 = 2050 -> K-trim to 2080 (mult of 32).
#define NK_PAD  1088
#define NF      (2 * NK_PAD)   // 2176
#define NF_USED 2080           // K-trim for G4' (cols 2050.. are zeros)

typedef short v8s __attribute__((ext_vector_type(8)));
typedef float v4f __attribute__((ext_vector_type(4)));
typedef unsigned short u16;
typedef unsigned int   u32;

__device__ __forceinline__ float b2f(unsigned short u) {
  return __uint_as_float(((unsigned)u) << 16);
}
__device__ __forceinline__ u16 f2b(float f) {
  __hip_bfloat16 h = __float2bfloat16(f);   // RNE
  return __builtin_bit_cast(unsigned short, h);
}

// twiddle (cos,sin)(2π idx/2048) — same expression the old table used,
// so values are bit-identical to the r8 tab[] path.
__device__ __forceinline__ float2 twiddle(int idx) {
  const float ang = 6.2831853071795864769f * (float)idx / 2048.f;
  return make_float2(__cosf(ang), __sinf(ang));
}

// async 16B global->LDS (direct-to-shared DMA). LDS dest = wave-uniform base
// + lane*16 -> LDS layout is forced packed lane-order.
__device__ __forceinline__ void g2l16(const void* g, void* l) {
  __builtin_amdgcn_global_load_lds(
      (const __attribute__((address_space(1))) void*)g,
      (__attribute__((address_space(3))) void*)l, 16, 0, 0);
}

// ---------------------------------------------------------------------------
// 128^2 bf16 MFMA GEMM (verified r6-r9 engine): 4 waves, BK=32, 5-buffer
// ring, prefetch depth 3, one barrier/step, counted vmcnt (12/8/4/0).
// Granule rotation swizzle at the GLOBAL address -> conflict-free ds_read.
// Bijective XCD swizzle. Used for G2/G3/FWt (small/odd-N GEMMs).
// ---------------------------------------------------------------------------
__global__ __launch_bounds__(256) void gemm_bf16(
    const u16* __restrict__ A,   // [M][lda] bf16
    const u16* __restrict__ Bt,  // [N][ldb] bf16  (weights pre-transposed)
    const float* __restrict__ bias,
    u16* __restrict__ C,         // [M][N] bf16
    int M, int N, int K, int lda, int ldb, float slope)
{
  __shared__ __align__(16) short Asb[5][128 * 32];   // 40 KiB
  __shared__ __align__(16) short Bsb[5][128 * 32];   // 40 KiB

  const int tid  = threadIdx.x;
  const int wave = tid >> 6, lane = tid & 63;
  const int wm = wave >> 1, wn = wave & 1;
  const int u = lane & 15, quad = lane >> 4;

  const int nwg = gridDim.x * gridDim.y;
  int id = blockIdx.y * gridDim.x + blockIdx.x;
  if ((nwg & 7) == 0) id = (id & 7) * (nwg >> 3) + (id >> 3);
  const int m0 = (id / gridDim.x) * 128, n0 = (id % gridDim.x) * 128;

  const int g_log = ((lane & 3) - ((lane >> 3) & 3)) & 3;
  const int srow  = wave * 32 + (lane >> 2);
  const u16* gA0 = A  + (size_t)(m0 + srow)      * lda + g_log * 8;
  const u16* gA1 = A  + (size_t)(m0 + srow + 16) * lda + g_log * 8;
  const u16* gB0 = Bt + (size_t)(n0 + srow)      * ldb + g_log * 8;
  const u16* gB1 = Bt + (size_t)(n0 + srow + 16) * ldb + g_log * 8;
  const int lo0 = (wave * 32)      * 32;
  const int lo1 = (wave * 32 + 16) * 32;

  const int gran = (quad + (u >> 1)) & 3;
  int offA[4], offB[4];
#pragma unroll
  for (int i = 0; i < 4; ++i) {
    offA[i] = (wm * 64 + i * 16 + u) * 32 + gran * 8;
    offB[i] = (wn * 64 + i * 16 + u) * 32 + gran * 8;
  }

  v4f acc[4][4];
#pragma unroll
  for (int i = 0; i < 4; ++i)
#pragma unroll
    for (int j = 0; j < 4; ++j) acc[i][j] = (v4f){0.f, 0.f, 0.f, 0.f};

  const int nsteps = K >> 5;   // BK=32

  auto stage = [&](int s, int buf) {
    const int k0 = s * 32;
    g2l16(gA0 + k0, &Asb[buf][lo0]);
    g2l16(gA1 + k0, &Asb[buf][lo1]);
    g2l16(gB0 + k0, &Bsb[buf][lo0]);
    g2l16(gB1 + k0, &Bsb[buf][lo1]);
  };

  stage(0, 0);
  if (nsteps > 1) stage(1, 1);
  if (nsteps > 2) stage(2, 2);

  int cb = 0, sb = 3;   // compute-buffer, stage-buffer (wrap mod 5)
  for (int t = 0; t < nsteps; ++t) {
    if (t + 3 < nsteps) stage(t + 3, sb);

    const int rem = nsteps - 1 - t;
    if (rem >= 3)      asm volatile("s_waitcnt vmcnt(12)" ::: "memory");
    else if (rem == 2) asm volatile("s_waitcnt vmcnt(8)"  ::: "memory");
    else if (rem == 1) asm volatile("s_waitcnt vmcnt(4)"  ::: "memory");
    else               asm volatile("s_waitcnt vmcnt(0)"  ::: "memory");
    __builtin_amdgcn_s_barrier();
    asm volatile("" ::: "memory");   // pin ds_reads below the barrier

    v8s a[4], b[4];
#pragma unroll
    for (int i = 0; i < 4; ++i) a[i] = *(const v8s*)&Asb[cb][offA[i]];
#pragma unroll
    for (int j = 0; j < 4; ++j) b[j] = *(const v8s*)&Bsb[cb][offB[j]];
    __builtin_amdgcn_s_setprio(1);
#pragma unroll
    for (int i = 0; i < 4; ++i)
#pragma unroll
      for (int j = 0; j < 4; ++j)
        acc[i][j] = __builtin_amdgcn_mfma_f32_16x16x32_bf16(a[i], b[j], acc[i][j], 0, 0, 0);
    __builtin_amdgcn_s_setprio(0);

    cb = (cb == 4) ? 0 : cb + 1;
    sb = (sb == 4) ? 0 : sb + 1;
  }

  // C/D layout (m89-verified): col = lane&15, row = quad*4 + reg
  float bcol[4];
#pragma unroll
  for (int j = 0; j < 4; ++j) bcol[j] = bias[n0 + wn * 64 + j * 16 + u];
#pragma unroll
  for (int i = 0; i < 4; ++i)
#pragma unroll
    for (int r = 0; r < 4; ++r) {
      const size_t ro = (size_t)(m0 + wm * 64 + i * 16 + quad * 4 + r) * N
                        + n0 + wn * 64 + u;
#pragma unroll
      for (int j = 0; j < 4; ++j) {
        float v = acc[i][j][r] + bcol[j];
        v = v >= 0.f ? v : slope * v;
        C[ro + j * 16] = f2b(v);
      }
    }
}

// ---------------------------------------------------------------------------
// 256^2 bf16 MFMA GEMM (r10): 512 threads / 8 waves (2M x 4N), per-wave
// output 128x64 -> 32 MFMA per barrier vs 12 ds_read_b128 (ratio 2.67 vs
// the 128^2 engine's 2.0) and HALF the barriers of an equal-FLOP 128^2 run.
// BK=32 kept so ALL verified addressing generalizes verbatim: staging
// srow = wave*32+(lane>>2) covers rows 0..255 with 8 waves; granule
// swizzle unchanged (row stride 64 B) -> conflict-free ds_read.
// Ring-4 buffers (128 KiB LDS, 1 block/CU), prefetch depth 2, counted
// vmcnt 8/4/0. WAR: stage(t+2) overwrites buf read at step t-2, whose
// reads precede barrier(t-1) in program order; stage issues after
// barrier(t-1) -> race-free. Accumulation order per output element is
// identical to the 128^2 engine -> bit-identical results.
// Requires M%256==0 && N%256==0. Used for G1 and G4'.
// ---------------------------------------------------------------------------
__global__ __launch_bounds__(512) void gemm256_bf16(
    const u16* __restrict__ A,   // [M][lda] bf16
    const u16* __restrict__ Bt,  // [N][ldb] bf16
    const float* __restrict__ bias,
    u16* __restrict__ C,         // [M][N] bf16
    int M, int N, int K, int lda, int ldb, float slope)
{
  __shared__ __align__(16) short Asb[4][256 * 32];   // 64 KiB
  __shared__ __align__(16) short Bsb[4][256 * 32];   // 64 KiB

  const int tid  = threadIdx.x;
  const int wave = tid >> 6, lane = tid & 63;
  const int wm = wave >> 2, wn = wave & 3;     // 2 x 4 wave grid
  const int u = lane & 15, quad = lane >> 4;

  const int nwg = gridDim.x * gridDim.y;
  int id = blockIdx.y * gridDim.x + blockIdx.x;
  if ((nwg & 7) == 0) id = (id & 7) * (nwg >> 3) + (id >> 3);
  const int m0 = (id / gridDim.x) * 256, n0 = (id % gridDim.x) * 256;

  const int g_log = ((lane & 3) - ((lane >> 3) & 3)) & 3;
  const int srow  = wave * 32 + (lane >> 2);   // 8 waves -> rows 0..255
  const u16* gA0 = A  + (size_t)(m0 + srow)      * lda + g_log * 8;
  const u16* gA1 = A  + (size_t)(m0 + srow + 16) * lda + g_log * 8;
  const u16* gB0 = Bt + (size_t)(n0 + srow)      * ldb + g_log * 8;
  const u16* gB1 = Bt + (size_t)(n0 + srow + 16) * ldb + g_log * 8;
  const int lo0 = (wave * 32)      * 32;
  const int lo1 = (wave * 32 + 16) * 32;

  const int gran = (quad + (u >> 1)) & 3;
  int offA[8], offB[4];
#pragma unroll
  for (int i = 0; i < 8; ++i)
    offA[i] = (wm * 128 + i * 16 + u) * 32 + gran * 8;
#pragma unroll
  for (int j = 0; j < 4; ++j)
    offB[j] = (wn * 64 + j * 16 + u) * 32 + gran * 8;

  v4f acc[8][4];
#pragma unroll
  for (int i = 0; i < 8; ++i)
#pragma unroll
    for (int j = 0; j < 4; ++j) acc[i][j] = (v4f){0.f, 0.f, 0.f, 0.f};

  const int nsteps = K >> 5;   // BK=32

  auto stage = [&](int s, int buf) {
    const int k0 = s * 32;
    g2l16(gA0 + k0, &Asb[buf][lo0]);
    g2l16(gA1 + k0, &Asb[buf][lo1]);
    g2l16(gB0 + k0, &Bsb[buf][lo0]);
    g2l16(gB1 + k0, &Bsb[buf][lo1]);
  };

  stage(0, 0);
  if (nsteps > 1) stage(1, 1);

  for (int t = 0; t < nsteps; ++t) {
    if (t + 2 < nsteps) stage(t + 2, (t + 2) & 3);

    const int rem = nsteps - 1 - t;
    if (rem >= 2)      asm volatile("s_waitcnt vmcnt(8)" ::: "memory");
    else if (rem == 1) asm volatile("s_waitcnt vmcnt(4)" ::: "memory");
    else               asm volatile("s_waitcnt vmcnt(0)" ::: "memory");
    __builtin_amdgcn_s_barrier();
    asm volatile("" ::: "memory");   // pin ds_reads below the barrier

    const int cb = t & 3;
    v8s a[8], b[4];
#pragma unroll
    for (int i = 0; i < 8; ++i) a[i] = *(const v8s*)&Asb[cb][offA[i]];
#pragma unroll
    for (int j = 0; j < 4; ++j) b[j] = *(const v8s*)&Bsb[cb][offB[j]];
    __builtin_amdgcn_s_setprio(1);
#pragma unroll
    for (int i = 0; i < 8; ++i)
#pragma unroll
      for (int j = 0; j < 4; ++j)
        acc[i][j] = __builtin_amdgcn_mfma_f32_16x16x32_bf16(a[i], b[j], acc[i][j], 0, 0, 0);
    __builtin_amdgcn_s_setprio(0);
  }

  // C/D layout: col = lane&15, row = quad*4 + reg
  float bcol[4];
#pragma unroll
  for (int j = 0; j < 4; ++j) bcol[j] = bias[n0 + wn * 64 + j * 16 + u];
#pragma unroll
  for (int i = 0; i < 8; ++i)
#pragma unroll
    for (int r = 0; r < 4; ++r) {
      const size_t ro = (size_t)(m0 + wm * 128 + i * 16 + quad * 4 + r) * N
                        + n0 + wn * 64 + u;
#pragma unroll
      for (int j = 0; j < 4; ++j) {
        float v = acc[i][j][r] + bcol[j];
        v = v >= 0.f ? v : slope * v;
        C[ro + j * 16] = f2b(v);
      }
    }
}

// ---------------------------------------------------------------------------
// Fused F1/F2/complex-product kernel (r8, verified).
// Each block computes BOTH K=128 GEMM passes for its (m,n) tile, then writes
// F1 <- acc1 (.)complex acc2 once, from f32 registers.
// Cross-pass LDS WAR race-free (see r8 proof). vmcnt ladder 12/8/4/0.
// ---------------------------------------------------------------------------
__device__ __forceinline__ void f_pass(
    const u16* gA0, const u16* gA1, const u16* gB0, const u16* gB1,
    short (*Asb)[128 * 32], short (*Bsb)[128 * 32],
    int lo0, int lo1, const int* offA, const int* offB,
    v4f (&acc)[4][4])
{
  auto stage = [&](int s, int buf) {
    const int k0 = s * 32;
    g2l16(gA0 + k0, &Asb[buf][lo0]);
    g2l16(gA1 + k0, &Asb[buf][lo1]);
    g2l16(gB0 + k0, &Bsb[buf][lo0]);
    g2l16(gB1 + k0, &Bsb[buf][lo1]);
  };
  stage(0, 0); stage(1, 1); stage(2, 2);
#pragma unroll
  for (int t = 0; t < 4; ++t) {
    if (t == 0) stage(3, 3);
    if (t == 0)      asm volatile("s_waitcnt vmcnt(12)" ::: "memory");
    else if (t == 1) asm volatile("s_waitcnt vmcnt(8)"  ::: "memory");
    else if (t == 2) asm volatile("s_waitcnt vmcnt(4)"  ::: "memory");
    else             asm volatile("s_waitcnt vmcnt(0)"  ::: "memory");
    __builtin_amdgcn_s_barrier();
    asm volatile("" ::: "memory");
    v8s a[4], b[4];
#pragma unroll
    for (int i = 0; i < 4; ++i) a[i] = *(const v8s*)&Asb[t][offA[i]];
#pragma unroll
    for (int j = 0; j < 4; ++j) b[j] = *(const v8s*)&Bsb[t][offB[j]];
    __builtin_amdgcn_s_setprio(1);
#pragma unroll
    for (int i = 0; i < 4; ++i)
#pragma unroll
      for (int j = 0; j < 4; ++j)
        acc[i][j] = __builtin_amdgcn_mfma_f32_16x16x32_bf16(a[i], b[j], acc[i][j], 0, 0, 0);
    __builtin_amdgcn_s_setprio(0);
  }
}

__global__ __launch_bounds__(256) void gemm_f1f2(
    const u16* __restrict__ E3,    // [2*BATCH][128]; rows B.. = centers
    const u16* __restrict__ C1t,   // [NF][128]
    const u16* __restrict__ C2t,   // [NF][128]
    u16* __restrict__ F1)          // [BATCH][NF] <- F1 .* F2
{
  __shared__ __align__(16) short Asb[5][128 * 32];
  __shared__ __align__(16) short Bsb[5][128 * 32];

  const int tid  = threadIdx.x;
  const int wave = tid >> 6, lane = tid & 63;
  const int wm = wave >> 1, wn = wave & 1;
  const int u = lane & 15, quad = lane >> 4;
  const int N = NF, K = H3_DIM;

  const int nwg = gridDim.x * gridDim.y;
  int id = blockIdx.y * gridDim.x + blockIdx.x;
  if ((nwg & 7) == 0) id = (id & 7) * (nwg >> 3) + (id >> 3);
  const int m0 = (id / gridDim.x) * 128, n0 = (id % gridDim.x) * 128;

  const int g_log = ((lane & 3) - ((lane >> 3) & 3)) & 3;
  const int srow  = wave * 32 + (lane >> 2);
  const size_t aoffX = (size_t)(m0 + srow) * K + g_log * 8;
  const size_t boff  = (size_t)(n0 + srow) * K + g_log * 8;
  const int lo0 = (wave * 32)      * 32;
  const int lo1 = (wave * 32 + 16) * 32;

  const int gran = (quad + (u >> 1)) & 3;
  int offA[4], offB[4];
#pragma unroll
  for (int i = 0; i < 4; ++i) {
    offA[i] = (wm * 64 + i * 16 + u) * 32 + gran * 8;
    offB[i] = (wn * 64 + i * 16 + u) * 32 + gran * 8;
  }

  v4f acc1[4][4], acc2[4][4];
#pragma unroll
  for (int i = 0; i < 4; ++i)
#pragma unroll
    for (int j = 0; j < 4; ++j) {
      acc1[i][j] = (v4f){0.f, 0.f, 0.f, 0.f};
      acc2[i][j] = (v4f){0.f, 0.f, 0.f, 0.f};
    }

  // pass 1: F1 = E3x @ C1^T
  f_pass(E3 + aoffX, E3 + aoffX + (size_t)16 * K,
         C1t + boff, C1t + boff + (size_t)16 * K,
         Asb, Bsb, lo0, lo1, offA, offB, acc1);
  // pass 2: F2 = E3c @ C2^T  (centers rows start at BATCH)
  const size_t aoffC = aoffX + (size_t)BATCH * K;
  f_pass(E3 + aoffC, E3 + aoffC + (size_t)16 * K,
         C2t + boff, C2t + boff + (size_t)16 * K,
         Asb, Bsb, lo0, lo1, offA, offB, acc2);

  // epilogue: complex product, all in registers.
  const bool im = (u & 1);
#pragma unroll
  for (int i = 0; i < 4; ++i)
#pragma unroll
    for (int r = 0; r < 4; ++r) {
      const size_t ro = (size_t)(m0 + wm * 64 + i * 16 + quad * 4 + r) * N
                        + n0 + wn * 64 + u;
#pragma unroll
      for (int j = 0; j < 4; ++j) {
        const float f1v = acc1[i][j][r];
        const float f1p = __shfl_xor(f1v, 1, 64);
        const float f2v = acc2[i][j][r];
        const float f2p = __shfl_xor(f2v, 1, 64);
        const float outv = im ? (f1p * f2v + f1v * f2p)
                              : (f1v * f2v - f1p * f2p);
        F1[ro + j * 16] = f2b(outv);
      }
    }
}

// ---------------------------------------------------------------------------
// prep_all (r9, verified): ONE launch for cast + transposes + C/T gen +
// zbias. Twiddles inline (bit-identical to table path).
// ---------------------------------------------------------------------------
#define CAST_NB   (BATCH * D_IN / 4 / 256)        // 16384 blocks per source
#define NB_CAST   (2 * CAST_NB)                   // 32768
#define NB_TW1    ((D_IN / 32) * (H1_DIM / 32))   // 512
#define NB_TW2    ((H1_DIM / 32) * (H2_DIM / 32)) // 128
#define NB_TW3    ((H2_DIM / 32) * (H3_DIM / 32)) // 32
#define NB_TWC1   ((D_CBP / 32) * (H_C / 32))     // 2048
#define NB_TRANS  (NB_TW1 + NB_TW2 + NB_TW3 + NB_TWC1)  // 2720
#define NB_GENC   (NF * H3_DIM / 256)             // 1088
#define NB_GENT   (NF)                            // 2176
#define NB_ZB     9
#define NB_PREP   (NB_CAST + NB_TRANS + NB_GENC + NB_GENT + NB_ZB)

__global__ __launch_bounds__(256) void prep_all(
    const float* __restrict__ X, const float* __restrict__ Centers,
    u16* __restrict__ Xb,
    const float* __restrict__ W1, u16* __restrict__ W1t,
    const float* __restrict__ W2, u16* __restrict__ W2t,
    const float* __restrict__ W3, u16* __restrict__ W3t,
    const float* __restrict__ Wc1, u16* __restrict__ Wc1t,
    const int* __restrict__ h1, const float* __restrict__ s1,
    const int* __restrict__ h2, const float* __restrict__ s2,
    u16* __restrict__ C1t, u16* __restrict__ C2t,
    u16* __restrict__ Tt, float* __restrict__ zbias)
{
  __shared__ float tile[32][33];
  int bx = blockIdx.x;
  const int t = threadIdx.x;

  if (bx < NB_CAST) {                       // ---- cast role ----
    const float* s = (bx < CAST_NB) ? X : Centers;
    const int i = ((bx < CAST_NB) ? bx : bx - CAST_NB) * 256 + t;
    u16* d = Xb + ((bx < CAST_NB) ? 0 : (size_t)BATCH * D_IN);
    const float4 v = ((const float4*)s)[i];
    __align__(8) u16 o[4] = {f2b(v.x), f2b(v.y), f2b(v.z), f2b(v.w)};
    *(uint2*)(d + (size_t)i * 4) = *(uint2*)o;
    return;
  }
  bx -= NB_CAST;

  if (bx < NB_TRANS) {                      // ---- transpose role ----
    const float* W; u16* Wt; int K, N;
    if (bx < NB_TW1)        { W = W1;  Wt = W1t;  K = D_IN;   N = H1_DIM; }
    else if (bx < NB_TW1 + NB_TW2) {
      bx -= NB_TW1;           W = W2;  Wt = W2t;  K = H1_DIM; N = H2_DIM; }
    else if (bx < NB_TW1 + NB_TW2 + NB_TW3) {
      bx -= NB_TW1 + NB_TW2;  W = W3;  Wt = W3t;  K = H2_DIM; N = H3_DIM; }
    else {
      bx -= NB_TW1 + NB_TW2 + NB_TW3;
                              W = Wc1; Wt = Wc1t; K = D_CBP;  N = H_C;    }
    const int nt = N / 32;
    const int k0 = (bx / nt) * 32, n0 = (bx % nt) * 32;
    const int tx = t & 31, ty = t >> 5;
#pragma unroll
    for (int s = 0; s < 4; ++s) {
      const int k = ty * 4 + s;
      tile[k][tx] = W[(size_t)(k0 + k) * N + n0 + tx];
    }
    __syncthreads();
#pragma unroll
    for (int s = 0; s < 4; ++s) {
      const int n = ty * 4 + s;
      Wt[(size_t)(n0 + n) * K + k0 + tx] = f2b(tile[tx][n]);
    }
    return;
  }
  bx -= NB_TRANS;

  if (bx < NB_GENC) {                       // ---- gen_C role ----
    const int id = bx * 256 + t;            // [0, NF*128)
    const int m = id >> 7, i = id & 127;
    const int k = m >> 1;
    float v1 = 0.f, v2 = 0.f;
    if (m < 2 * (D_CBP / 2 + 1)) {          // m < 2050
      const float2 c1 = twiddle((k * h1[i]) & (D_CBP - 1));
      const float2 c2 = twiddle((k * h2[i]) & (D_CBP - 1));
      v1 = (m & 1) ? -s1[i] * c1.y : s1[i] * c1.x;
      v2 = (m & 1) ? -s2[i] * c2.y : s2[i] * c2.x;
    }
    C1t[id] = f2b(v1);
    C2t[id] = f2b(v2);
    return;
  }
  bx -= NB_GENC;

  if (bx < NB_GENT) {                       // ---- gen_T role ----
    const int id = bx * 256 + t;            // [0, NF*256)
    const int m = id >> 8, q0 = (id & 255) * 8;
    const int k = m >> 1;
    const float sc = ((k == 0) || (k == D_CBP / 2)) ? (1.f / D_CBP)
                                                    : (2.f / D_CBP);
    __align__(16) u16 o[8];
#pragma unroll
    for (int j = 0; j < 8; ++j) {
      float v = 0.f;
      if (m < 2 * (D_CBP / 2 + 1)) {
        const float2 cs = twiddle((k * (q0 + j)) & (D_CBP - 1));
        v = (m & 1) ? -sc * cs.y : sc * cs.x;
      }
      o[j] = f2b(v);
    }
    *(v8s*)&Tt[(size_t)m * D_CBP + q0] = *(v8s*)o;
    return;
  }
  bx -= NB_GENT;

  {                                         // ---- zbias role ----
    const int i = bx * 256 + t;
    if (i < NF) zbias[i] = 0.f;
  }
}

// ---------------------------------------------------------------------------
// Head: logits = Z[B,1024](bf16) @ Wc2[1024,10] + bc2; softmax -> fp32 out.
// ---------------------------------------------------------------------------
__global__ __launch_bounds__(256) void head_softmax(
    const u16* __restrict__ Z, const float* __restrict__ Wc2,
    const float* __restrict__ bc2, float* __restrict__ out)
{
  const int row  = blockIdx.x * 4 + (threadIdx.x >> 6);
  const int lane = threadIdx.x & 63;

  float acc[CLASSES];
#pragma unroll
  for (int c = 0; c < CLASSES; ++c) acc[c] = 0.f;

  const u16* z = Z + (size_t)row * H_C;
  for (int k = lane; k < H_C; k += 64) {
    const float zv = b2f(z[k]);
    const float* w = Wc2 + (size_t)k * CLASSES;
#pragma unroll
    for (int c = 0; c < CLASSES; ++c) acc[c] += zv * w[c];
  }
#pragma unroll
  for (int c = 0; c < CLASSES; ++c) {
#pragma unroll
    for (int off = 32; off > 0; off >>= 1)
      acc[c] += __shfl_down(acc[c], off);
  }
  if (lane == 0) {
    float l[CLASSES], mx = -1e30f;
#pragma unroll
    for (int c = 0; c < CLASSES; ++c) { l[c] = acc[c] + bc2[c]; mx = fmaxf(mx, l[c]); }
    float s = 0.f;
#pragma unroll
    for (int c = 0; c < CLASSES; ++c) { l[c] = __expf(l[c] - mx); s += l[c]; }
    const float inv = 1.f / s;
#pragma unroll
    for (int c = 0; c < CLASSES; ++c) out[(size_t)row * CLASSES + c] = l[c] * inv;
  }
}

// ---------------------------------------------------------------------------
// Launcher (8 dispatches).  Workspace map as r9 (peak < 128 MiB).
// G1 and G4' now run on the 256^2 engine (grids 2x128 / 4x64 = 256 blocks
// = exactly 1 block/CU); G2/G3/FWt stay on the 128^2 engine.
// ---------------------------------------------------------------------------
extern "C" void kernel_launch(void* const* d_in, const int* in_sizes, int n_in,
                              void* d_out, int out_size, void* d_ws, size_t ws_size,
                              hipStream_t stream) {
  const float* X       = (const float*)d_in[0];
  const float* Centers = (const float*)d_in[1];
  const float* W1      = (const float*)d_in[2];
  const float* b1      = (const float*)d_in[3];
  const float* W2      = (const float*)d_in[4];
  const float* b2      = (const float*)d_in[5];
  const float* W3      = (const float*)d_in[6];
  const float* b3      = (const float*)d_in[7];
  const int*   h1      = (const int*)d_in[8];
  const float* s1      = (const float*)d_in[9];
  const int*   h2      = (const int*)d_in[10];
  const float* s2      = (const float*)d_in[11];
  const float* Wc1     = (const float*)d_in[12];
  const float* bc1     = (const float*)d_in[13];
  const float* Wc2     = (const float*)d_in[14];
  const float* bc2     = (const float*)d_in[15];
  float* out = (float*)d_out;

  char* ws = (char*)d_ws;
  const size_t MB = 1u << 20;
  const size_t KB = 1u << 10;
  u16*    Xb    = (u16*)(ws);
  u16*    FWt   = (u16*)(ws + 8 * MB + 512 * KB);
  u16*    F1    = (u16*)(ws + 13 * MB);
  u16*    E1b   = (u16*)(ws + 64 * MB);
  u16*    Zb    = (u16*)(ws + 81 * MB);
  u16*    E2b   = (u16*)(ws + 96 * MB);
  u16*    Tt    = (u16*)(ws + 96 * MB);             // dead before G2
  u16*    E3b   = (u16*)(ws + 113 * MB);
  u16*    W1t   = (u16*)(ws + 121 * MB);
  u16*    W2t   = (u16*)(ws + 122 * MB);
  u16*    W3t   = (u16*)(ws + 122 * MB + 256 * KB);
  u16*    Wc1t  = (u16*)(ws + 122 * MB + 512 * KB);
  u16*    C1t   = (u16*)(ws + 126 * MB + 512 * KB);
  u16*    C2t   = (u16*)(ws + 127 * MB + 64 * KB);
  float*  zbias = (float*)(ws + 127 * MB + 672 * KB);

  const dim3 blk(256), blk512(512);

  // all input prep in one launch
  prep_all<<<dim3(NB_PREP), blk, 0, stream>>>(
      X, Centers, Xb, W1, W1t, W2, W2t, W3, W3t, Wc1, Wc1t,
      h1, s1, h2, s2, C1t, C2t, Tt, zbias);

  // G1 on the 256^2 engine (grid 2x128 = 256 blocks, 1/CU)
  gemm256_bf16<<<dim3(H1_DIM / 256, 2 * BATCH / 256), blk512, 0, stream>>>(
      Xb, W1t, b1, E1b, 2 * BATCH, H1_DIM, D_IN, D_IN, D_IN, SLOPE);

  // FWt = Wc1t @ Tt^T   [1024][2176]   (consumes Tt before G2 kills it)
  gemm_bf16<<<dim3(NF / 128, H_C / 128), blk, 0, stream>>>(
      Wc1t, Tt, zbias, FWt, H_C, NF, D_CBP, D_CBP, D_CBP, 1.0f);

  // G2, G3 on the 128^2 engine
  gemm_bf16<<<dim3(H2_DIM / 128, 2 * BATCH / 128), blk, 0, stream>>>(
      E1b, W2t, b2, E2b, 2 * BATCH, H2_DIM, H1_DIM, H1_DIM, H1_DIM, SLOPE);
  gemm_bf16<<<dim3(H3_DIM / 128, 2 * BATCH / 128), blk, 0, stream>>>(
      E2b, W3t, b3, E3b, 2 * BATCH, H3_DIM, H2_DIM, H2_DIM, H2_DIM, SLOPE);

  // P = F1 .* F2, fused dual-GEMM, register complex product
  gemm_f1f2<<<dim3(NF / 128, BATCH / 128), blk, 0, stream>>>(
      E3b, C1t, C2t, F1);

  // Z = lrelu(P @ FWt^T + bc1) on the 256^2 engine (grid 4x64 = 256 blocks)
  gemm256_bf16<<<dim3(H_C / 256, BATCH / 256), blk512, 0, stream>>>(
      F1, FWt, bc1, Zb, BATCH, H_C, NF_USED, NF, NF, SLOPE);

  // head
  head_softmax<<<dim3(BATCH / 4), blk, 0, stream>>>(Zb, Wc2, bc2, out);
}

// Round 11
// 428.321 us; speedup vs baseline: 1.3182x; 1.0118x over previous
//
#include <hip/hip_runtime.h>
#include <hip/hip_bf16.h>
#include <math.h>

// ---------------------------------------------------------------------------
// Dims (fixed per reference)
// ---------------------------------------------------------------------------
#define BATCH   16384
#define D_IN    1024
#define H1_DIM  512
#define H2_DIM  256
#define H3_DIM  128
#define D_CBP   2048
#define H_C     1024
#define CLASSES 10
#define SLOPE   0.2f

// FFT-domain dims: rfft bins k = 0..1024 (1025), padded to 1088 complex
// -> 2176 real columns (Re,Im interleaved), = 17 tiles of 128.
// Non-zero real columns: 2*1025 = 2050 -> K-trim to 2080 (mult of 32).
#define NK_PAD  1088
#define NF      (2 * NK_PAD)   // 2176
#define NF_USED 2080           // K-trim for G4' (cols 2050.. are zeros)

typedef short v8s __attribute__((ext_vector_type(8)));
typedef float v4f __attribute__((ext_vector_type(4)));
typedef unsigned short u16;
typedef unsigned int   u32;

__device__ __forceinline__ float b2f(unsigned short u) {
  return __uint_as_float(((unsigned)u) << 16);
}
__device__ __forceinline__ u16 f2b(float f) {
  __hip_bfloat16 h = __float2bfloat16(f);   // RNE
  return __builtin_bit_cast(unsigned short, h);
}

// twiddle (cos,sin)(2π idx/2048) — same expression the old table used,
// so values are bit-identical to the r8 tab[] path.
__device__ __forceinline__ float2 twiddle(int idx) {
  const float ang = 6.2831853071795864769f * (float)idx / 2048.f;
  return make_float2(__cosf(ang), __sinf(ang));
}

// async 16B global->LDS (direct-to-shared DMA). LDS dest = wave-uniform base
// + lane*16 -> LDS layout is forced packed lane-order.
__device__ __forceinline__ void g2l16(const void* g, void* l) {
  __builtin_amdgcn_global_load_lds(
      (const __attribute__((address_space(1))) void*)g,
      (__attribute__((address_space(3))) void*)l, 16, 0, 0);
}

// ---------------------------------------------------------------------------
// 128^2 bf16 MFMA GEMM (verified r6-r9 engine): 4 waves, BK=32, 5-buffer
// ring, prefetch depth 3, one barrier/step, counted vmcnt (12/8/4/0).
// Granule rotation swizzle at the GLOBAL address -> conflict-free ds_read.
// Bijective XCD swizzle. Used for G2/G3/FWt (small/odd-N GEMMs).
// ---------------------------------------------------------------------------
__global__ __launch_bounds__(256) void gemm_bf16(
    const u16* __restrict__ A,   // [M][lda] bf16
    const u16* __restrict__ Bt,  // [N][ldb] bf16  (weights pre-transposed)
    const float* __restrict__ bias,
    u16* __restrict__ C,         // [M][N] bf16
    int M, int N, int K, int lda, int ldb, float slope)
{
  __shared__ __align__(16) short Asb[5][128 * 32];   // 40 KiB
  __shared__ __align__(16) short Bsb[5][128 * 32];   // 40 KiB

  const int tid  = threadIdx.x;
  const int wave = tid >> 6, lane = tid & 63;
  const int wm = wave >> 1, wn = wave & 1;
  const int u = lane & 15, quad = lane >> 4;

  const int nwg = gridDim.x * gridDim.y;
  int id = blockIdx.y * gridDim.x + blockIdx.x;
  if ((nwg & 7) == 0) id = (id & 7) * (nwg >> 3) + (id >> 3);
  const int m0 = (id / gridDim.x) * 128, n0 = (id % gridDim.x) * 128;

  const int g_log = ((lane & 3) - ((lane >> 3) & 3)) & 3;
  const int srow  = wave * 32 + (lane >> 2);
  const u16* gA0 = A  + (size_t)(m0 + srow)      * lda + g_log * 8;
  const u16* gA1 = A  + (size_t)(m0 + srow + 16) * lda + g_log * 8;
  const u16* gB0 = Bt + (size_t)(n0 + srow)      * ldb + g_log * 8;
  const u16* gB1 = Bt + (size_t)(n0 + srow + 16) * ldb + g_log * 8;
  const int lo0 = (wave * 32)      * 32;
  const int lo1 = (wave * 32 + 16) * 32;

  const int gran = (quad + (u >> 1)) & 3;
  int offA[4], offB[4];
#pragma unroll
  for (int i = 0; i < 4; ++i) {
    offA[i] = (wm * 64 + i * 16 + u) * 32 + gran * 8;
    offB[i] = (wn * 64 + i * 16 + u) * 32 + gran * 8;
  }

  v4f acc[4][4];
#pragma unroll
  for (int i = 0; i < 4; ++i)
#pragma unroll
    for (int j = 0; j < 4; ++j) acc[i][j] = (v4f){0.f, 0.f, 0.f, 0.f};

  const int nsteps = K >> 5;   // BK=32

  auto stage = [&](int s, int buf) {
    const int k0 = s * 32;
    g2l16(gA0 + k0, &Asb[buf][lo0]);
    g2l16(gA1 + k0, &Asb[buf][lo1]);
    g2l16(gB0 + k0, &Bsb[buf][lo0]);
    g2l16(gB1 + k0, &Bsb[buf][lo1]);
  };

  stage(0, 0);
  if (nsteps > 1) stage(1, 1);
  if (nsteps > 2) stage(2, 2);

  int cb = 0, sb = 3;   // compute-buffer, stage-buffer (wrap mod 5)
  for (int t = 0; t < nsteps; ++t) {
    if (t + 3 < nsteps) stage(t + 3, sb);

    const int rem = nsteps - 1 - t;
    if (rem >= 3)      asm volatile("s_waitcnt vmcnt(12)" ::: "memory");
    else if (rem == 2) asm volatile("s_waitcnt vmcnt(8)"  ::: "memory");
    else if (rem == 1) asm volatile("s_waitcnt vmcnt(4)"  ::: "memory");
    else               asm volatile("s_waitcnt vmcnt(0)"  ::: "memory");
    __builtin_amdgcn_s_barrier();
    asm volatile("" ::: "memory");   // pin ds_reads below the barrier

    v8s a[4], b[4];
#pragma unroll
    for (int i = 0; i < 4; ++i) a[i] = *(const v8s*)&Asb[cb][offA[i]];
#pragma unroll
    for (int j = 0; j < 4; ++j) b[j] = *(const v8s*)&Bsb[cb][offB[j]];
    __builtin_amdgcn_s_setprio(1);
#pragma unroll
    for (int i = 0; i < 4; ++i)
#pragma unroll
      for (int j = 0; j < 4; ++j)
        acc[i][j] = __builtin_amdgcn_mfma_f32_16x16x32_bf16(a[i], b[j], acc[i][j], 0, 0, 0);
    __builtin_amdgcn_s_setprio(0);

    cb = (cb == 4) ? 0 : cb + 1;
    sb = (sb == 4) ? 0 : sb + 1;
  }

  // C/D layout (m89-verified): col = lane&15, row = quad*4 + reg
  float bcol[4];
#pragma unroll
  for (int j = 0; j < 4; ++j) bcol[j] = bias[n0 + wn * 64 + j * 16 + u];
#pragma unroll
  for (int i = 0; i < 4; ++i)
#pragma unroll
    for (int r = 0; r < 4; ++r) {
      const size_t ro = (size_t)(m0 + wm * 64 + i * 16 + quad * 4 + r) * N
                        + n0 + wn * 64 + u;
#pragma unroll
      for (int j = 0; j < 4; ++j) {
        float v = acc[i][j][r] + bcol[j];
        v = v >= 0.f ? v : slope * v;
        C[ro + j * 16] = f2b(v);
      }
    }
}

// ---------------------------------------------------------------------------
// 256^2 bf16 MFMA GEMM, r11: software-pipelined LDS reads.
// r10 post-mortem: at 1 block/CU the ds_reads sat AFTER the barrier on the
// critical path (step ~2.7K cyc vs 310 cyc MFMA). Now reads for step t+1
// are issued right after the barrier into a SECOND register set (a_n/b_n)
// and complete under step t's 32-MFMA cluster — the m201 template's core
// overlap, retrofitted onto the verified BK=32 addressing (granule swizzle
// unchanged -> still conflict-free; read:MFMA ratio 12:32 matches m201's).
// Ring-4 LDS, stage depth 2->3-in-flight; steady vmcnt(4), tail 0.
// Hazards: stage(t+3) overwrites buf (t-1)&3 — its reads completed before
// MFMA(t-1), which precedes this iter's barrier in program order; stage is
// issued after the barrier -> race-free. Accumulation order identical ->
// bit-identical results. Requires M%256==0 && N%256==0 (G1, G4').
// ---------------------------------------------------------------------------
__global__ __launch_bounds__(512) void gemm256_bf16(
    const u16* __restrict__ A,   // [M][lda] bf16
    const u16* __restrict__ Bt,  // [N][ldb] bf16
    const float* __restrict__ bias,
    u16* __restrict__ C,         // [M][N] bf16
    int M, int N, int K, int lda, int ldb, float slope)
{
  __shared__ __align__(16) short Asb[4][256 * 32];   // 64 KiB
  __shared__ __align__(16) short Bsb[4][256 * 32];   // 64 KiB

  const int tid  = threadIdx.x;
  const int wave = tid >> 6, lane = tid & 63;
  const int wm = wave >> 2, wn = wave & 3;     // 2 x 4 wave grid
  const int u = lane & 15, quad = lane >> 4;

  const int nwg = gridDim.x * gridDim.y;
  int id = blockIdx.y * gridDim.x + blockIdx.x;
  if ((nwg & 7) == 0) id = (id & 7) * (nwg >> 3) + (id >> 3);
  const int m0 = (id / gridDim.x) * 256, n0 = (id % gridDim.x) * 256;

  const int g_log = ((lane & 3) - ((lane >> 3) & 3)) & 3;
  const int srow  = wave * 32 + (lane >> 2);   // 8 waves -> rows 0..255
  const u16* gA0 = A  + (size_t)(m0 + srow)      * lda + g_log * 8;
  const u16* gA1 = A  + (size_t)(m0 + srow + 16) * lda + g_log * 8;
  const u16* gB0 = Bt + (size_t)(n0 + srow)      * ldb + g_log * 8;
  const u16* gB1 = Bt + (size_t)(n0 + srow + 16) * ldb + g_log * 8;
  const int lo0 = (wave * 32)      * 32;
  const int lo1 = (wave * 32 + 16) * 32;

  const int gran = (quad + (u >> 1)) & 3;
  int offA[8], offB[4];
#pragma unroll
  for (int i = 0; i < 8; ++i)
    offA[i] = (wm * 128 + i * 16 + u) * 32 + gran * 8;
#pragma unroll
  for (int j = 0; j < 4; ++j)
    offB[j] = (wn * 64 + j * 16 + u) * 32 + gran * 8;

  v4f acc[8][4];
#pragma unroll
  for (int i = 0; i < 8; ++i)
#pragma unroll
    for (int j = 0; j < 4; ++j) acc[i][j] = (v4f){0.f, 0.f, 0.f, 0.f};

  const int nsteps = K >> 5;   // BK=32

  auto stage = [&](int s) {
    const int k0 = s * 32, buf = s & 3;
    g2l16(gA0 + k0, &Asb[buf][lo0]);
    g2l16(gA1 + k0, &Asb[buf][lo1]);
    g2l16(gB0 + k0, &Bsb[buf][lo0]);
    g2l16(gB1 + k0, &Bsb[buf][lo1]);
  };

  // prologue: stage 0..2, wait step 0, pre-issue reads of buf0
  stage(0);
  if (nsteps > 1) stage(1);
  if (nsteps > 2) stage(2);
  if (nsteps > 2)      asm volatile("s_waitcnt vmcnt(8)" ::: "memory");
  else if (nsteps > 1) asm volatile("s_waitcnt vmcnt(4)" ::: "memory");
  else                 asm volatile("s_waitcnt vmcnt(0)" ::: "memory");
  __builtin_amdgcn_s_barrier();
  asm volatile("" ::: "memory");

  v8s a_c[8], b_c[4], a_n[8], b_n[4];
#pragma unroll
  for (int i = 0; i < 8; ++i) a_c[i] = *(const v8s*)&Asb[0][offA[i]];
#pragma unroll
  for (int j = 0; j < 4; ++j) b_c[j] = *(const v8s*)&Bsb[0][offB[j]];

  for (int t = 0; t < nsteps; ++t) {
    const int rem = nsteps - 1 - t;
    if (rem > 0) {
      // retire step t+1's stage (issued >=2 iters ago -> near-free wait),
      // then issue its ds_reads; they complete under MFMA(t) below.
      if (rem >= 2) asm volatile("s_waitcnt vmcnt(4)" ::: "memory");
      else          asm volatile("s_waitcnt vmcnt(0)" ::: "memory");
      __builtin_amdgcn_s_barrier();
      asm volatile("" ::: "memory");   // pin ds_reads below the barrier
      const int nb = (t + 1) & 3;
#pragma unroll
      for (int i = 0; i < 8; ++i) a_n[i] = *(const v8s*)&Asb[nb][offA[i]];
#pragma unroll
      for (int j = 0; j < 4; ++j) b_n[j] = *(const v8s*)&Bsb[nb][offB[j]];
    }

    __builtin_amdgcn_s_setprio(1);
#pragma unroll
    for (int i = 0; i < 8; ++i)
#pragma unroll
      for (int j = 0; j < 4; ++j)
        acc[i][j] = __builtin_amdgcn_mfma_f32_16x16x32_bf16(a_c[i], b_c[j], acc[i][j], 0, 0, 0);
    __builtin_amdgcn_s_setprio(0);

    if (t + 3 < nsteps) stage(t + 3);   // overwrites buf (t-1)&3: safe (see hdr)

    if (rem > 0) {
#pragma unroll
      for (int i = 0; i < 8; ++i) a_c[i] = a_n[i];
#pragma unroll
      for (int j = 0; j < 4; ++j) b_c[j] = b_n[j];
    }
  }

  // C/D layout: col = lane&15, row = quad*4 + reg
  float bcol[4];
#pragma unroll
  for (int j = 0; j < 4; ++j) bcol[j] = bias[n0 + wn * 64 + j * 16 + u];
#pragma unroll
  for (int i = 0; i < 8; ++i)
#pragma unroll
    for (int r = 0; r < 4; ++r) {
      const size_t ro = (size_t)(m0 + wm * 128 + i * 16 + quad * 4 + r) * N
                        + n0 + wn * 64 + u;
#pragma unroll
      for (int j = 0; j < 4; ++j) {
        float v = acc[i][j][r] + bcol[j];
        v = v >= 0.f ? v : slope * v;
        C[ro + j * 16] = f2b(v);
      }
    }
}

// ---------------------------------------------------------------------------
// Fused F1/F2/complex-product kernel (r8, verified).
// Each block computes BOTH K=128 GEMM passes for its (m,n) tile, then writes
// F1 <- acc1 (.)complex acc2 once, from f32 registers.
// Cross-pass LDS WAR race-free (see r8 proof). vmcnt ladder 12/8/4/0.
// ---------------------------------------------------------------------------
__device__ __forceinline__ void f_pass(
    const u16* gA0, const u16* gA1, const u16* gB0, const u16* gB1,
    short (*Asb)[128 * 32], short (*Bsb)[128 * 32],
    int lo0, int lo1, const int* offA, const int* offB,
    v4f (&acc)[4][4])
{
  auto stage = [&](int s, int buf) {
    const int k0 = s * 32;
    g2l16(gA0 + k0, &Asb[buf][lo0]);
    g2l16(gA1 + k0, &Asb[buf][lo1]);
    g2l16(gB0 + k0, &Bsb[buf][lo0]);
    g2l16(gB1 + k0, &Bsb[buf][lo1]);
  };
  stage(0, 0); stage(1, 1); stage(2, 2);
#pragma unroll
  for (int t = 0; t < 4; ++t) {
    if (t == 0) stage(3, 3);
    if (t == 0)      asm volatile("s_waitcnt vmcnt(12)" ::: "memory");
    else if (t == 1) asm volatile("s_waitcnt vmcnt(8)"  ::: "memory");
    else if (t == 2) asm volatile("s_waitcnt vmcnt(4)"  ::: "memory");
    else             asm volatile("s_waitcnt vmcnt(0)"  ::: "memory");
    __builtin_amdgcn_s_barrier();
    asm volatile("" ::: "memory");
    v8s a[4], b[4];
#pragma unroll
    for (int i = 0; i < 4; ++i) a[i] = *(const v8s*)&Asb[t][offA[i]];
#pragma unroll
    for (int j = 0; j < 4; ++j) b[j] = *(const v8s*)&Bsb[t][offB[j]];
    __builtin_amdgcn_s_setprio(1);
#pragma unroll
    for (int i = 0; i < 4; ++i)
#pragma unroll
      for (int j = 0; j < 4; ++j)
        acc[i][j] = __builtin_amdgcn_mfma_f32_16x16x32_bf16(a[i], b[j], acc[i][j], 0, 0, 0);
    __builtin_amdgcn_s_setprio(0);
  }
}

__global__ __launch_bounds__(256) void gemm_f1f2(
    const u16* __restrict__ E3,    // [2*BATCH][128]; rows B.. = centers
    const u16* __restrict__ C1t,   // [NF][128]
    const u16* __restrict__ C2t,   // [NF][128]
    u16* __restrict__ F1)          // [BATCH][NF] <- F1 .* F2
{
  __shared__ __align__(16) short Asb[5][128 * 32];
  __shared__ __align__(16) short Bsb[5][128 * 32];

  const int tid  = threadIdx.x;
  const int wave = tid >> 6, lane = tid & 63;
  const int wm = wave >> 1, wn = wave & 1;
  const int u = lane & 15, quad = lane >> 4;
  const int N = NF, K = H3_DIM;

  const int nwg = gridDim.x * gridDim.y;
  int id = blockIdx.y * gridDim.x + blockIdx.x;
  if ((nwg & 7) == 0) id = (id & 7) * (nwg >> 3) + (id >> 3);
  const int m0 = (id / gridDim.x) * 128, n0 = (id % gridDim.x) * 128;

  const int g_log = ((lane & 3) - ((lane >> 3) & 3)) & 3;
  const int srow  = wave * 32 + (lane >> 2);
  const size_t aoffX = (size_t)(m0 + srow) * K + g_log * 8;
  const size_t boff  = (size_t)(n0 + srow) * K + g_log * 8;
  const int lo0 = (wave * 32)      * 32;
  const int lo1 = (wave * 32 + 16) * 32;

  const int gran = (quad + (u >> 1)) & 3;
  int offA[4], offB[4];
#pragma unroll
  for (int i = 0; i < 4; ++i) {
    offA[i] = (wm * 64 + i * 16 + u) * 32 + gran * 8;
    offB[i] = (wn * 64 + i * 16 + u) * 32 + gran * 8;
  }

  v4f acc1[4][4], acc2[4][4];
#pragma unroll
  for (int i = 0; i < 4; ++i)
#pragma unroll
    for (int j = 0; j < 4; ++j) {
      acc1[i][j] = (v4f){0.f, 0.f, 0.f, 0.f};
      acc2[i][j] = (v4f){0.f, 0.f, 0.f, 0.f};
    }

  // pass 1: F1 = E3x @ C1^T
  f_pass(E3 + aoffX, E3 + aoffX + (size_t)16 * K,
         C1t + boff, C1t + boff + (size_t)16 * K,
         Asb, Bsb, lo0, lo1, offA, offB, acc1);
  // pass 2: F2 = E3c @ C2^T  (centers rows start at BATCH)
  const size_t aoffC = aoffX + (size_t)BATCH * K;
  f_pass(E3 + aoffC, E3 + aoffC + (size_t)16 * K,
         C2t + boff, C2t + boff + (size_t)16 * K,
         Asb, Bsb, lo0, lo1, offA, offB, acc2);

  // epilogue: complex product, all in registers.
  const bool im = (u & 1);
#pragma unroll
  for (int i = 0; i < 4; ++i)
#pragma unroll
    for (int r = 0; r < 4; ++r) {
      const size_t ro = (size_t)(m0 + wm * 64 + i * 16 + quad * 4 + r) * N
                        + n0 + wn * 64 + u;
#pragma unroll
      for (int j = 0; j < 4; ++j) {
        const float f1v = acc1[i][j][r];
        const float f1p = __shfl_xor(f1v, 1, 64);
        const float f2v = acc2[i][j][r];
        const float f2p = __shfl_xor(f2v, 1, 64);
        const float outv = im ? (f1p * f2v + f1v * f2p)
                              : (f1v * f2v - f1p * f2p);
        F1[ro + j * 16] = f2b(outv);
      }
    }
}

// ---------------------------------------------------------------------------
// prep_all (r9, verified): ONE launch for cast + transposes + C/T gen +
// zbias. Twiddles inline (bit-identical to table path).
// ---------------------------------------------------------------------------
#define CAST_NB   (BATCH * D_IN / 4 / 256)        // 16384 blocks per source
#define NB_CAST   (2 * CAST_NB)                   // 32768
#define NB_TW1    ((D_IN / 32) * (H1_DIM / 32))   // 512
#define NB_TW2    ((H1_DIM / 32) * (H2_DIM / 32)) // 128
#define NB_TW3    ((H2_DIM / 32) * (H3_DIM / 32)) // 32
#define NB_TWC1   ((D_CBP / 32) * (H_C / 32))     // 2048
#define NB_TRANS  (NB_TW1 + NB_TW2 + NB_TW3 + NB_TWC1)  // 2720
#define NB_GENC   (NF * H3_DIM / 256)             // 1088
#define NB_GENT   (NF)                            // 2176
#define NB_ZB     9
#define NB_PREP   (NB_CAST + NB_TRANS + NB_GENC + NB_GENT + NB_ZB)

__global__ __launch_bounds__(256) void prep_all(
    const float* __restrict__ X, const float* __restrict__ Centers,
    u16* __restrict__ Xb,
    const float* __restrict__ W1, u16* __restrict__ W1t,
    const float* __restrict__ W2, u16* __restrict__ W2t,
    const float* __restrict__ W3, u16* __restrict__ W3t,
    const float* __restrict__ Wc1, u16* __restrict__ Wc1t,
    const int* __restrict__ h1, const float* __restrict__ s1,
    const int* __restrict__ h2, const float* __restrict__ s2,
    u16* __restrict__ C1t, u16* __restrict__ C2t,
    u16* __restrict__ Tt, float* __restrict__ zbias)
{
  __shared__ float tile[32][33];
  int bx = blockIdx.x;
  const int t = threadIdx.x;

  if (bx < NB_CAST) {                       // ---- cast role ----
    const float* s = (bx < CAST_NB) ? X : Centers;
    const int i = ((bx < CAST_NB) ? bx : bx - CAST_NB) * 256 + t;
    u16* d = Xb + ((bx < CAST_NB) ? 0 : (size_t)BATCH * D_IN);
    const float4 v = ((const float4*)s)[i];
    __align__(8) u16 o[4] = {f2b(v.x), f2b(v.y), f2b(v.z), f2b(v.w)};
    *(uint2*)(d + (size_t)i * 4) = *(uint2*)o;
    return;
  }
  bx -= NB_CAST;

  if (bx < NB_TRANS) {                      // ---- transpose role ----
    const float* W; u16* Wt; int K, N;
    if (bx < NB_TW1)        { W = W1;  Wt = W1t;  K = D_IN;   N = H1_DIM; }
    else if (bx < NB_TW1 + NB_TW2) {
      bx -= NB_TW1;           W = W2;  Wt = W2t;  K = H1_DIM; N = H2_DIM; }
    else if (bx < NB_TW1 + NB_TW2 + NB_TW3) {
      bx -= NB_TW1 + NB_TW2;  W = W3;  Wt = W3t;  K = H2_DIM; N = H3_DIM; }
    else {
      bx -= NB_TW1 + NB_TW2 + NB_TW3;
                              W = Wc1; Wt = Wc1t; K = D_CBP;  N = H_C;    }
    const int nt = N / 32;
    const int k0 = (bx / nt) * 32, n0 = (bx % nt) * 32;
    const int tx = t & 31, ty = t >> 5;
#pragma unroll
    for (int s = 0; s < 4; ++s) {
      const int k = ty * 4 + s;
      tile[k][tx] = W[(size_t)(k0 + k) * N + n0 + tx];
    }
    __syncthreads();
#pragma unroll
    for (int s = 0; s < 4; ++s) {
      const int n = ty * 4 + s;
      Wt[(size_t)(n0 + n) * K + k0 + tx] = f2b(tile[tx][n]);
    }
    return;
  }
  bx -= NB_TRANS;

  if (bx < NB_GENC) {                       // ---- gen_C role ----
    const int id = bx * 256 + t;            // [0, NF*128)
    const int m = id >> 7, i = id & 127;
    const int k = m >> 1;
    float v1 = 0.f, v2 = 0.f;
    if (m < 2 * (D_CBP / 2 + 1)) {          // m < 2050
      const float2 c1 = twiddle((k * h1[i]) & (D_CBP - 1));
      const float2 c2 = twiddle((k * h2[i]) & (D_CBP - 1));
      v1 = (m & 1) ? -s1[i] * c1.y : s1[i] * c1.x;
      v2 = (m & 1) ? -s2[i] * c2.y : s2[i] * c2.x;
    }
    C1t[id] = f2b(v1);
    C2t[id] = f2b(v2);
    return;
  }
  bx -= NB_GENC;

  if (bx < NB_GENT) {                       // ---- gen_T role ----
    const int id = bx * 256 + t;            // [0, NF*256)
    const int m = id >> 8, q0 = (id & 255) * 8;
    const int k = m >> 1;
    const float sc = ((k == 0) || (k == D_CBP / 2)) ? (1.f / D_CBP)
                                                    : (2.f / D_CBP);
    __align__(16) u16 o[8];
#pragma unroll
    for (int j = 0; j < 8; ++j) {
      float v = 0.f;
      if (m < 2 * (D_CBP / 2 + 1)) {
        const float2 cs = twiddle((k * (q0 + j)) & (D_CBP - 1));
        v = (m & 1) ? -sc * cs.y : sc * cs.x;
      }
      o[j] = f2b(v);
    }
    *(v8s*)&Tt[(size_t)m * D_CBP + q0] = *(v8s*)o;
    return;
  }
  bx -= NB_GENT;

  {                                         // ---- zbias role ----
    const int i = bx * 256 + t;
    if (i < NF) zbias[i] = 0.f;
  }
}

// ---------------------------------------------------------------------------
// Head: logits = Z[B,1024](bf16) @ Wc2[1024,10] + bc2; softmax -> fp32 out.
// ---------------------------------------------------------------------------
__global__ __launch_bounds__(256) void head_softmax(
    const u16* __restrict__ Z, const float* __restrict__ Wc2,
    const float* __restrict__ bc2, float* __restrict__ out)
{
  const int row  = blockIdx.x * 4 + (threadIdx.x >> 6);
  const int lane = threadIdx.x & 63;

  float acc[CLASSES];
#pragma unroll
  for (int c = 0; c < CLASSES; ++c) acc[c] = 0.f;

  const u16* z = Z + (size_t)row * H_C;
  for (int k = lane; k < H_C; k += 64) {
    const float zv = b2f(z[k]);
    const float* w = Wc2 + (size_t)k * CLASSES;
#pragma unroll
    for (int c = 0; c < CLASSES; ++c) acc[c] += zv * w[c];
  }
#pragma unroll
  for (int c = 0; c < CLASSES; ++c) {
#pragma unroll
    for (int off = 32; off > 0; off >>= 1)
      acc[c] += __shfl_down(acc[c], off);
  }
  if (lane == 0) {
    float l[CLASSES], mx = -1e30f;
#pragma unroll
    for (int c = 0; c < CLASSES; ++c) { l[c] = acc[c] + bc2[c]; mx = fmaxf(mx, l[c]); }
    float s = 0.f;
#pragma unroll
    for (int c = 0; c < CLASSES; ++c) { l[c] = __expf(l[c] - mx); s += l[c]; }
    const float inv = 1.f / s;
#pragma unroll
    for (int c = 0; c < CLASSES; ++c) out[(size_t)row * CLASSES + c] = l[c] * inv;
  }
}

// ---------------------------------------------------------------------------
// Launcher (8 dispatches).  Workspace map as r9 (peak < 128 MiB).
// G1 / G4' on the pipelined 256^2 engine; G2/G3/FWt on the 128^2 engine.
// ---------------------------------------------------------------------------
extern "C" void kernel_launch(void* const* d_in, const int* in_sizes, int n_in,
                              void* d_out, int out_size, void* d_ws, size_t ws_size,
                              hipStream_t stream) {
  const float* X       = (const float*)d_in[0];
  const float* Centers = (const float*)d_in[1];
  const float* W1      = (const float*)d_in[2];
  const float* b1      = (const float*)d_in[3];
  const float* W2      = (const float*)d_in[4];
  const float* b2      = (const float*)d_in[5];
  const float* W3      = (const float*)d_in[6];
  const float* b3      = (const float*)d_in[7];
  const int*   h1      = (const int*)d_in[8];
  const float* s1      = (const float*)d_in[9];
  const int*   h2      = (const int*)d_in[10];
  const float* s2      = (const float*)d_in[11];
  const float* Wc1     = (const float*)d_in[12];
  const float* bc1     = (const float*)d_in[13];
  const float* Wc2     = (const float*)d_in[14];
  const float* bc2     = (const float*)d_in[15];
  float* out = (float*)d_out;

  char* ws = (char*)d_ws;
  const size_t MB = 1u << 20;
  const size_t KB = 1u << 10;
  u16*    Xb    = (u16*)(ws);
  u16*    FWt   = (u16*)(ws + 8 * MB + 512 * KB);
  u16*    F1    = (u16*)(ws + 13 * MB);
  u16*    E1b   = (u16*)(ws + 64 * MB);
  u16*    Zb    = (u16*)(ws + 81 * MB);
  u16*    E2b   = (u16*)(ws + 96 * MB);
  u16*    Tt    = (u16*)(ws + 96 * MB);             // dead before G2
  u16*    E3b   = (u16*)(ws + 113 * MB);
  u16*    W1t   = (u16*)(ws + 121 * MB);
  u16*    W2t   = (u16*)(ws + 122 * MB);
  u16*    W3t   = (u16*)(ws + 122 * MB + 256 * KB);
  u16*    Wc1t  = (u16*)(ws + 122 * MB + 512 * KB);
  u16*    C1t   = (u16*)(ws + 126 * MB + 512 * KB);
  u16*    C2t   = (u16*)(ws + 127 * MB + 64 * KB);
  float*  zbias = (float*)(ws + 127 * MB + 672 * KB);

  const dim3 blk(256), blk512(512);

  // all input prep in one launch
  prep_all<<<dim3(NB_PREP), blk, 0, stream>>>(
      X, Centers, Xb, W1, W1t, W2, W2t, W3, W3t, Wc1, Wc1t,
      h1, s1, h2, s2, C1t, C2t, Tt, zbias);

  // G1 on the 256^2 engine (grid 2x128 = 256 blocks, 1/CU)
  gemm256_bf16<<<dim3(H1_DIM / 256, 2 * BATCH / 256), blk512, 0, stream>>>(
      Xb, W1t, b1, E1b, 2 * BATCH, H1_DIM, D_IN, D_IN, D_IN, SLOPE);

  // FWt = Wc1t @ Tt^T   [1024][2176]   (consumes Tt before G2 kills it)
  gemm_bf16<<<dim3(NF / 128, H_C / 128), blk, 0, stream>>>(
      Wc1t, Tt, zbias, FWt, H_C, NF, D_CBP, D_CBP, D_CBP, 1.0f);

  // G2, G3 on the 128^2 engine
  gemm_bf16<<<dim3(H2_DIM / 128, 2 * BATCH / 128), blk, 0, stream>>>(
      E1b, W2t, b2, E2b, 2 * BATCH, H2_DIM, H1_DIM, H1_DIM, H1_DIM, SLOPE);
  gemm_bf16<<<dim3(H3_DIM / 128, 2 * BATCH / 128), blk, 0, stream>>>(
      E2b, W3t, b3, E3b, 2 * BATCH, H3_DIM, H2_DIM, H2_DIM, H2_DIM, SLOPE);

  // P = F1 .* F2, fused dual-GEMM, register complex product
  gemm_f1f2<<<dim3(NF / 128, BATCH / 128), blk, 0, stream>>>(
      E3b, C1t, C2t, F1);

  // Z = lrelu(P @ FWt^T + bc1) on the 256^2 engine (grid 4x64 = 256 blocks)
  gemm256_bf16<<<dim3(H_C / 256, BATCH / 256), blk512, 0, stream>>>(
      F1, FWt, bc1, Zb, BATCH, H_C, NF_USED, NF, NF, SLOPE);

  // head
  head_softmax<<<dim3(BATCH / 4), blk, 0, stream>>>(Zb, Wc2, bc2, out);
}